// Round 19
// baseline (1276.703 us; speedup 1.0000x reference)
//
#include <hip/hip_runtime.h>
#include <hip/hip_fp16.h>
#include <math.h>

#define N_USERS 50000
#define N_ITEMS 30000
#define NNODES  80000
#define NEDGES  640000
#define NCLUS   64
#define NEG     0.2f
#define EPSV    1e-5f

typedef __attribute__((ext_vector_type(8))) short bf16x8;
typedef __attribute__((ext_vector_type(4))) float f32x4;

__device__ __forceinline__ float lrelu(float x){ return x > 0.f ? x : NEG*x; }

__device__ __forceinline__ unsigned short f2bf(float f){
  unsigned u = __float_as_uint(f);
  u += 0x7fffu + ((u>>16)&1u);
  return (unsigned short)(u>>16);
}
__device__ __forceinline__ unsigned pk2(float lo, float hi){
  return (unsigned)f2bf(lo) | ((unsigned)f2bf(hi) << 16);
}
__device__ __forceinline__ float4 f4add(float4 a, float4 b){
  return make_float4(a.x+b.x, a.y+b.y, a.z+b.z, a.w+b.w);
}
__device__ __forceinline__ float4 f4fma1(float s, float4 a, float4 b){
  return make_float4(fmaf(s,a.x,b.x), fmaf(s,a.y,b.y), fmaf(s,a.z,b.z), fmaf(s,a.w,b.w));
}

// ---------------- phase 0: pair histogram (LDS-aggregated, 1024-thread blocks) ----------------
__global__ __launch_bounds__(1024) void k_pairhist(
    const int* __restrict__ ei, const float* __restrict__ eattr, const int* __restrict__ clus,
    int* __restrict__ cnt, int* __restrict__ intra,
    float* __restrict__ pcb, float* __restrict__ pa0b, float* __restrict__ pa1b)
{
  __shared__ float pc[4096];
  __shared__ float pa0[4096];
  __shared__ float pa1[4096];
  for (int i=threadIdx.x; i<4096; i+=1024){ pc[i]=0.f; pa0[i]=0.f; pa1[i]=0.f; }
  __syncthreads();
  for (int e = blockIdx.x*1024 + threadIdx.x; e < NEDGES; e += 128*1024){
    int s = ei[e], d = ei[NEDGES+e];
    int cu = clus[s], cv = clus[d];
    atomicAdd(&cnt[d], 1);
    if (cu == cv) { atomicAdd(&intra[d], 1); }
    else {
      float2 a = *reinterpret_cast<const float2*>(&eattr[2*e]);
      int k = cu*NCLUS + cv;
      atomicAdd(&pc[k], 1.f);
      atomicAdd(&pa0[k], a.x);
      atomicAdd(&pa1[k], a.y);
    }
  }
  __syncthreads();
  int b = blockIdx.x;
  for (int i=threadIdx.x; i<4096; i+=1024){
    pcb [i*128 + b] = pc[i];
    pa0b[i*128 + b] = pa0[i];
    pa1b[i*128 + b] = pa1[i];
  }
}

__global__ __launch_bounds__(64) void k_pairreduce(
    const float* __restrict__ pcb, const float* __restrict__ pa0b, const float* __restrict__ pa1b,
    float* __restrict__ pair_cnt, float* __restrict__ avg_attr)
{
  int i = blockIdx.x*64 + threadIdx.x;  // 4096 total over grid 64
  float c=0.f, s0=0.f, s1=0.f;
  const float4* P0 = (const float4*)(pcb  + (size_t)i*128);
  const float4* P1 = (const float4*)(pa0b + (size_t)i*128);
  const float4* P2 = (const float4*)(pa1b + (size_t)i*128);
  for (int b=0;b<32;b++){
    float4 v0=P0[b], v1=P1[b], v2=P2[b];
    c  += v0.x+v0.y+v0.z+v0.w;
    s0 += v1.x+v1.y+v1.z+v1.w;
    s1 += v2.x+v2.y+v2.z+v2.w;
  }
  pair_cnt[i] = c;
  float inv = 1.f/fmaxf(c, 1.f);
  avg_attr[2*i]   = s0*inv;
  avg_attr[2*i+1] = s1*inv;
}

// dual scan: cnt->offs and intra->ioffs, one launch; csize histogram LDS-aggregated
__global__ __launch_bounds__(256) void k_scan_block2(const int* __restrict__ in1, const int* __restrict__ in2,
                                                     int* __restrict__ out1, int* __restrict__ out2,
                                                     int* __restrict__ bsum1, int* __restrict__ bsum2, int n,
                                                     const int* __restrict__ clus, int* __restrict__ csize){
  __shared__ int buf[256];
  __shared__ int lcs[NCLUS];
  int i = blockIdx.x*256 + threadIdx.x;
  if (threadIdx.x < NCLUS) lcs[threadIdx.x] = 0;
  __syncthreads();
  if (i < n) atomicAdd(&lcs[clus[i]], 1);
  int v = (i < n) ? in1[i] : 0;
  buf[threadIdx.x] = v; __syncthreads();
  for (int off=1; off<256; off<<=1){
    int t = (threadIdx.x>=off) ? buf[threadIdx.x-off] : 0;
    __syncthreads();
    buf[threadIdx.x] += t;
    __syncthreads();
  }
  if (i < n) out1[i] = buf[threadIdx.x] - v;
  if (threadIdx.x == 255) bsum1[blockIdx.x] = buf[255];
  __syncthreads();
  v = (i < n) ? in2[i] : 0;
  buf[threadIdx.x] = v; __syncthreads();
  for (int off=1; off<256; off<<=1){
    int t = (threadIdx.x>=off) ? buf[threadIdx.x-off] : 0;
    __syncthreads();
    buf[threadIdx.x] += t;
    __syncthreads();
  }
  if (i < n) out2[i] = buf[threadIdx.x] - v;
  if (threadIdx.x == 255) bsum2[blockIdx.x] = buf[255];
  __syncthreads();
  if (threadIdx.x < NCLUS){
    int c = lcs[threadIdx.x];
    if (c) atomicAdd(&csize[threadIdx.x], c);
  }
}

__global__ __launch_bounds__(512) void k_scan_bsum2(int* __restrict__ bsum1, int* __restrict__ bsum2, int nb){
  int* bs = blockIdx.x ? bsum2 : bsum1;
  __shared__ int buf[512];
  int v = (threadIdx.x < nb) ? bs[threadIdx.x] : 0;
  buf[threadIdx.x] = v; __syncthreads();
  for (int off=1; off<512; off<<=1){
    int t = (threadIdx.x>=off) ? buf[threadIdx.x-off] : 0;
    __syncthreads();
    buf[threadIdx.x] += t;
    __syncthreads();
  }
  if (threadIdx.x < nb) bs[threadIdx.x] = buf[threadIdx.x] - v;
}

__global__ __launch_bounds__(256) void k_scan_add2(int* __restrict__ out1, int* __restrict__ out2,
                                                   const int* __restrict__ bsum1, const int* __restrict__ bsum2,
                                                   int n, int total1, int total2){
  int* out = blockIdx.y ? out2 : out1;
  const int* bs = blockIdx.y ? bsum2 : bsum1;
  int total = blockIdx.y ? total2 : total1;
  int i = blockIdx.x*256 + threadIdx.x;
  if (i < n) out[i] += bs[i>>8];
  if (i == 0) out[n] = total;
}

// fill main CSR + intra CSR (no atomics on float data)
__global__ __launch_bounds__(256) void k_fill_csr(const int* __restrict__ ei, const int* __restrict__ clus,
                                                  const int* __restrict__ offs, const int* __restrict__ ioffs,
                                                  int* __restrict__ cursor, int* __restrict__ cursor2,
                                                  int2* __restrict__ csr, int* __restrict__ csr2){
  int e = blockIdx.x*256 + threadIdx.x;
  if (e >= NEDGES) return;
  int s = ei[e], d = ei[NEDGES+e];
  int pos = offs[d] + atomicAdd(&cursor[d], 1);
  csr[pos] = make_int2(s, e);
  if (clus[s] == clus[d]){
    int p2 = ioffs[d] + atomicAdd(&cursor2[d], 1);
    csr2[p2] = s;
  }
}

// per-node mean edge-attr (self-loop fill), from CSR
__global__ __launch_bounds__(256) void k_loopattr(const int* __restrict__ offs, const int2* __restrict__ csr,
                                                  const float* __restrict__ eattr, float* __restrict__ la){
  int n = blockIdx.x*256 + threadIdx.x;
  if (n >= NNODES) return;
  int b0 = offs[n], b1 = offs[n+1];
  float s0=0.f, s1=0.f;
  for (int i=b0; i<b1; ++i){
    int e = csr[i].y;
    float2 a = *reinterpret_cast<const float2*>(&eattr[2*e]);
    s0 += a.x; s1 += a.y;
  }
  float inv = 1.f/fmaxf((float)(b1-b0), 1.f);
  la[2*n] = s0*inv; la[2*n+1] = s1*inv;
}

// ---------------- weight converts + glt2(W' for agg GEMM) + AsAll/AdAll + M2, one kernel ----------------
__global__ __launch_bounds__(256) void k_wtall_m2(const float* __restrict__ W1, const float* __restrict__ W2,
                       const float* __restrict__ gcnW, const float* __restrict__ gat_lin,
                       unsigned short* __restrict__ W1t, unsigned short* __restrict__ W2t,
                       unsigned short* __restrict__ gcnWt, unsigned short* __restrict__ glt2,
                       const float* __restrict__ att_s, const float* __restrict__ att_d,
                       float* __restrict__ AsAll, float* __restrict__ AdAll,
                       const float* __restrict__ g_lin_e, const float* __restrict__ g_att_e,
                       const float* __restrict__ gat_lin_e, const float* __restrict__ gat_att_e,
                       float* __restrict__ M2g, float* __restrict__ M2){
  int i = blockIdx.x*256 + threadIdx.x;
  if (i < 229376){            // W1: K=896, N=256
    int n = i/896, k = i - n*896;
    W1t[i] = f2bf(W1[(size_t)k*256 + n]);
  } else if (i < 262144){     // W2: K=256, N=128
    int j = i - 229376; int n = j/256, k = j - n*256;
    W2t[j] = f2bf(W2[(size_t)k*128 + n]);
  } else if (i < 278528){     // gcnW: 128x128
    int j = i - 262144; int n = j/128, k = j - n*128;
    gcnWt[j] = f2bf(gcnW[(size_t)k*128 + n]);
  } else if (i < 475136){     // glt2: 3 x [128 d][512 hk]
    int j = i - 278528; int l = j >> 16; int r = j & 65535; int d = r >> 9; int hk = r & 511;
    glt2[j] = f2bf(0.25f * gat_lin[(size_t)l*65536 + (size_t)(hk & 127)*512 + (hk >> 7)*128 + d]);
  } else if (i < 478208){     // AsAll/AdAll: 3*128*4*2
    int j = i - 475136;
    int which = j & 1, h = (j >> 1) & 3, k = (j >> 3) & 127, l = j >> 10;
    const float* att = which ? att_d : att_s;
    float s = 0.f;
    for (int c=0;c<128;c++) s += gat_lin[(size_t)l*65536 + k*512 + h*128 + c] * att[l*512 + h*128 + c];
    float* dst = which ? AdAll : AsAll;
    dst[l*512 + k*4 + h] = s;
  } else if (i < 478240){     // M2 precompute
    int t = i - 478208;
    if (t < 8){
      int j = t >> 2, h = t & 3;
      float s = 0.f;
      for (int c=0;c<128;c++) s += g_lin_e[j*512 + h*128 + c] * g_att_e[h*128 + c];
      M2g[j*4+h] = s;
    } else {
      int u = t - 8; int l = u >> 3, j = (u >> 2) & 1, h = u & 3;
      float s = 0.f;
      for (int c=0;c<128;c++) s += gat_lin_e[l*1024 + j*512 + h*128 + c] * gat_att_e[l*512 + h*128 + c];
      M2[l*8 + j*4 + h] = s;
    }
  }
}

// ---------------- bf16 MFMA GEMM: C = act(A @ Bt^T + bias), 128x128 tile ----------------
template<int AF32, int CONCAT, int OUT, int RELU, int BIAS>
__global__ __launch_bounds__(256)
void k_mgemm(const void* __restrict__ Av, const float* __restrict__ A2,
             const unsigned short* __restrict__ Bt, const float* __restrict__ bias,
             void* __restrict__ Cv, int M, int N, int K, int K1)
{
  __shared__ unsigned short As[128*64];
  __shared__ unsigned short Bs[128*64];
  const int tid = threadIdx.x;
  const int lane = tid & 63, w = tid >> 6;
  const int row0 = blockIdx.x*128, col0 = blockIdx.y*128;
  const int wm = w >> 1, wn = w & 1;
  const int l15 = lane & 15, l4 = lane >> 4;
  f32x4 acc[4][4];
  #pragma unroll
  for (int i=0;i<4;i++)
    #pragma unroll
    for (int n=0;n<4;n++) acc[i][n] = (f32x4){0.f,0.f,0.f,0.f};

  const int rr0 = w*32 + (lane>>3);
  const int cA = lane & 7;

  for (int kt = 0; kt < K; kt += 64){
    uint4 ra[4], rb[4];
    #pragma unroll
    for (int i=0;i<4;i++){
      int rr = rr0 + i*8;
      int ga = row0 + rr; ga = (ga < M) ? ga : (M-1);
      int gb = col0 + rr; gb = (gb < N) ? gb : (N-1);
      int gk = kt + cA*8;
      if (AF32){
        const float* Af = (const float*)Av;
        const float* src;
        if (CONCAT && gk >= K1) src = A2 + (size_t)ga*(K-K1) + (gk - K1);
        else                    src = Af + (size_t)ga*(CONCAT ? K1 : K) + gk;
        float4 f0 = ((const float4*)src)[0];
        float4 f1 = ((const float4*)src)[1];
        ra[i] = make_uint4(pk2(f0.x,f0.y), pk2(f0.z,f0.w), pk2(f1.x,f1.y), pk2(f1.z,f1.w));
      } else {
        ra[i] = *reinterpret_cast<const uint4*>((const unsigned short*)Av + (size_t)ga*K + gk);
      }
      rb[i] = *reinterpret_cast<const uint4*>(Bt + (size_t)gb*K + gk);
    }
    __syncthreads();
    #pragma unroll
    for (int i=0;i<4;i++){
      int rr = rr0 + i*8;
      int ch = cA ^ (rr & 7);
      *reinterpret_cast<uint4*>(&As[rr*64 + ch*8]) = ra[i];
      *reinterpret_cast<uint4*>(&Bs[rr*64 + ch*8]) = rb[i];
    }
    __syncthreads();
    #pragma unroll
    for (int k0=0;k0<2;k0++){
      bf16x8 af[4], bff[4];
      #pragma unroll
      for (int i=0;i<4;i++){
        int row = wm*64 + i*16 + l15;
        int ch = (k0*4 + l4) ^ (row & 7);
        af[i] = *reinterpret_cast<const bf16x8*>(&As[row*64 + ch*8]);
      }
      #pragma unroll
      for (int n=0;n<4;n++){
        int row = wn*64 + n*16 + l15;
        int ch = (k0*4 + l4) ^ (row & 7);
        bff[n] = *reinterpret_cast<const bf16x8*>(&Bs[row*64 + ch*8]);
      }
      #pragma unroll
      for (int i=0;i<4;i++)
        #pragma unroll
        for (int n=0;n<4;n++)
          acc[i][n] = __builtin_amdgcn_mfma_f32_16x16x32_bf16(af[i], bff[n], acc[i][n], 0, 0, 0);
    }
  }
  // C store
  #pragma unroll
  for (int i=0;i<4;i++){
    int rowb = row0 + wm*64 + i*16 + l4*4;
    #pragma unroll
    for (int n=0;n<4;n++){
      int col = col0 + wn*64 + n*16 + l15;
      float bv = BIAS ? bias[col] : 0.f;
      #pragma unroll
      for (int r=0;r<4;r++){
        int row = rowb + r;
        if (row < M){
          float y = acc[i][n][r] + bv;
          if (RELU) y = fmaxf(y, 0.f);
          if (OUT == 1)      ((unsigned short*)Cv)[(size_t)row*N + col] = f2bf(y);
          else if (OUT == 2) ((__half*)Cv)[(size_t)row*N + col] = __float2half(y);
          else               ((float*)Cv)[(size_t)row*N + col] = y;
        }
      }
    }
  }
}

// ---------------- tall-skinny bf16 GEMM: 64-row tile, N=128, f16 out + bias ----------------
__global__ __launch_bounds__(256)
void k_mgemm64(const unsigned short* __restrict__ A, const unsigned short* __restrict__ Bt,
               const float* __restrict__ bias, __half* __restrict__ C, int M, int K)
{
  __shared__ unsigned short As[64*64];    // 8KB
  __shared__ unsigned short Bs[128*64];   // 16KB
  const int tid = threadIdx.x;
  const int lane = tid & 63, w = tid >> 6;
  const int row0 = blockIdx.x*64;
  const int l15 = lane & 15, l4 = lane >> 4;
  f32x4 acc[8];
  #pragma unroll
  for (int n=0;n<8;n++) acc[n] = (f32x4){0.f,0.f,0.f,0.f};

  const int rA = tid >> 3;       // 0..31
  const int cA = tid & 7;        // chunk

  for (int kt = 0; kt < K; kt += 64){
    uint4 ra[2], rb[4];
    #pragma unroll
    for (int i=0;i<2;i++){
      int rr = rA + i*32;
      int ga = row0 + rr; ga = (ga < M) ? ga : (M-1);
      ra[i] = *reinterpret_cast<const uint4*>(A + (size_t)ga*K + kt + cA*8);
    }
    #pragma unroll
    for (int i=0;i<4;i++){
      int rr = rA + i*32;
      rb[i] = *reinterpret_cast<const uint4*>(Bt + (size_t)rr*K + kt + cA*8);
    }
    __syncthreads();
    #pragma unroll
    for (int i=0;i<2;i++){
      int rr = rA + i*32;
      int ch = cA ^ (rr & 7);
      *reinterpret_cast<uint4*>(&As[rr*64 + ch*8]) = ra[i];
    }
    #pragma unroll
    for (int i=0;i<4;i++){
      int rr = rA + i*32;
      int ch = cA ^ (rr & 7);
      *reinterpret_cast<uint4*>(&Bs[rr*64 + ch*8]) = rb[i];
    }
    __syncthreads();
    #pragma unroll
    for (int k0=0;k0<2;k0++){
      int arow = w*16 + l15;
      int ach = (k0*4 + l4) ^ (arow & 7);
      bf16x8 af = *reinterpret_cast<const bf16x8*>(&As[arow*64 + ach*8]);
      #pragma unroll
      for (int n=0;n<8;n++){
        int brow = n*16 + l15;
        int bch = (k0*4 + l4) ^ (brow & 7);
        bf16x8 bf = *reinterpret_cast<const bf16x8*>(&Bs[brow*64 + bch*8]);
        acc[n] = __builtin_amdgcn_mfma_f32_16x16x32_bf16(af, bf, acc[n], 0, 0, 0);
      }
    }
    __syncthreads();
  }
  int rowb = row0 + w*16 + l4*4;
  #pragma unroll
  for (int n=0;n<8;n++){
    int col = n*16 + l15;
    float bv = bias[col];
    #pragma unroll
    for (int r=0;r<4;r++){
      int row = rowb + r;
      if (row < M) C[(size_t)row*128 + col] = __float2half(acc[n][r] + bv);
    }
  }
}

// ---------------- f32 SGEMM (tiny pooled GEMM only) ----------------
template<int CONCAT, int ACT>
__global__ __launch_bounds__(256)
void k_sgemm(const float* __restrict__ A, const float* __restrict__ A2,
             const float* __restrict__ B, const float* __restrict__ bias,
             float* __restrict__ C, int M, int N, int K, int K1)
{
  __shared__ float As[8][128];
  __shared__ float Bs[8][128];
  int row0 = blockIdx.x*128, col0 = blockIdx.y*128;
  int tid = threadIdx.x;
  int tx = tid & 15, ty = tid >> 4;
  float acc[8][8];
  #pragma unroll
  for (int i=0;i<8;i++)
    #pragma unroll
    for (int j=0;j<8;j++) acc[i][j]=0.f;

  int arow = tid >> 1, acol = (tid & 1)*4;
  int brow = tid >> 5, bcol = (tid & 31)*4;
  int K2 = K - K1;

  for (int k0=0; k0<K; k0+=8){
    float4 av = make_float4(0.f,0.f,0.f,0.f);
    int gr = row0 + arow, gk = k0 + acol;
    if (gr < M){
      if (CONCAT){
        if (gk < K1) av = *reinterpret_cast<const float4*>(&A [(size_t)gr*K1 + gk]);
        else         av = *reinterpret_cast<const float4*>(&A2[(size_t)gr*K2 + (gk-K1)]);
      } else {
        av = *reinterpret_cast<const float4*>(&A[(size_t)gr*K + gk]);
      }
    }
    As[acol+0][arow]=av.x; As[acol+1][arow]=av.y; As[acol+2][arow]=av.z; As[acol+3][arow]=av.w;
    float4 bv = *reinterpret_cast<const float4*>(&B[(size_t)(k0+brow)*N + col0 + bcol]);
    *reinterpret_cast<float4*>(&Bs[brow][bcol]) = bv;
    __syncthreads();
    #pragma unroll
    for (int kk=0; kk<8; ++kk){
      float a[8], b[8];
      *(float4*)&a[0] = *(float4*)&As[kk][ty*8];
      *(float4*)&a[4] = *(float4*)&As[kk][ty*8+4];
      *(float4*)&b[0] = *(float4*)&Bs[kk][tx*8];
      *(float4*)&b[4] = *(float4*)&Bs[kk][tx*8+4];
      #pragma unroll
      for (int i=0;i<8;i++)
        #pragma unroll
        for (int j=0;j<8;j++) acc[i][j] = fmaf(a[i], b[j], acc[i][j]);
    }
    __syncthreads();
  }
  #pragma unroll
  for (int i=0;i<8;i++){
    int r = row0 + ty*8 + i;
    if (r >= M) continue;
    #pragma unroll
    for (int j4=0;j4<2;j4++){
      int c = col0 + tx*8 + j4*4;
      float4 v = make_float4(acc[i][j4*4], acc[i][j4*4+1], acc[i][j4*4+2], acc[i][j4*4+3]);
      if (bias){
        float4 bb = *reinterpret_cast<const float4*>(&bias[c]);
        v = f4add(v, bb);
      }
      if (ACT == 1){
        v.x=fmaxf(v.x,0.f); v.y=fmaxf(v.y,0.f); v.z=fmaxf(v.z,0.f); v.w=fmaxf(v.w,0.f);
      }
      *reinterpret_cast<float4*>(&C[(size_t)r*N + c]) = v;
    }
  }
}

// ---------------- GCN aggregation (intra-CSR: only intra-cluster edges) ----------------
__global__ __launch_bounds__(256) void k_gcn(const unsigned short* __restrict__ XWh, const int* __restrict__ ioffs,
                      const int* __restrict__ csr2, const int* __restrict__ intra,
                      const float* __restrict__ gcn_b, float* __restrict__ Xc)
{
  int wid  = (blockIdx.x*blockDim.x + threadIdx.x) >> 6;
  int lane = threadIdx.x & 63;
  int nw   = (gridDim.x*blockDim.x) >> 6;
  for (int n = wid; n < NNODES; n += nw){
    int cntn = intra[n];
    float deg = 1.f + (float)cntn;
    float dinv_n = rsqrtf(deg);
    __half2 hx = *reinterpret_cast<const __half2*>(XWh + (size_t)n*128 + lane*2);
    float2 acc;
    acc.x = __low2float(hx)/deg; acc.y = __high2float(hx)/deg;
    int io0 = ioffs[n];
    for (int j=0; j<cntn; ++j){
      int s = csr2[io0+j];
      float w = dinv_n * rsqrtf(1.f + (float)intra[s]);
      __half2 hs = *reinterpret_cast<const __half2*>(XWh + (size_t)s*128 + lane*2);
      acc.x = fmaf(w, __low2float(hs), acc.x);
      acc.y = fmaf(w, __high2float(hs), acc.y);
    }
    float2 bb = *reinterpret_cast<const float2*>(&gcn_b[lane*2]);
    acc.x += bb.x; acc.y += bb.y;
    *reinterpret_cast<float2*>(&Xc[(size_t)n*128 + lane*2]) = acc;
  }
}

// ---------------- cluster pooling: LDS partials + reduce ----------------
__global__ __launch_bounds__(256) void k_pool1(const float* __restrict__ Xc, const int* __restrict__ clus,
                                               float* __restrict__ part){
  __shared__ float lp[8192];
  for (int i=threadIdx.x; i<8192; i+=256) lp[i]=0.f;
  __syncthreads();
  int d = threadIdx.x & 127, rg = threadIdx.x >> 7;
  int n0 = blockIdx.x*200;
  for (int n = n0+rg; n < n0+200; n += 2){
    int c = clus[n];
    atomicAdd(&lp[c*128 + d], Xc[(size_t)n*128 + d]);
  }
  __syncthreads();
  for (int i=threadIdx.x; i<8192; i+=256) part[(size_t)blockIdx.x*8192 + i] = lp[i];
}
__global__ __launch_bounds__(256) void k_pool2(const float* __restrict__ part, const int* __restrict__ csize,
                                               float* __restrict__ pooled){
  int i = blockIdx.x*256 + threadIdx.x; // 8192
  float s = 0.f;
  for (int b=0;b<400;b++) s += part[(size_t)b*8192 + i];
  pooled[i] = s / fmaxf((float)csize[i>>7], 1.f);
}

// ---------------- cluster GAT small kernels fused: block0=asc, block1=loop_c ----------------
__global__ __launch_bounds__(256) void k_cluster_small(const float* __restrict__ xh_c,
                     const float* __restrict__ g_att_s, const float* __restrict__ g_att_d,
                     float* __restrict__ a_s_c, float* __restrict__ a_d_c,
                     const float* __restrict__ pair_cnt, const float* __restrict__ avg_attr,
                     float* __restrict__ loop_c){
  int t = threadIdx.x;
  if (blockIdx.x == 0){
    int s = t >> 2, h = t & 3;
    float ss=0.f, sd=0.f;
    for (int c=0;c<128;c++){
      float x = xh_c[s*512 + h*128 + c];
      ss += x * g_att_s[h*128 + c];
      sd += x * g_att_d[h*128 + c];
    }
    a_s_c[s*4+h] = ss; a_d_c[s*4+h] = sd;
  } else {
    if (t >= NCLUS) return;
    int d = t;
    float ic=0.f, l0=0.f, l1=0.f;
    for (int s=0;s<NCLUS;s++){
      int k = s*NCLUS + d;
      if (pair_cnt[k] > 0.f){ ic += 1.f; l0 += avg_attr[2*k]; l1 += avg_attr[2*k+1]; }
    }
    float inv = 1.f / fmaxf(ic, 1.f);
    loop_c[2*d] = l0*inv; loop_c[2*d+1] = l1*inv;
  }
}

__global__ __launch_bounds__(128) void k_clout(const float* __restrict__ a_s_c, const float* __restrict__ a_d_c,
                       const float* __restrict__ loop_c, const float* __restrict__ M2g,
                       const float* __restrict__ pair_cnt, const float* __restrict__ avg_attr,
                       const float* __restrict__ xh_c, const float* __restrict__ g_bias,
                       float* __restrict__ cl_out)
{
  int d = blockIdx.x;
  __shared__ float p[NCLUS*4];
  int t = threadIdx.x;
  if (t < NCLUS){
    int s = t;
    for (int h=0; h<4; ++h){
      float v;
      if (s == d){
        v = lrelu(a_s_c[d*4+h] + a_d_c[d*4+h] + loop_c[2*d]*M2g[h] + loop_c[2*d+1]*M2g[4+h]);
      } else if (pair_cnt[s*NCLUS+d] > 0.f){
        int k = s*NCLUS + d;
        v = lrelu(a_s_c[s*4+h] + a_d_c[d*4+h] + avg_attr[2*k]*M2g[h] + avg_attr[2*k+1]*M2g[4+h]);
      } else {
        v = -INFINITY;
      }
      p[s*4+h] = v;
    }
  }
  __syncthreads();
  if (t < 4){
    int h = t;
    float m = -INFINITY;
    for (int s=0;s<NCLUS;s++) m = fmaxf(m, p[s*4+h]);
    float sum = 0.f;
    for (int s=0;s<NCLUS;s++){
      float a = p[s*4+h];
      float e = (a == -INFINITY) ? 0.f : expf(a - m);
      p[s*4+h] = e; sum += e;
    }
    float inv = 1.f/sum;
    for (int s=0;s<NCLUS;s++) p[s*4+h] *= inv;
  }
  __syncthreads();
  int c = t;
  float acc = 0.f;
  for (int s=0;s<NCLUS;s++){
    #pragma unroll
    for (int h=0;h<4;h++) acc += p[s*4+h]*xh_c[s*512 + h*128 + c];
  }
  cl_out[d*128 + c] = 0.25f*acc + g_bias[c];
}

// Xcomb = Xc + cl_out[clus]; write f16 X + fused a_s/a_d dots (layer 0)
__global__ __launch_bounds__(256) void k_xcomb(const float* __restrict__ Xc, const float* __restrict__ cl_out,
                                               const int* __restrict__ clus, __half* __restrict__ xh16,
                                               const float* __restrict__ AsA, const float* __restrict__ AdA,
                                               float* __restrict__ a_s, float* __restrict__ a_d){
  int i = blockIdx.x*256 + threadIdx.x;
  int stride = gridDim.x*256;
  for (; i < NNODES*32; i += stride){
    int n = i >> 5, d4 = i & 31;
    float4 a = ((const float4*)Xc)[i];
    float4 b = ((const float4*)&cl_out[clus[n]*128])[d4];
    float4 r = f4add(a, b);
    __half2 hv[2];
    hv[0] = __floats2half2_rn(r.x, r.y);
    hv[1] = __floats2half2_rn(r.z, r.w);
    ((uint2*)xh16)[i] = *reinterpret_cast<uint2*>(hv);
    float4 ps = make_float4(0,0,0,0), pd = make_float4(0,0,0,0);
    const float4* As4 = (const float4*)(AsA) + d4*4;
    const float4* Ad4 = (const float4*)(AdA) + d4*4;
    ps = f4fma1(r.x, As4[0], ps); ps = f4fma1(r.y, As4[1], ps);
    ps = f4fma1(r.z, As4[2], ps); ps = f4fma1(r.w, As4[3], ps);
    pd = f4fma1(r.x, Ad4[0], pd); pd = f4fma1(r.y, Ad4[1], pd);
    pd = f4fma1(r.z, Ad4[2], pd); pd = f4fma1(r.w, Ad4[3], pd);
    #pragma unroll
    for (int m=16; m>=1; m>>=1){
      ps.x += __shfl_xor(ps.x, m); ps.y += __shfl_xor(ps.y, m);
      ps.z += __shfl_xor(ps.z, m); ps.w += __shfl_xor(ps.w, m);
      pd.x += __shfl_xor(pd.x, m); pd.y += __shfl_xor(pd.y, m);
      pd.z += __shfl_xor(pd.z, m); pd.w += __shfl_xor(pd.w, m);
    }
    if (d4 == 0){
      *reinterpret_cast<float4*>(&a_s[n*4]) = ps;
      *reinterpret_cast<float4*>(&a_d[n*4]) = pd;
    }
  }
}

// ---------------- GAT aggregation in X-space (f16 X gather, full 2-deep prefetch of all operands) ----------------
__global__ __launch_bounds__(256) void k_gat_x(const __half* __restrict__ Xh, const float* __restrict__ a_s,
                     const float* __restrict__ a_d, const float* __restrict__ eattr,
                     const int* __restrict__ offs, const int2* __restrict__ csr,
                     const float* __restrict__ la, const float* __restrict__ M2l,
                     unsigned short* __restrict__ agg)
{
  int wid  = (blockIdx.x*blockDim.x + threadIdx.x) >> 6;
  int lane = threadIdx.x & 63;
  int nw   = (gridDim.x*blockDim.x) >> 6;
  int h = lane >> 4;
  int kslot = (lane & 15)*8;
  float m2a = M2l[h], m2b = M2l[4+h];
  for (int n = wid; n < NNODES; n += nw){
    float asn = a_s[n*4+h];
    float adn = a_d[n*4+h];
    float al = lrelu(asn + adn + la[2*n]*m2a + la[2*n+1]*m2b);
    float pl = __expf(al);
    float denom = pl;
    uint4 u0 = *reinterpret_cast<const uint4*>(Xh + (size_t)n*128 + kslot);
    __half2* x0 = reinterpret_cast<__half2*>(&u0);
    __half2 pl2 = __float2half2_rn(pl);
    __half2 acc0 = __hmul2(x0[0], pl2), acc1 = __hmul2(x0[1], pl2);
    __half2 acc2 = __hmul2(x0[2], pl2), acc3 = __hmul2(x0[3], pl2);
    int b0 = offs[n], b1 = offs[n+1];
    int2 seA = make_int2(0,0), seB = make_int2(0,0);
    uint4 uA = make_uint4(0,0,0,0), uB = make_uint4(0,0,0,0);
    float asA = 0.f, asB = 0.f;
    float2 eaA = make_float2(0.f,0.f), eaB = make_float2(0.f,0.f);
    if (b0 < b1){
      seA = csr[b0];
      uA  = *reinterpret_cast<const uint4*>(Xh + (size_t)seA.x*128 + kslot);
      asA = a_s[seA.x*4+h];
      eaA = *reinterpret_cast<const float2*>(&eattr[2*seA.y]);
    }
    if (b0+1 < b1){
      seB = csr[b0+1];
      uB  = *reinterpret_cast<const uint4*>(Xh + (size_t)seB.x*128 + kslot);
      asB = a_s[seB.x*4+h];
      eaB = *reinterpret_cast<const float2*>(&eattr[2*seB.y]);
    }
    for (int idx=b0; idx<b1; ++idx){
      uint4 u = uA; float asv = asA; float2 ea = eaA;
      seA = seB; uA = uB; asA = asB; eaA = eaB;
      if (idx+2 < b1){
        seB = csr[idx+2];
        uB  = *reinterpret_cast<const uint4*>(Xh + (size_t)seB.x*128 + kslot);
        asB = a_s[seB.x*4+h];
        eaB = *reinterpret_cast<const float2*>(&eattr[2*seB.y]);
      }
      float pe = __expf(lrelu(asv + adn + ea.x*m2a + ea.y*m2b));
      denom += pe;
      __half2 pe2 = __float2half2_rn(pe);
      __half2* y = reinterpret_cast<__half2*>(&u);
      acc0 = __hfma2(y[0], pe2, acc0);
      acc1 = __hfma2(y[1], pe2, acc1);
      acc2 = __hfma2(y[2], pe2, acc2);
      acc3 = __hfma2(y[3], pe2, acc3);
    }
    float sc = 1.f/denom;   // 0.25 mean folded into glt2
    uint4 w;
    w.x = pk2(__low2float(acc0)*sc, __high2float(acc0)*sc);
    w.y = pk2(__low2float(acc1)*sc, __high2float(acc1)*sc);
    w.z = pk2(__low2float(acc2)*sc, __high2float(acc2)*sc);
    w.w = pk2(__low2float(acc3)*sc, __high2float(acc3)*sc);
    *reinterpret_cast<uint4*>(agg + (size_t)n*512 + h*128 + kslot) = w;
  }
}

// ---------------- graph norm: colstat + finstat fused (threadfence last-block pattern) ----------------
__global__ __launch_bounds__(256) void k_colstat_fin(const __half* __restrict__ X, float* __restrict__ part,
                         int* __restrict__ counter,
                         const float* __restrict__ w, const float* __restrict__ b, const float* __restrict__ ms,
                         float* __restrict__ scaleA, float* __restrict__ shiftB){
  int d = threadIdx.x & 127;
  int rg = threadIdx.x >> 7;
  float s1=0.f, s2=0.f;
  for (int n = blockIdx.x*2 + rg; n < NNODES; n += 512){
    float v = __half2float(X[(size_t)n*128 + d]);
    s1 += v; s2 = fmaf(v, v, s2);
  }
  __shared__ float sh[512];
  sh[threadIdx.x] = s1; sh[256+threadIdx.x] = s2;
  __syncthreads();
  if (threadIdx.x < 128){
    s1 = sh[threadIdx.x] + sh[threadIdx.x+128];
    s2 = sh[256+threadIdx.x] + sh[256+threadIdx.x+128];
    part[blockIdx.x*256 + d]       = s1;
    part[blockIdx.x*256 + 128 + d] = s2;
  }
  __threadfence();
  __syncthreads();
  __shared__ int isLast;
  if (threadIdx.x == 0){
    int done = atomicAdd(counter, 1);
    isLast = (done == 255);
  }
  __syncthreads();
  if (isLast){
    __threadfence();
    if (threadIdx.x < 128){
      int dd = threadIdx.x;
      float t1=0.f, t2=0.f;
      for (int bq=0; bq<256; bq++){ t1 += part[bq*256 + dd]; t2 += part[bq*256 + 128 + dd]; }
      float mean = t1 * (1.f/NNODES);
      float ex2  = t2 * (1.f/NNODES);
      float m = ms[dd];
      float var = ex2 - m*mean*mean*(2.f - m);
      float sc = w[dd] * rsqrtf(var + EPSV);
      scaleA[dd] = sc;
      shiftB[dd] = b[dd] - sc*m*mean;
    }
    if (threadIdx.x == 0) *counter = 0;
  }
}

// norm + residual(f16) + ELU; write f16 X + fused next-layer a_s/a_d (or f32 final output)
__global__ __launch_bounds__(256) void k_normelu(const __half* __restrict__ o, __half* __restrict__ xh16,
                         const float* __restrict__ scaleA, const float* __restrict__ shiftB,
                         const float* __restrict__ AsA, const float* __restrict__ AdA,
                         float* __restrict__ a_s, float* __restrict__ a_d,
                         float* __restrict__ fout){
  int i = blockIdx.x*256 + threadIdx.x;
  int stride = gridDim.x*256;
  for (; i < NNODES*32; i += stride){
    int n = i >> 5, d4 = i & 31;
    uint2 ou = ((const uint2*)o)[i];
    __half2* oh = reinterpret_cast<__half2*>(&ou);
    float o0 = __low2float(oh[0]), o1 = __high2float(oh[0]);
    float o2 = __low2float(oh[1]), o3 = __high2float(oh[1]);
    uint2 xu = ((const uint2*)xh16)[i];
    __half2* xh = reinterpret_cast<__half2*>(&xu);
    float xi0 = __low2float(xh[0]), xi1 = __high2float(xh[0]);
    float xi2 = __low2float(xh[1]), xi3 = __high2float(xh[1]);
    float4 sc = ((const float4*)scaleA)[d4];
    float4 sh = ((const float4*)shiftB)[d4];
    float4 r; float y;
    y = fmaf(sc.x, o0, sh.x) + xi0; r.x = y > 0.f ? y : expm1f(y);
    y = fmaf(sc.y, o1, sh.y) + xi1; r.y = y > 0.f ? y : expm1f(y);
    y = fmaf(sc.z, o2, sh.z) + xi2; r.z = y > 0.f ? y : expm1f(y);
    y = fmaf(sc.w, o3, sh.w) + xi3; r.w = y > 0.f ? y : expm1f(y);
    if (fout){
      ((float4*)fout)[i] = r;
    } else {
      __half2 hv[2];
      hv[0] = __floats2half2_rn(r.x, r.y);
      hv[1] = __floats2half2_rn(r.z, r.w);
      ((uint2*)xh16)[i] = *reinterpret_cast<uint2*>(hv);
      float4 ps = make_float4(0,0,0,0), pd = make_float4(0,0,0,0);
      const float4* As4 = (const float4*)(AsA) + d4*4;
      const float4* Ad4 = (const float4*)(AdA) + d4*4;
      ps = f4fma1(r.x, As4[0], ps); ps = f4fma1(r.y, As4[1], ps);
      ps = f4fma1(r.z, As4[2], ps); ps = f4fma1(r.w, As4[3], ps);
      pd = f4fma1(r.x, Ad4[0], pd); pd = f4fma1(r.y, Ad4[1], pd);
      pd = f4fma1(r.z, Ad4[2], pd); pd = f4fma1(r.w, Ad4[3], pd);
      #pragma unroll
      for (int m=16; m>=1; m>>=1){
        ps.x += __shfl_xor(ps.x, m); ps.y += __shfl_xor(ps.y, m);
        ps.z += __shfl_xor(ps.z, m); ps.w += __shfl_xor(ps.w, m);
        pd.x += __shfl_xor(pd.x, m); pd.y += __shfl_xor(pd.y, m);
        pd.z += __shfl_xor(pd.z, m); pd.w += __shfl_xor(pd.w, m);
      }
      if (d4 == 0){
        *reinterpret_cast<float4*>(&a_s[n*4]) = ps;
        *reinterpret_cast<float4*>(&a_d[n*4]) = pd;
      }
    }
  }
}

// ---------------- host launch ----------------
extern "C" void kernel_launch(void* const* d_in, const int* in_sizes, int n_in,
                              void* d_out, int out_size, void* d_ws, size_t ws_size,
                              hipStream_t stream)
{
  const float* extra    = (const float*)d_in[0];
  const int*   ei       = (const int*)  d_in[1];
  const float* eattr    = (const float*)d_in[2];
  const int*   clus     = (const int*)  d_in[3];
  const float* user     = (const float*)d_in[4];
  const float* item     = (const float*)d_in[5];
  const float* W1       = (const float*)d_in[6];
  const float* b1       = (const float*)d_in[7];
  const float* W2       = (const float*)d_in[8];
  const float* b2       = (const float*)d_in[9];
  const float* gcnW     = (const float*)d_in[10];
  const float* gcnb     = (const float*)d_in[11];
  const float* g_lin    = (const float*)d_in[12];
  const float* g_lin_e  = (const float*)d_in[13];
  const float* g_att_s  = (const float*)d_in[14];
  const float* g_att_d  = (const float*)d_in[15];
  const float* g_att_e  = (const float*)d_in[16];
  const float* g_bias   = (const float*)d_in[17];
  const float* gat_lin  = (const float*)d_in[18];
  const float* gat_lin_e= (const float*)d_in[19];
  const float* gat_att_s= (const float*)d_in[20];
  const float* gat_att_d= (const float*)d_in[21];
  const float* gat_att_e= (const float*)d_in[22];
  const float* gat_bias = (const float*)d_in[23];
  const float* nw_      = (const float*)d_in[24];
  const float* nb_      = (const float*)d_in[25];
  const float* nms_     = (const float*)d_in[26];

  char* ws = (char*)d_ws;
  size_t off = 0;
  auto alloc = [&](size_t bytes)->char*{
    char* p = ws + off;
    off += (bytes + 255) & ~size_t(255);
    return p;
  };

  float* bufX = (float*)alloc((size_t)NNODES*128*4);
  float* bufY = (float*)alloc((size_t)NNODES*128*4);
  float* bufZ = (float*)alloc((size_t)NNODES*128*4);
  char* big = alloc((size_t)112*1024*1024);
  __half* Xh16          = (__half*)big;
  unsigned short* agg   = (unsigned short*)(big + (size_t)22*1024*1024);
  unsigned short* Hbf   = (unsigned short*)(big + (size_t)22*1024*1024);
  float* pcb  = (float*)(big + (size_t)22*1024*1024);
  float* pa0b = pcb  + 4096*128;
  float* pa1b = pa0b + 4096*128;
  float* ppart = (float*)(big + (size_t)40*1024*1024);
  int* offs   = (int*)alloc((NNODES+1)*4);
  int* ioffs  = (int*)alloc((NNODES+1)*4);
  int* bsum   = (int*)alloc(1024*4);
  int* bsum2  = (int*)alloc(1024*4);
  int2* csr   = (int2*)alloc((size_t)NEDGES*8);
  int* csr2   = (int*)alloc((size_t)NEDGES*4);
  float* a_s  = (float*)alloc((size_t)NNODES*4*4);
  float* a_d  = (float*)alloc((size_t)NNODES*4*4);
  float* la   = (float*)alloc((size_t)NNODES*2*4);
  // zeroed-per-call region (single memset)
  char* zero0 = ws + off;
  int*   cnt      = (int*)  alloc((size_t)NNODES*4);
  int*   intra    = (int*)  alloc((size_t)NNODES*4);
  int*   cursor   = (int*)  alloc((size_t)NNODES*4);
  int*   cursor2  = (int*)  alloc((size_t)NNODES*4);
  int*   csize    = (int*)  alloc(256*4);
  int*   lcounter = (int*)  alloc(256);
  size_t zbytes = (size_t)((ws + off) - zero0);
  // small buffers
  float* pooled= (float*)alloc(8192*4);
  float* M2g   = (float*)alloc(8*4);
  float* M2    = (float*)alloc(24*4);
  float* AsAll = (float*)alloc(3*512*4);
  float* AdAll = (float*)alloc(3*512*4);
  float* pair_cnt = (float*)alloc(4096*4);
  float* avg_attr = (float*)alloc(8192*4);
  float* loop_c   = (float*)alloc(128*4);
  float* xh_c     = (float*)alloc(64*512*4);
  float* a_s_c    = (float*)alloc(256*4);
  float* a_d_c    = (float*)alloc(256*4);
  float* cl_out   = (float*)alloc(64*128*4);
  float* colpart  = (float*)alloc(256*256*4);
  float* scaleA   = (float*)alloc(128*4);
  float* shiftB   = (float*)alloc(128*4);
  unsigned short* W1t  = (unsigned short*)alloc((size_t)896*256*2);
  unsigned short* W2t  = (unsigned short*)alloc((size_t)256*128*2);
  unsigned short* gcnWt= (unsigned short*)alloc((size_t)128*128*2);
  unsigned short* glt2 = (unsigned short*)alloc((size_t)3*128*512*2);
  if (off > ws_size) return;

  hipMemsetAsync(zero0, 0, zbytes, stream);

  const int NB = (NNODES+255)/256;
  // phase 0: pair hist + cnt/intra, reduce; fused dual scans (LDS csize); fill; gather la
  k_pairhist<<<128, 1024, 0, stream>>>(ei, eattr, clus, cnt, intra, pcb, pa0b, pa1b);
  k_pairreduce<<<64, 64, 0, stream>>>(pcb, pa0b, pa1b, pair_cnt, avg_attr);
  k_scan_block2<<<NB, 256, 0, stream>>>(cnt, intra, offs, ioffs, bsum, bsum2, NNODES, clus, csize);
  k_scan_bsum2<<<2, 512, 0, stream>>>(bsum, bsum2, NB);
  {
    dim3 ga(NB, 2);
    k_scan_add2<<<ga, 256, 0, stream>>>(offs, ioffs, bsum, bsum2, NNODES, NEDGES, 0);
  }
  k_fill_csr<<<(NEDGES+255)/256, 256, 0, stream>>>(ei, clus, offs, ioffs, cursor, cursor2, csr, csr2);
  k_loopattr<<<NB, 256, 0, stream>>>(offs, csr, eattr, la);

  // weight conversions + glt2 + AsAll/AdAll + M2 (one kernel)
  k_wtall_m2<<<1869, 256, 0, stream>>>(W1, W2, gcnW, gat_lin, W1t, W2t, gcnWt, glt2,
                                       gat_att_s, gat_att_d, AsAll, AdAll,
                                       g_lin_e, g_att_e, gat_lin_e, gat_att_e, M2g, M2);

  // enrichment MLP (bf16 MFMA, f32-A fused conversion); Hbf reuses dead pairhist region
  {
    dim3 g1((N_ITEMS+127)/128, 2);
    k_mgemm<1,1,1,1,1><<<g1, 256, 0, stream>>>((const void*)item, extra, W1t, b1, (void*)Hbf,
                                               N_ITEMS, 256, 896, 128);
    dim3 g2((N_ITEMS+127)/128, 1);
    k_mgemm<0,0,0,0,1><<<g2, 256, 0, stream>>>((const void*)Hbf, nullptr, W2t, b2,
                                               (void*)(bufX + (size_t)N_USERS*128),
                                               N_ITEMS, 128, 256, 0);
  }
  hipMemcpyAsync(bufX, user, (size_t)N_USERS*128*4, hipMemcpyDeviceToDevice, stream);

  // cluster GCN: XW (f16) = X @ gcnW; aggregate over intra-CSR only
  {
    dim3 g3((NNODES+127)/128, 1);
    k_mgemm<1,0,2,0,0><<<g3, 256, 0, stream>>>((const void*)bufX, nullptr, gcnWt, nullptr, (void*)bufY,
                                               NNODES, 128, 128, 0);
  }
  k_gcn<<<5000, 256, 0, stream>>>((const unsigned short*)bufY, ioffs, csr2, intra, gcnb, bufZ);

  // pooling (LDS partials) + cluster GAT
  k_pool1<<<400, 256, 0, stream>>>(bufZ, clus, ppart);
  k_pool2<<<32, 256, 0, stream>>>(ppart, csize, pooled);
  {
    dim3 g4(1, 4);
    k_sgemm<0,0><<<g4, 256, 0, stream>>>(pooled, nullptr, g_lin, nullptr, xh_c, 64, 512, 128, 0);
  }
  k_cluster_small<<<2, 256, 0, stream>>>(xh_c, g_att_s, g_att_d, a_s_c, a_d_c, pair_cnt, avg_attr, loop_c);
  k_clout<<<64, 128, 0, stream>>>(a_s_c, a_d_c, loop_c, M2g, pair_cnt, avg_attr, xh_c, g_bias, cl_out);
  k_xcomb<<<1280, 256, 0, stream>>>(bufZ, cl_out, clus, Xh16, AsAll, AdAll, a_s, a_d);

  // 3 GAT layers: k_gat_x (fused logits, X-space agg) -> tall-skinny agg @ glt2 GEMM
  for (int l = 0; l < 3; ++l){
    k_gat_x<<<20000, 256, 0, stream>>>(Xh16, a_s, a_d, eattr, offs, csr, la, M2 + l*8, agg);
    k_mgemm64<<<(NNODES+63)/64, 256, 0, stream>>>(agg, glt2 + (size_t)l*65536,
                                                  gat_bias + l*128, (__half*)bufY, NNODES, 512);
    k_colstat_fin<<<256, 256, 0, stream>>>((const __half*)bufY, colpart, lcounter,
                                           nw_ + l*128, nb_ + l*128, nms_ + l*128, scaleA, shiftB);
    k_normelu<<<1280, 256, 0, stream>>>((const __half*)bufY, Xh16, scaleA, shiftB,
                                        AsAll + (l+1 < 3 ? (l+1)*512 : 0),
                                        AdAll + (l+1 < 3 ? (l+1)*512 : 0),
                                        a_s, a_d,
                                        (l==2) ? (float*)d_out : nullptr);
  }
}

// Round 20
// 1264.997 us; speedup vs baseline: 1.0093x; 1.0093x over previous
//
#include <hip/hip_runtime.h>
#include <hip/hip_fp16.h>
#include <math.h>

#define N_USERS 50000
#define N_ITEMS 30000
#define NNODES  80000
#define NEDGES  640000
#define NCLUS   64
#define NEG     0.2f
#define EPSV    1e-5f

typedef __attribute__((ext_vector_type(8))) short bf16x8;
typedef __attribute__((ext_vector_type(4))) float f32x4;

__device__ __forceinline__ float lrelu(float x){ return x > 0.f ? x : NEG*x; }

__device__ __forceinline__ unsigned short f2bf(float f){
  unsigned u = __float_as_uint(f);
  u += 0x7fffu + ((u>>16)&1u);
  return (unsigned short)(u>>16);
}
__device__ __forceinline__ unsigned pk2(float lo, float hi){
  return (unsigned)f2bf(lo) | ((unsigned)f2bf(hi) << 16);
}
__device__ __forceinline__ float4 f4add(float4 a, float4 b){
  return make_float4(a.x+b.x, a.y+b.y, a.z+b.z, a.w+b.w);
}
__device__ __forceinline__ float4 f4fma1(float s, float4 a, float4 b){
  return make_float4(fmaf(s,a.x,b.x), fmaf(s,a.y,b.y), fmaf(s,a.z,b.z), fmaf(s,a.w,b.w));
}

// ---------------- phase 0: pair histogram (LDS-aggregated, 1024-thread blocks) ----------------
__global__ __launch_bounds__(1024) void k_pairhist(
    const int* __restrict__ ei, const float* __restrict__ eattr, const int* __restrict__ clus,
    int* __restrict__ cnt, int* __restrict__ intra,
    float* __restrict__ pcb, float* __restrict__ pa0b, float* __restrict__ pa1b)
{
  __shared__ float pc[4096];
  __shared__ float pa0[4096];
  __shared__ float pa1[4096];
  for (int i=threadIdx.x; i<4096; i+=1024){ pc[i]=0.f; pa0[i]=0.f; pa1[i]=0.f; }
  __syncthreads();
  for (int e = blockIdx.x*1024 + threadIdx.x; e < NEDGES; e += 128*1024){
    int s = ei[e], d = ei[NEDGES+e];
    int cu = clus[s], cv = clus[d];
    atomicAdd(&cnt[d], 1);
    if (cu == cv) { atomicAdd(&intra[d], 1); }
    else {
      float2 a = *reinterpret_cast<const float2*>(&eattr[2*e]);
      int k = cu*NCLUS + cv;
      atomicAdd(&pc[k], 1.f);
      atomicAdd(&pa0[k], a.x);
      atomicAdd(&pa1[k], a.y);
    }
  }
  __syncthreads();
  int b = blockIdx.x;
  for (int i=threadIdx.x; i<4096; i+=1024){
    pcb [i*128 + b] = pc[i];
    pa0b[i*128 + b] = pa0[i];
    pa1b[i*128 + b] = pa1[i];
  }
}

__global__ __launch_bounds__(64) void k_pairreduce(
    const float* __restrict__ pcb, const float* __restrict__ pa0b, const float* __restrict__ pa1b,
    float* __restrict__ pair_cnt, float* __restrict__ avg_attr)
{
  int i = blockIdx.x*64 + threadIdx.x;  // 4096 total over grid 64
  float c=0.f, s0=0.f, s1=0.f;
  const float4* P0 = (const float4*)(pcb  + (size_t)i*128);
  const float4* P1 = (const float4*)(pa0b + (size_t)i*128);
  const float4* P2 = (const float4*)(pa1b + (size_t)i*128);
  for (int b=0;b<32;b++){
    float4 v0=P0[b], v1=P1[b], v2=P2[b];
    c  += v0.x+v0.y+v0.z+v0.w;
    s0 += v1.x+v1.y+v1.z+v1.w;
    s1 += v2.x+v2.y+v2.z+v2.w;
  }
  pair_cnt[i] = c;
  float inv = 1.f/fmaxf(c, 1.f);
  avg_attr[2*i]   = s0*inv;
  avg_attr[2*i+1] = s1*inv;
}

// dual scan: cnt->offs and intra->ioffs, one launch; csize histogram LDS-aggregated
__global__ __launch_bounds__(256) void k_scan_block2(const int* __restrict__ in1, const int* __restrict__ in2,
                                                     int* __restrict__ out1, int* __restrict__ out2,
                                                     int* __restrict__ bsum1, int* __restrict__ bsum2, int n,
                                                     const int* __restrict__ clus, int* __restrict__ csize){
  __shared__ int buf[256];
  __shared__ int lcs[NCLUS];
  int i = blockIdx.x*256 + threadIdx.x;
  if (threadIdx.x < NCLUS) lcs[threadIdx.x] = 0;
  __syncthreads();
  if (i < n) atomicAdd(&lcs[clus[i]], 1);
  int v = (i < n) ? in1[i] : 0;
  buf[threadIdx.x] = v; __syncthreads();
  for (int off=1; off<256; off<<=1){
    int t = (threadIdx.x>=off) ? buf[threadIdx.x-off] : 0;
    __syncthreads();
    buf[threadIdx.x] += t;
    __syncthreads();
  }
  if (i < n) out1[i] = buf[threadIdx.x] - v;
  if (threadIdx.x == 255) bsum1[blockIdx.x] = buf[255];
  __syncthreads();
  v = (i < n) ? in2[i] : 0;
  buf[threadIdx.x] = v; __syncthreads();
  for (int off=1; off<256; off<<=1){
    int t = (threadIdx.x>=off) ? buf[threadIdx.x-off] : 0;
    __syncthreads();
    buf[threadIdx.x] += t;
    __syncthreads();
  }
  if (i < n) out2[i] = buf[threadIdx.x] - v;
  if (threadIdx.x == 255) bsum2[blockIdx.x] = buf[255];
  __syncthreads();
  if (threadIdx.x < NCLUS){
    int c = lcs[threadIdx.x];
    if (c) atomicAdd(&csize[threadIdx.x], c);
  }
}

__global__ __launch_bounds__(512) void k_scan_bsum2(int* __restrict__ bsum1, int* __restrict__ bsum2, int nb){
  int* bs = blockIdx.x ? bsum2 : bsum1;
  __shared__ int buf[512];
  int v = (threadIdx.x < nb) ? bs[threadIdx.x] : 0;
  buf[threadIdx.x] = v; __syncthreads();
  for (int off=1; off<512; off<<=1){
    int t = (threadIdx.x>=off) ? buf[threadIdx.x-off] : 0;
    __syncthreads();
    buf[threadIdx.x] += t;
    __syncthreads();
  }
  if (threadIdx.x < nb) bs[threadIdx.x] = buf[threadIdx.x] - v;
}

__global__ __launch_bounds__(256) void k_scan_add2(int* __restrict__ out1, int* __restrict__ out2,
                                                   const int* __restrict__ bsum1, const int* __restrict__ bsum2,
                                                   int n, int total1, int total2){
  int* out = blockIdx.y ? out2 : out1;
  const int* bs = blockIdx.y ? bsum2 : bsum1;
  int total = blockIdx.y ? total2 : total1;
  int i = blockIdx.x*256 + threadIdx.x;
  if (i < n) out[i] += bs[i>>8];
  if (i == 0) out[n] = total;
}

// fill main CSR + intra CSR (no atomics on float data)
__global__ __launch_bounds__(256) void k_fill_csr(const int* __restrict__ ei, const int* __restrict__ clus,
                                                  const int* __restrict__ offs, const int* __restrict__ ioffs,
                                                  int* __restrict__ cursor, int* __restrict__ cursor2,
                                                  int2* __restrict__ csr, int* __restrict__ csr2){
  int e = blockIdx.x*256 + threadIdx.x;
  if (e >= NEDGES) return;
  int s = ei[e], d = ei[NEDGES+e];
  int pos = offs[d] + atomicAdd(&cursor[d], 1);
  csr[pos] = make_int2(s, e);
  if (clus[s] == clus[d]){
    int p2 = ioffs[d] + atomicAdd(&cursor2[d], 1);
    csr2[p2] = s;
  }
}

// per-node mean edge-attr (self-loop fill), from CSR
__global__ __launch_bounds__(256) void k_loopattr(const int* __restrict__ offs, const int2* __restrict__ csr,
                                                  const float* __restrict__ eattr, float* __restrict__ la){
  int n = blockIdx.x*256 + threadIdx.x;
  if (n >= NNODES) return;
  int b0 = offs[n], b1 = offs[n+1];
  float s0=0.f, s1=0.f;
  for (int i=b0; i<b1; ++i){
    int e = csr[i].y;
    float2 a = *reinterpret_cast<const float2*>(&eattr[2*e]);
    s0 += a.x; s1 += a.y;
  }
  float inv = 1.f/fmaxf((float)(b1-b0), 1.f);
  la[2*n] = s0*inv; la[2*n+1] = s1*inv;
}

// ---------------- weight converts + glt2(W' for agg GEMM) + AsAll/AdAll + M2, one kernel ----------------
__global__ __launch_bounds__(256) void k_wtall_m2(const float* __restrict__ W1, const float* __restrict__ W2,
                       const float* __restrict__ gcnW, const float* __restrict__ gat_lin,
                       unsigned short* __restrict__ W1t, unsigned short* __restrict__ W2t,
                       unsigned short* __restrict__ gcnWt, unsigned short* __restrict__ glt2,
                       const float* __restrict__ att_s, const float* __restrict__ att_d,
                       float* __restrict__ AsAll, float* __restrict__ AdAll,
                       const float* __restrict__ g_lin_e, const float* __restrict__ g_att_e,
                       const float* __restrict__ gat_lin_e, const float* __restrict__ gat_att_e,
                       float* __restrict__ M2g, float* __restrict__ M2){
  int i = blockIdx.x*256 + threadIdx.x;
  if (i < 229376){            // W1: K=896, N=256
    int n = i/896, k = i - n*896;
    W1t[i] = f2bf(W1[(size_t)k*256 + n]);
  } else if (i < 262144){     // W2: K=256, N=128
    int j = i - 229376; int n = j/256, k = j - n*256;
    W2t[j] = f2bf(W2[(size_t)k*128 + n]);
  } else if (i < 278528){     // gcnW: 128x128
    int j = i - 262144; int n = j/128, k = j - n*128;
    gcnWt[j] = f2bf(gcnW[(size_t)k*128 + n]);
  } else if (i < 475136){     // glt2: 3 x [128 d][512 hk]
    int j = i - 278528; int l = j >> 16; int r = j & 65535; int d = r >> 9; int hk = r & 511;
    glt2[j] = f2bf(0.25f * gat_lin[(size_t)l*65536 + (size_t)(hk & 127)*512 + (hk >> 7)*128 + d]);
  } else if (i < 478208){     // AsAll/AdAll: 3*128*4*2
    int j = i - 475136;
    int which = j & 1, h = (j >> 1) & 3, k = (j >> 3) & 127, l = j >> 10;
    const float* att = which ? att_d : att_s;
    float s = 0.f;
    for (int c=0;c<128;c++) s += gat_lin[(size_t)l*65536 + k*512 + h*128 + c] * att[l*512 + h*128 + c];
    float* dst = which ? AdAll : AsAll;
    dst[l*512 + k*4 + h] = s;
  } else if (i < 478240){     // M2 precompute
    int t = i - 478208;
    if (t < 8){
      int j = t >> 2, h = t & 3;
      float s = 0.f;
      for (int c=0;c<128;c++) s += g_lin_e[j*512 + h*128 + c] * g_att_e[h*128 + c];
      M2g[j*4+h] = s;
    } else {
      int u = t - 8; int l = u >> 3, j = (u >> 2) & 1, h = u & 3;
      float s = 0.f;
      for (int c=0;c<128;c++) s += gat_lin_e[l*1024 + j*512 + h*128 + c] * gat_att_e[l*512 + h*128 + c];
      M2[l*8 + j*4 + h] = s;
    }
  }
}

// ---------------- bf16 MFMA GEMM: C = act(A @ Bt^T + bias), 128x128 tile, prefetch-pipelined ----------------
template<int AF32, int CONCAT, int OUT, int RELU, int BIAS>
__global__ __launch_bounds__(256)
void k_mgemm(const void* __restrict__ Av, const float* __restrict__ A2,
             const unsigned short* __restrict__ Bt, const float* __restrict__ bias,
             void* __restrict__ Cv, int M, int N, int K, int K1)
{
  __shared__ unsigned short As[128*64];
  __shared__ unsigned short Bs[128*64];
  const int tid = threadIdx.x;
  const int lane = tid & 63, w = tid >> 6;
  const int row0 = blockIdx.x*128, col0 = blockIdx.y*128;
  const int wm = w >> 1, wn = w & 1;
  const int l15 = lane & 15, l4 = lane >> 4;
  f32x4 acc[4][4];
  #pragma unroll
  for (int i=0;i<4;i++)
    #pragma unroll
    for (int n=0;n<4;n++) acc[i][n] = (f32x4){0.f,0.f,0.f,0.f};

  const int rr0 = w*32 + (lane>>3);
  const int cA = lane & 7;

  uint4 ra[4], rb[4];
  float4 fa[4][2];

  auto load_tile = [&](int kt, uint4* raO, float4 (*faO)[2], uint4* rbO){
    #pragma unroll
    for (int i=0;i<4;i++){
      int rr = rr0 + i*8;
      int ga = row0 + rr; ga = (ga < M) ? ga : (M-1);
      int gb = col0 + rr; gb = (gb < N) ? gb : (N-1);
      int gk = kt + cA*8;
      if (AF32){
        const float* Af = (const float*)Av;
        const float* src;
        if (CONCAT && gk >= K1) src = A2 + (size_t)ga*(K-K1) + (gk - K1);
        else                    src = Af + (size_t)ga*(CONCAT ? K1 : K) + gk;
        faO[i][0] = ((const float4*)src)[0];
        faO[i][1] = ((const float4*)src)[1];
      } else {
        raO[i] = *reinterpret_cast<const uint4*>((const unsigned short*)Av + (size_t)ga*K + gk);
      }
      rbO[i] = *reinterpret_cast<const uint4*>(Bt + (size_t)gb*K + gk);
    }
  };

  load_tile(0, ra, fa, rb);

  for (int kt = 0; kt < K; kt += 64){
    __syncthreads();   // previous MFMA reads complete; LDS writable
    #pragma unroll
    for (int i=0;i<4;i++){
      int rr = rr0 + i*8;
      int ch = cA ^ (rr & 7);
      uint4 va;
      if (AF32){
        float4 f0 = fa[i][0], f1 = fa[i][1];
        va = make_uint4(pk2(f0.x,f0.y), pk2(f0.z,f0.w), pk2(f1.x,f1.y), pk2(f1.z,f1.w));
      } else {
        va = ra[i];
      }
      *reinterpret_cast<uint4*>(&As[rr*64 + ch*8]) = va;
      *reinterpret_cast<uint4*>(&Bs[rr*64 + ch*8]) = rb[i];
    }
    __syncthreads();
    // prefetch next K-tile BEFORE the MFMA block (hide global latency under MFMA)
    uint4 ra2[4], rb2[4];
    float4 fa2[4][2];
    if (kt + 64 < K) load_tile(kt + 64, ra2, fa2, rb2);
    #pragma unroll
    for (int k0=0;k0<2;k0++){
      bf16x8 af[4], bff[4];
      #pragma unroll
      for (int i=0;i<4;i++){
        int row = wm*64 + i*16 + l15;
        int ch = (k0*4 + l4) ^ (row & 7);
        af[i] = *reinterpret_cast<const bf16x8*>(&As[row*64 + ch*8]);
      }
      #pragma unroll
      for (int n=0;n<4;n++){
        int row = wn*64 + n*16 + l15;
        int ch = (k0*4 + l4) ^ (row & 7);
        bff[n] = *reinterpret_cast<const bf16x8*>(&Bs[row*64 + ch*8]);
      }
      #pragma unroll
      for (int i=0;i<4;i++)
        #pragma unroll
        for (int n=0;n<4;n++)
          acc[i][n] = __builtin_amdgcn_mfma_f32_16x16x32_bf16(af[i], bff[n], acc[i][n], 0, 0, 0);
    }
    #pragma unroll
    for (int i=0;i<4;i++){
      ra[i] = ra2[i]; rb[i] = rb2[i];
      fa[i][0] = fa2[i][0]; fa[i][1] = fa2[i][1];
    }
  }
  // C store
  #pragma unroll
  for (int i=0;i<4;i++){
    int rowb = row0 + wm*64 + i*16 + l4*4;
    #pragma unroll
    for (int n=0;n<4;n++){
      int col = col0 + wn*64 + n*16 + l15;
      float bv = BIAS ? bias[col] : 0.f;
      #pragma unroll
      for (int r=0;r<4;r++){
        int row = rowb + r;
        if (row < M){
          float y = acc[i][n][r] + bv;
          if (RELU) y = fmaxf(y, 0.f);
          if (OUT == 1)      ((unsigned short*)Cv)[(size_t)row*N + col] = f2bf(y);
          else if (OUT == 2) ((__half*)Cv)[(size_t)row*N + col] = __float2half(y);
          else               ((float*)Cv)[(size_t)row*N + col] = y;
        }
      }
    }
  }
}

// ---------------- f32 SGEMM (tiny pooled GEMM only) ----------------
template<int CONCAT, int ACT>
__global__ __launch_bounds__(256)
void k_sgemm(const float* __restrict__ A, const float* __restrict__ A2,
             const float* __restrict__ B, const float* __restrict__ bias,
             float* __restrict__ C, int M, int N, int K, int K1)
{
  __shared__ float As[8][128];
  __shared__ float Bs[8][128];
  int row0 = blockIdx.x*128, col0 = blockIdx.y*128;
  int tid = threadIdx.x;
  int tx = tid & 15, ty = tid >> 4;
  float acc[8][8];
  #pragma unroll
  for (int i=0;i<8;i++)
    #pragma unroll
    for (int j=0;j<8;j++) acc[i][j]=0.f;

  int arow = tid >> 1, acol = (tid & 1)*4;
  int brow = tid >> 5, bcol = (tid & 31)*4;
  int K2 = K - K1;

  for (int k0=0; k0<K; k0+=8){
    float4 av = make_float4(0.f,0.f,0.f,0.f);
    int gr = row0 + arow, gk = k0 + acol;
    if (gr < M){
      if (CONCAT){
        if (gk < K1) av = *reinterpret_cast<const float4*>(&A [(size_t)gr*K1 + gk]);
        else         av = *reinterpret_cast<const float4*>(&A2[(size_t)gr*K2 + (gk-K1)]);
      } else {
        av = *reinterpret_cast<const float4*>(&A[(size_t)gr*K + gk]);
      }
    }
    As[acol+0][arow]=av.x; As[acol+1][arow]=av.y; As[acol+2][arow]=av.z; As[acol+3][arow]=av.w;
    float4 bv = *reinterpret_cast<const float4*>(&B[(size_t)(k0+brow)*N + col0 + bcol]);
    *reinterpret_cast<float4*>(&Bs[brow][bcol]) = bv;
    __syncthreads();
    #pragma unroll
    for (int kk=0; kk<8; ++kk){
      float a[8], b[8];
      *(float4*)&a[0] = *(float4*)&As[kk][ty*8];
      *(float4*)&a[4] = *(float4*)&As[kk][ty*8+4];
      *(float4*)&b[0] = *(float4*)&Bs[kk][tx*8];
      *(float4*)&b[4] = *(float4*)&Bs[kk][tx*8+4];
      #pragma unroll
      for (int i=0;i<8;i++)
        #pragma unroll
        for (int j=0;j<8;j++) acc[i][j] = fmaf(a[i], b[j], acc[i][j]);
    }
    __syncthreads();
  }
  #pragma unroll
  for (int i=0;i<8;i++){
    int r = row0 + ty*8 + i;
    if (r >= M) continue;
    #pragma unroll
    for (int j4=0;j4<2;j4++){
      int c = col0 + tx*8 + j4*4;
      float4 v = make_float4(acc[i][j4*4], acc[i][j4*4+1], acc[i][j4*4+2], acc[i][j4*4+3]);
      if (bias){
        float4 bb = *reinterpret_cast<const float4*>(&bias[c]);
        v = f4add(v, bb);
      }
      if (ACT == 1){
        v.x=fmaxf(v.x,0.f); v.y=fmaxf(v.y,0.f); v.z=fmaxf(v.z,0.f); v.w=fmaxf(v.w,0.f);
      }
      *reinterpret_cast<float4*>(&C[(size_t)r*N + c]) = v;
    }
  }
}

// ---------------- GCN aggregation (intra-CSR: only intra-cluster edges) ----------------
__global__ __launch_bounds__(256) void k_gcn(const unsigned short* __restrict__ XWh, const int* __restrict__ ioffs,
                      const int* __restrict__ csr2, const int* __restrict__ intra,
                      const float* __restrict__ gcn_b, float* __restrict__ Xc)
{
  int wid  = (blockIdx.x*blockDim.x + threadIdx.x) >> 6;
  int lane = threadIdx.x & 63;
  int nw   = (gridDim.x*blockDim.x) >> 6;
  for (int n = wid; n < NNODES; n += nw){
    int cntn = intra[n];
    float deg = 1.f + (float)cntn;
    float dinv_n = rsqrtf(deg);
    __half2 hx = *reinterpret_cast<const __half2*>(XWh + (size_t)n*128 + lane*2);
    float2 acc;
    acc.x = __low2float(hx)/deg; acc.y = __high2float(hx)/deg;
    int io0 = ioffs[n];
    for (int j=0; j<cntn; ++j){
      int s = csr2[io0+j];
      float w = dinv_n * rsqrtf(1.f + (float)intra[s]);
      __half2 hs = *reinterpret_cast<const __half2*>(XWh + (size_t)s*128 + lane*2);
      acc.x = fmaf(w, __low2float(hs), acc.x);
      acc.y = fmaf(w, __high2float(hs), acc.y);
    }
    float2 bb = *reinterpret_cast<const float2*>(&gcn_b[lane*2]);
    acc.x += bb.x; acc.y += bb.y;
    *reinterpret_cast<float2*>(&Xc[(size_t)n*128 + lane*2]) = acc;
  }
}

// ---------------- cluster pooling: LDS partials + reduce ----------------
__global__ __launch_bounds__(256) void k_pool1(const float* __restrict__ Xc, const int* __restrict__ clus,
                                               float* __restrict__ part){
  __shared__ float lp[8192];
  for (int i=threadIdx.x; i<8192; i+=256) lp[i]=0.f;
  __syncthreads();
  int d = threadIdx.x & 127, rg = threadIdx.x >> 7;
  int n0 = blockIdx.x*200;
  for (int n = n0+rg; n < n0+200; n += 2){
    int c = clus[n];
    atomicAdd(&lp[c*128 + d], Xc[(size_t)n*128 + d]);
  }
  __syncthreads();
  for (int i=threadIdx.x; i<8192; i+=256) part[(size_t)blockIdx.x*8192 + i] = lp[i];
}
__global__ __launch_bounds__(256) void k_pool2(const float* __restrict__ part, const int* __restrict__ csize,
                                               float* __restrict__ pooled){
  int i = blockIdx.x*256 + threadIdx.x; // 8192
  float s = 0.f;
  for (int b=0;b<400;b++) s += part[(size_t)b*8192 + i];
  pooled[i] = s / fmaxf((float)csize[i>>7], 1.f);
}

// ---------------- cluster GAT small kernels fused: block0=asc, block1=loop_c ----------------
__global__ __launch_bounds__(256) void k_cluster_small(const float* __restrict__ xh_c,
                     const float* __restrict__ g_att_s, const float* __restrict__ g_att_d,
                     float* __restrict__ a_s_c, float* __restrict__ a_d_c,
                     const float* __restrict__ pair_cnt, const float* __restrict__ avg_attr,
                     float* __restrict__ loop_c){
  int t = threadIdx.x;
  if (blockIdx.x == 0){
    int s = t >> 2, h = t & 3;
    float ss=0.f, sd=0.f;
    for (int c=0;c<128;c++){
      float x = xh_c[s*512 + h*128 + c];
      ss += x * g_att_s[h*128 + c];
      sd += x * g_att_d[h*128 + c];
    }
    a_s_c[s*4+h] = ss; a_d_c[s*4+h] = sd;
  } else {
    if (t >= NCLUS) return;
    int d = t;
    float ic=0.f, l0=0.f, l1=0.f;
    for (int s=0;s<NCLUS;s++){
      int k = s*NCLUS + d;
      if (pair_cnt[k] > 0.f){ ic += 1.f; l0 += avg_attr[2*k]; l1 += avg_attr[2*k+1]; }
    }
    float inv = 1.f / fmaxf(ic, 1.f);
    loop_c[2*d] = l0*inv; loop_c[2*d+1] = l1*inv;
  }
}

__global__ __launch_bounds__(128) void k_clout(const float* __restrict__ a_s_c, const float* __restrict__ a_d_c,
                       const float* __restrict__ loop_c, const float* __restrict__ M2g,
                       const float* __restrict__ pair_cnt, const float* __restrict__ avg_attr,
                       const float* __restrict__ xh_c, const float* __restrict__ g_bias,
                       float* __restrict__ cl_out)
{
  int d = blockIdx.x;
  __shared__ float p[NCLUS*4];
  int t = threadIdx.x;
  if (t < NCLUS){
    int s = t;
    for (int h=0; h<4; ++h){
      float v;
      if (s == d){
        v = lrelu(a_s_c[d*4+h] + a_d_c[d*4+h] + loop_c[2*d]*M2g[h] + loop_c[2*d+1]*M2g[4+h]);
      } else if (pair_cnt[s*NCLUS+d] > 0.f){
        int k = s*NCLUS + d;
        v = lrelu(a_s_c[s*4+h] + a_d_c[d*4+h] + avg_attr[2*k]*M2g[h] + avg_attr[2*k+1]*M2g[4+h]);
      } else {
        v = -INFINITY;
      }
      p[s*4+h] = v;
    }
  }
  __syncthreads();
  if (t < 4){
    int h = t;
    float m = -INFINITY;
    for (int s=0;s<NCLUS;s++) m = fmaxf(m, p[s*4+h]);
    float sum = 0.f;
    for (int s=0;s<NCLUS;s++){
      float a = p[s*4+h];
      float e = (a == -INFINITY) ? 0.f : expf(a - m);
      p[s*4+h] = e; sum += e;
    }
    float inv = 1.f/sum;
    for (int s=0;s<NCLUS;s++) p[s*4+h] *= inv;
  }
  __syncthreads();
  int c = t;
  float acc = 0.f;
  for (int s=0;s<NCLUS;s++){
    #pragma unroll
    for (int h=0;h<4;h++) acc += p[s*4+h]*xh_c[s*512 + h*128 + c];
  }
  cl_out[d*128 + c] = 0.25f*acc + g_bias[c];
}

// Xcomb = Xc + cl_out[clus]; write f16 X + fused a_s/a_d dots (layer 0)
__global__ __launch_bounds__(256) void k_xcomb(const float* __restrict__ Xc, const float* __restrict__ cl_out,
                                               const int* __restrict__ clus, __half* __restrict__ xh16,
                                               const float* __restrict__ AsA, const float* __restrict__ AdA,
                                               float* __restrict__ a_s, float* __restrict__ a_d){
  int i = blockIdx.x*256 + threadIdx.x;
  int stride = gridDim.x*256;
  for (; i < NNODES*32; i += stride){
    int n = i >> 5, d4 = i & 31;
    float4 a = ((const float4*)Xc)[i];
    float4 b = ((const float4*)&cl_out[clus[n]*128])[d4];
    float4 r = f4add(a, b);
    __half2 hv[2];
    hv[0] = __floats2half2_rn(r.x, r.y);
    hv[1] = __floats2half2_rn(r.z, r.w);
    ((uint2*)xh16)[i] = *reinterpret_cast<uint2*>(hv);
    float4 ps = make_float4(0,0,0,0), pd = make_float4(0,0,0,0);
    const float4* As4 = (const float4*)(AsA) + d4*4;
    const float4* Ad4 = (const float4*)(AdA) + d4*4;
    ps = f4fma1(r.x, As4[0], ps); ps = f4fma1(r.y, As4[1], ps);
    ps = f4fma1(r.z, As4[2], ps); ps = f4fma1(r.w, As4[3], ps);
    pd = f4fma1(r.x, Ad4[0], pd); pd = f4fma1(r.y, Ad4[1], pd);
    pd = f4fma1(r.z, Ad4[2], pd); pd = f4fma1(r.w, Ad4[3], pd);
    #pragma unroll
    for (int m=16; m>=1; m>>=1){
      ps.x += __shfl_xor(ps.x, m); ps.y += __shfl_xor(ps.y, m);
      ps.z += __shfl_xor(ps.z, m); ps.w += __shfl_xor(ps.w, m);
      pd.x += __shfl_xor(pd.x, m); pd.y += __shfl_xor(pd.y, m);
      pd.z += __shfl_xor(pd.z, m); pd.w += __shfl_xor(pd.w, m);
    }
    if (d4 == 0){
      *reinterpret_cast<float4*>(&a_s[n*4]) = ps;
      *reinterpret_cast<float4*>(&a_d[n*4]) = pd;
    }
  }
}

// ---------------- GAT aggregation in X-space (f16 X gather, full 2-deep prefetch of all operands) ----------------
__global__ __launch_bounds__(256) void k_gat_x(const __half* __restrict__ Xh, const float* __restrict__ a_s,
                     const float* __restrict__ a_d, const float* __restrict__ eattr,
                     const int* __restrict__ offs, const int2* __restrict__ csr,
                     const float* __restrict__ la, const float* __restrict__ M2l,
                     unsigned short* __restrict__ agg)
{
  int wid  = (blockIdx.x*blockDim.x + threadIdx.x) >> 6;
  int lane = threadIdx.x & 63;
  int nw   = (gridDim.x*blockDim.x) >> 6;
  int h = lane >> 4;
  int kslot = (lane & 15)*8;
  float m2a = M2l[h], m2b = M2l[4+h];
  for (int n = wid; n < NNODES; n += nw){
    float asn = a_s[n*4+h];
    float adn = a_d[n*4+h];
    float al = lrelu(asn + adn + la[2*n]*m2a + la[2*n+1]*m2b);
    float pl = __expf(al);
    float denom = pl;
    uint4 u0 = *reinterpret_cast<const uint4*>(Xh + (size_t)n*128 + kslot);
    __half2* x0 = reinterpret_cast<__half2*>(&u0);
    __half2 pl2 = __float2half2_rn(pl);
    __half2 acc0 = __hmul2(x0[0], pl2), acc1 = __hmul2(x0[1], pl2);
    __half2 acc2 = __hmul2(x0[2], pl2), acc3 = __hmul2(x0[3], pl2);
    int b0 = offs[n], b1 = offs[n+1];
    int2 seA = make_int2(0,0), seB = make_int2(0,0);
    uint4 uA = make_uint4(0,0,0,0), uB = make_uint4(0,0,0,0);
    float asA = 0.f, asB = 0.f;
    float2 eaA = make_float2(0.f,0.f), eaB = make_float2(0.f,0.f);
    if (b0 < b1){
      seA = csr[b0];
      uA  = *reinterpret_cast<const uint4*>(Xh + (size_t)seA.x*128 + kslot);
      asA = a_s[seA.x*4+h];
      eaA = *reinterpret_cast<const float2*>(&eattr[2*seA.y]);
    }
    if (b0+1 < b1){
      seB = csr[b0+1];
      uB  = *reinterpret_cast<const uint4*>(Xh + (size_t)seB.x*128 + kslot);
      asB = a_s[seB.x*4+h];
      eaB = *reinterpret_cast<const float2*>(&eattr[2*seB.y]);
    }
    for (int idx=b0; idx<b1; ++idx){
      uint4 u = uA; float asv = asA; float2 ea = eaA;
      seA = seB; uA = uB; asA = asB; eaA = eaB;
      if (idx+2 < b1){
        seB = csr[idx+2];
        uB  = *reinterpret_cast<const uint4*>(Xh + (size_t)seB.x*128 + kslot);
        asB = a_s[seB.x*4+h];
        eaB = *reinterpret_cast<const float2*>(&eattr[2*seB.y]);
      }
      float pe = __expf(lrelu(asv + adn + ea.x*m2a + ea.y*m2b));
      denom += pe;
      __half2 pe2 = __float2half2_rn(pe);
      __half2* y = reinterpret_cast<__half2*>(&u);
      acc0 = __hfma2(y[0], pe2, acc0);
      acc1 = __hfma2(y[1], pe2, acc1);
      acc2 = __hfma2(y[2], pe2, acc2);
      acc3 = __hfma2(y[3], pe2, acc3);
    }
    float sc = 1.f/denom;   // 0.25 mean folded into glt2
    uint4 w;
    w.x = pk2(__low2float(acc0)*sc, __high2float(acc0)*sc);
    w.y = pk2(__low2float(acc1)*sc, __high2float(acc1)*sc);
    w.z = pk2(__low2float(acc2)*sc, __high2float(acc2)*sc);
    w.w = pk2(__low2float(acc3)*sc, __high2float(acc3)*sc);
    *reinterpret_cast<uint4*>(agg + (size_t)n*512 + h*128 + kslot) = w;
  }
}

// ---------------- graph norm: colstat + finstat fused (threadfence last-block pattern) ----------------
__global__ __launch_bounds__(256) void k_colstat_fin(const __half* __restrict__ X, float* __restrict__ part,
                         int* __restrict__ counter,
                         const float* __restrict__ w, const float* __restrict__ b, const float* __restrict__ ms,
                         float* __restrict__ scaleA, float* __restrict__ shiftB){
  int d = threadIdx.x & 127;
  int rg = threadIdx.x >> 7;
  float s1=0.f, s2=0.f;
  for (int n = blockIdx.x*2 + rg; n < NNODES; n += 512){
    float v = __half2float(X[(size_t)n*128 + d]);
    s1 += v; s2 = fmaf(v, v, s2);
  }
  __shared__ float sh[512];
  sh[threadIdx.x] = s1; sh[256+threadIdx.x] = s2;
  __syncthreads();
  if (threadIdx.x < 128){
    s1 = sh[threadIdx.x] + sh[threadIdx.x+128];
    s2 = sh[256+threadIdx.x] + sh[256+threadIdx.x+128];
    part[blockIdx.x*256 + d]       = s1;
    part[blockIdx.x*256 + 128 + d] = s2;
  }
  __threadfence();
  __syncthreads();
  __shared__ int isLast;
  if (threadIdx.x == 0){
    int done = atomicAdd(counter, 1);
    isLast = (done == 255);
  }
  __syncthreads();
  if (isLast){
    __threadfence();
    if (threadIdx.x < 128){
      int dd = threadIdx.x;
      float t1=0.f, t2=0.f;
      for (int bq=0; bq<256; bq++){ t1 += part[bq*256 + dd]; t2 += part[bq*256 + 128 + dd]; }
      float mean = t1 * (1.f/NNODES);
      float ex2  = t2 * (1.f/NNODES);
      float m = ms[dd];
      float var = ex2 - m*mean*mean*(2.f - m);
      float sc = w[dd] * rsqrtf(var + EPSV);
      scaleA[dd] = sc;
      shiftB[dd] = b[dd] - sc*m*mean;
    }
    if (threadIdx.x == 0) *counter = 0;
  }
}

// norm + residual(f16) + ELU; write f16 X + fused next-layer a_s/a_d (or f32 final output)
__global__ __launch_bounds__(256) void k_normelu(const __half* __restrict__ o, __half* __restrict__ xh16,
                         const float* __restrict__ scaleA, const float* __restrict__ shiftB,
                         const float* __restrict__ AsA, const float* __restrict__ AdA,
                         float* __restrict__ a_s, float* __restrict__ a_d,
                         float* __restrict__ fout){
  int i = blockIdx.x*256 + threadIdx.x;
  int stride = gridDim.x*256;
  for (; i < NNODES*32; i += stride){
    int n = i >> 5, d4 = i & 31;
    uint2 ou = ((const uint2*)o)[i];
    __half2* oh = reinterpret_cast<__half2*>(&ou);
    float o0 = __low2float(oh[0]), o1 = __high2float(oh[0]);
    float o2 = __low2float(oh[1]), o3 = __high2float(oh[1]);
    uint2 xu = ((const uint2*)xh16)[i];
    __half2* xh = reinterpret_cast<__half2*>(&xu);
    float xi0 = __low2float(xh[0]), xi1 = __high2float(xh[0]);
    float xi2 = __low2float(xh[1]), xi3 = __high2float(xh[1]);
    float4 sc = ((const float4*)scaleA)[d4];
    float4 sh = ((const float4*)shiftB)[d4];
    float4 r; float y;
    y = fmaf(sc.x, o0, sh.x) + xi0; r.x = y > 0.f ? y : expm1f(y);
    y = fmaf(sc.y, o1, sh.y) + xi1; r.y = y > 0.f ? y : expm1f(y);
    y = fmaf(sc.z, o2, sh.z) + xi2; r.z = y > 0.f ? y : expm1f(y);
    y = fmaf(sc.w, o3, sh.w) + xi3; r.w = y > 0.f ? y : expm1f(y);
    if (fout){
      ((float4*)fout)[i] = r;
    } else {
      __half2 hv[2];
      hv[0] = __floats2half2_rn(r.x, r.y);
      hv[1] = __floats2half2_rn(r.z, r.w);
      ((uint2*)xh16)[i] = *reinterpret_cast<uint2*>(hv);
      float4 ps = make_float4(0,0,0,0), pd = make_float4(0,0,0,0);
      const float4* As4 = (const float4*)(AsA) + d4*4;
      const float4* Ad4 = (const float4*)(AdA) + d4*4;
      ps = f4fma1(r.x, As4[0], ps); ps = f4fma1(r.y, As4[1], ps);
      ps = f4fma1(r.z, As4[2], ps); ps = f4fma1(r.w, As4[3], ps);
      pd = f4fma1(r.x, Ad4[0], pd); pd = f4fma1(r.y, Ad4[1], pd);
      pd = f4fma1(r.z, Ad4[2], pd); pd = f4fma1(r.w, Ad4[3], pd);
      #pragma unroll
      for (int m=16; m>=1; m>>=1){
        ps.x += __shfl_xor(ps.x, m); ps.y += __shfl_xor(ps.y, m);
        ps.z += __shfl_xor(ps.z, m); ps.w += __shfl_xor(ps.w, m);
        pd.x += __shfl_xor(pd.x, m); pd.y += __shfl_xor(pd.y, m);
        pd.z += __shfl_xor(pd.z, m); pd.w += __shfl_xor(pd.w, m);
      }
      if (d4 == 0){
        *reinterpret_cast<float4*>(&a_s[n*4]) = ps;
        *reinterpret_cast<float4*>(&a_d[n*4]) = pd;
      }
    }
  }
}

// ---------------- host launch ----------------
extern "C" void kernel_launch(void* const* d_in, const int* in_sizes, int n_in,
                              void* d_out, int out_size, void* d_ws, size_t ws_size,
                              hipStream_t stream)
{
  const float* extra    = (const float*)d_in[0];
  const int*   ei       = (const int*)  d_in[1];
  const float* eattr    = (const float*)d_in[2];
  const int*   clus     = (const int*)  d_in[3];
  const float* user     = (const float*)d_in[4];
  const float* item     = (const float*)d_in[5];
  const float* W1       = (const float*)d_in[6];
  const float* b1       = (const float*)d_in[7];
  const float* W2       = (const float*)d_in[8];
  const float* b2       = (const float*)d_in[9];
  const float* gcnW     = (const float*)d_in[10];
  const float* gcnb     = (const float*)d_in[11];
  const float* g_lin    = (const float*)d_in[12];
  const float* g_lin_e  = (const float*)d_in[13];
  const float* g_att_s  = (const float*)d_in[14];
  const float* g_att_d  = (const float*)d_in[15];
  const float* g_att_e  = (const float*)d_in[16];
  const float* g_bias   = (const float*)d_in[17];
  const float* gat_lin  = (const float*)d_in[18];
  const float* gat_lin_e= (const float*)d_in[19];
  const float* gat_att_s= (const float*)d_in[20];
  const float* gat_att_d= (const float*)d_in[21];
  const float* gat_att_e= (const float*)d_in[22];
  const float* gat_bias = (const float*)d_in[23];
  const float* nw_      = (const float*)d_in[24];
  const float* nb_      = (const float*)d_in[25];
  const float* nms_     = (const float*)d_in[26];

  char* ws = (char*)d_ws;
  size_t off = 0;
  auto alloc = [&](size_t bytes)->char*{
    char* p = ws + off;
    off += (bytes + 255) & ~size_t(255);
    return p;
  };

  float* bufX = (float*)alloc((size_t)NNODES*128*4);
  float* bufY = (float*)alloc((size_t)NNODES*128*4);
  float* bufZ = (float*)alloc((size_t)NNODES*128*4);
  char* big = alloc((size_t)112*1024*1024);
  __half* Xh16          = (__half*)big;
  unsigned short* agg   = (unsigned short*)(big + (size_t)22*1024*1024);
  unsigned short* Hbf   = (unsigned short*)(big + (size_t)22*1024*1024);
  float* pcb  = (float*)(big + (size_t)22*1024*1024);
  float* pa0b = pcb  + 4096*128;
  float* pa1b = pa0b + 4096*128;
  float* ppart = (float*)(big + (size_t)40*1024*1024);
  int* offs   = (int*)alloc((NNODES+1)*4);
  int* ioffs  = (int*)alloc((NNODES+1)*4);
  int* bsum   = (int*)alloc(1024*4);
  int* bsum2  = (int*)alloc(1024*4);
  int2* csr   = (int2*)alloc((size_t)NEDGES*8);
  int* csr2   = (int*)alloc((size_t)NEDGES*4);
  float* a_s  = (float*)alloc((size_t)NNODES*4*4);
  float* a_d  = (float*)alloc((size_t)NNODES*4*4);
  float* la   = (float*)alloc((size_t)NNODES*2*4);
  // zeroed-per-call region (single memset)
  char* zero0 = ws + off;
  int*   cnt      = (int*)  alloc((size_t)NNODES*4);
  int*   intra    = (int*)  alloc((size_t)NNODES*4);
  int*   cursor   = (int*)  alloc((size_t)NNODES*4);
  int*   cursor2  = (int*)  alloc((size_t)NNODES*4);
  int*   csize    = (int*)  alloc(256*4);
  int*   lcounter = (int*)  alloc(256);
  size_t zbytes = (size_t)((ws + off) - zero0);
  // small buffers
  float* pooled= (float*)alloc(8192*4);
  float* M2g   = (float*)alloc(8*4);
  float* M2    = (float*)alloc(24*4);
  float* AsAll = (float*)alloc(3*512*4);
  float* AdAll = (float*)alloc(3*512*4);
  float* pair_cnt = (float*)alloc(4096*4);
  float* avg_attr = (float*)alloc(8192*4);
  float* loop_c   = (float*)alloc(128*4);
  float* xh_c     = (float*)alloc(64*512*4);
  float* a_s_c    = (float*)alloc(256*4);
  float* a_d_c    = (float*)alloc(256*4);
  float* cl_out   = (float*)alloc(64*128*4);
  float* colpart  = (float*)alloc(256*256*4);
  float* scaleA   = (float*)alloc(128*4);
  float* shiftB   = (float*)alloc(128*4);
  unsigned short* W1t  = (unsigned short*)alloc((size_t)896*256*2);
  unsigned short* W2t  = (unsigned short*)alloc((size_t)256*128*2);
  unsigned short* gcnWt= (unsigned short*)alloc((size_t)128*128*2);
  unsigned short* glt2 = (unsigned short*)alloc((size_t)3*128*512*2);
  if (off > ws_size) return;

  hipMemsetAsync(zero0, 0, zbytes, stream);

  const int NB = (NNODES+255)/256;
  // phase 0: pair hist + cnt/intra, reduce; fused dual scans (LDS csize); fill; gather la
  k_pairhist<<<128, 1024, 0, stream>>>(ei, eattr, clus, cnt, intra, pcb, pa0b, pa1b);
  k_pairreduce<<<64, 64, 0, stream>>>(pcb, pa0b, pa1b, pair_cnt, avg_attr);
  k_scan_block2<<<NB, 256, 0, stream>>>(cnt, intra, offs, ioffs, bsum, bsum2, NNODES, clus, csize);
  k_scan_bsum2<<<2, 512, 0, stream>>>(bsum, bsum2, NB);
  {
    dim3 ga(NB, 2);
    k_scan_add2<<<ga, 256, 0, stream>>>(offs, ioffs, bsum, bsum2, NNODES, NEDGES, 0);
  }
  k_fill_csr<<<(NEDGES+255)/256, 256, 0, stream>>>(ei, clus, offs, ioffs, cursor, cursor2, csr, csr2);
  k_loopattr<<<NB, 256, 0, stream>>>(offs, csr, eattr, la);

  // weight conversions + glt2 + AsAll/AdAll + M2 (one kernel)
  k_wtall_m2<<<1869, 256, 0, stream>>>(W1, W2, gcnW, gat_lin, W1t, W2t, gcnWt, glt2,
                                       gat_att_s, gat_att_d, AsAll, AdAll,
                                       g_lin_e, g_att_e, gat_lin_e, gat_att_e, M2g, M2);

  // enrichment MLP (bf16 MFMA, f32-A fused conversion); Hbf reuses dead pairhist region
  {
    dim3 g1((N_ITEMS+127)/128, 2);
    k_mgemm<1,1,1,1,1><<<g1, 256, 0, stream>>>((const void*)item, extra, W1t, b1, (void*)Hbf,
                                               N_ITEMS, 256, 896, 128);
    dim3 g2((N_ITEMS+127)/128, 1);
    k_mgemm<0,0,0,0,1><<<g2, 256, 0, stream>>>((const void*)Hbf, nullptr, W2t, b2,
                                               (void*)(bufX + (size_t)N_USERS*128),
                                               N_ITEMS, 128, 256, 0);
  }
  hipMemcpyAsync(bufX, user, (size_t)N_USERS*128*4, hipMemcpyDeviceToDevice, stream);

  // cluster GCN: XW (f16) = X @ gcnW; aggregate over intra-CSR only
  {
    dim3 g3((NNODES+127)/128, 1);
    k_mgemm<1,0,2,0,0><<<g3, 256, 0, stream>>>((const void*)bufX, nullptr, gcnWt, nullptr, (void*)bufY,
                                               NNODES, 128, 128, 0);
  }
  k_gcn<<<5000, 256, 0, stream>>>((const unsigned short*)bufY, ioffs, csr2, intra, gcnb, bufZ);

  // pooling (LDS partials) + cluster GAT
  k_pool1<<<400, 256, 0, stream>>>(bufZ, clus, ppart);
  k_pool2<<<32, 256, 0, stream>>>(ppart, csize, pooled);
  {
    dim3 g4(1, 4);
    k_sgemm<0,0><<<g4, 256, 0, stream>>>(pooled, nullptr, g_lin, nullptr, xh_c, 64, 512, 128, 0);
  }
  k_cluster_small<<<2, 256, 0, stream>>>(xh_c, g_att_s, g_att_d, a_s_c, a_d_c, pair_cnt, avg_attr, loop_c);
  k_clout<<<64, 128, 0, stream>>>(a_s_c, a_d_c, loop_c, M2g, pair_cnt, avg_attr, xh_c, g_bias, cl_out);
  k_xcomb<<<1280, 256, 0, stream>>>(bufZ, cl_out, clus, Xh16, AsAll, AdAll, a_s, a_d);

  // 3 GAT layers: k_gat_x (fused logits, X-space agg) -> agg @ glt2 GEMM (128x128 tile, prefetch)
  for (int l = 0; l < 3; ++l){
    k_gat_x<<<20000, 256, 0, stream>>>(Xh16, a_s, a_d, eattr, offs, csr, la, M2 + l*8, agg);
    {
      dim3 gg((NNODES+127)/128, 1);
      k_mgemm<0,0,2,0,1><<<gg, 256, 0, stream>>>((const void*)agg, nullptr, glt2 + (size_t)l*65536,
                                                 gat_bias + l*128, (void*)bufY, NNODES, 128, 512, 0);
    }
    k_colstat_fin<<<256, 256, 0, stream>>>((const __half*)bufY, colpart, lcounter,
                                           nw_ + l*128, nb_ + l*128, nms_ + l*128, scaleA, shiftB);
    k_normelu<<<1280, 256, 0, stream>>>((const __half*)bufY, Xh16, scaleA, shiftB,
                                        AsAll + (l+1 < 3 ? (l+1)*512 : 0),
                                        AdAll + (l+1 < 3 ? (l+1)*512 : 0),
                                        a_s, a_d,
                                        (l==2) ? (float*)d_out : nullptr);
  }
}

// Round 21
// 1049.602 us; speedup vs baseline: 1.2164x; 1.2052x over previous
//
#include <hip/hip_runtime.h>
#include <hip/hip_fp16.h>
#include <math.h>

#define N_USERS 50000
#define N_ITEMS 30000
#define NNODES  80000
#define NEDGES  640000
#define NCLUS   64
#define NEG     0.2f
#define EPSV    1e-5f

typedef __attribute__((ext_vector_type(8))) short bf16x8;
typedef __attribute__((ext_vector_type(4))) float f32x4;

__device__ __forceinline__ float lrelu(float x){ return x > 0.f ? x : NEG*x; }

__device__ __forceinline__ unsigned short f2bf(float f){
  unsigned u = __float_as_uint(f);
  u += 0x7fffu + ((u>>16)&1u);
  return (unsigned short)(u>>16);
}
__device__ __forceinline__ unsigned pk2(float lo, float hi){
  return (unsigned)f2bf(lo) | ((unsigned)f2bf(hi) << 16);
}
__device__ __forceinline__ float4 f4add(float4 a, float4 b){
  return make_float4(a.x+b.x, a.y+b.y, a.z+b.z, a.w+b.w);
}
__device__ __forceinline__ float4 f4fma1(float s, float4 a, float4 b){
  return make_float4(fmaf(s,a.x,b.x), fmaf(s,a.y,b.y), fmaf(s,a.z,b.z), fmaf(s,a.w,b.w));
}
__device__ __forceinline__ void gload_lds16(const void* g, void* l){
  __builtin_amdgcn_global_load_lds(
    (const __attribute__((address_space(1))) unsigned int*)g,
    (__attribute__((address_space(3))) unsigned int*)l, 16, 0, 0);
}

// ---------------- phase 0: pair histogram (LDS-aggregated, 1024-thread blocks) ----------------
__global__ __launch_bounds__(1024) void k_pairhist(
    const int* __restrict__ ei, const float* __restrict__ eattr, const int* __restrict__ clus,
    int* __restrict__ cnt, int* __restrict__ intra,
    float* __restrict__ pcb, float* __restrict__ pa0b, float* __restrict__ pa1b)
{
  __shared__ float pc[4096];
  __shared__ float pa0[4096];
  __shared__ float pa1[4096];
  for (int i=threadIdx.x; i<4096; i+=1024){ pc[i]=0.f; pa0[i]=0.f; pa1[i]=0.f; }
  __syncthreads();
  for (int e = blockIdx.x*1024 + threadIdx.x; e < NEDGES; e += 128*1024){
    int s = ei[e], d = ei[NEDGES+e];
    int cu = clus[s], cv = clus[d];
    atomicAdd(&cnt[d], 1);
    if (cu == cv) { atomicAdd(&intra[d], 1); }
    else {
      float2 a = *reinterpret_cast<const float2*>(&eattr[2*e]);
      int k = cu*NCLUS + cv;
      atomicAdd(&pc[k], 1.f);
      atomicAdd(&pa0[k], a.x);
      atomicAdd(&pa1[k], a.y);
    }
  }
  __syncthreads();
  int b = blockIdx.x;
  for (int i=threadIdx.x; i<4096; i+=1024){
    pcb [i*128 + b] = pc[i];
    pa0b[i*128 + b] = pa0[i];
    pa1b[i*128 + b] = pa1[i];
  }
}

__global__ __launch_bounds__(64) void k_pairreduce(
    const float* __restrict__ pcb, const float* __restrict__ pa0b, const float* __restrict__ pa1b,
    float* __restrict__ pair_cnt, float* __restrict__ avg_attr)
{
  int i = blockIdx.x*64 + threadIdx.x;  // 4096 total over grid 64
  float c=0.f, s0=0.f, s1=0.f;
  const float4* P0 = (const float4*)(pcb  + (size_t)i*128);
  const float4* P1 = (const float4*)(pa0b + (size_t)i*128);
  const float4* P2 = (const float4*)(pa1b + (size_t)i*128);
  for (int b=0;b<32;b++){
    float4 v0=P0[b], v1=P1[b], v2=P2[b];
    c  += v0.x+v0.y+v0.z+v0.w;
    s0 += v1.x+v1.y+v1.z+v1.w;
    s1 += v2.x+v2.y+v2.z+v2.w;
  }
  pair_cnt[i] = c;
  float inv = 1.f/fmaxf(c, 1.f);
  avg_attr[2*i]   = s0*inv;
  avg_attr[2*i+1] = s1*inv;
}

// dual scan: cnt->offs and intra->ioffs, one launch; csize histogram LDS-aggregated
__global__ __launch_bounds__(256) void k_scan_block2(const int* __restrict__ in1, const int* __restrict__ in2,
                                                     int* __restrict__ out1, int* __restrict__ out2,
                                                     int* __restrict__ bsum1, int* __restrict__ bsum2, int n,
                                                     const int* __restrict__ clus, int* __restrict__ csize){
  __shared__ int buf[256];
  __shared__ int lcs[NCLUS];
  int i = blockIdx.x*256 + threadIdx.x;
  if (threadIdx.x < NCLUS) lcs[threadIdx.x] = 0;
  __syncthreads();
  if (i < n) atomicAdd(&lcs[clus[i]], 1);
  int v = (i < n) ? in1[i] : 0;
  buf[threadIdx.x] = v; __syncthreads();
  for (int off=1; off<256; off<<=1){
    int t = (threadIdx.x>=off) ? buf[threadIdx.x-off] : 0;
    __syncthreads();
    buf[threadIdx.x] += t;
    __syncthreads();
  }
  if (i < n) out1[i] = buf[threadIdx.x] - v;
  if (threadIdx.x == 255) bsum1[blockIdx.x] = buf[255];
  __syncthreads();
  v = (i < n) ? in2[i] : 0;
  buf[threadIdx.x] = v; __syncthreads();
  for (int off=1; off<256; off<<=1){
    int t = (threadIdx.x>=off) ? buf[threadIdx.x-off] : 0;
    __syncthreads();
    buf[threadIdx.x] += t;
    __syncthreads();
  }
  if (i < n) out2[i] = buf[threadIdx.x] - v;
  if (threadIdx.x == 255) bsum2[blockIdx.x] = buf[255];
  __syncthreads();
  if (threadIdx.x < NCLUS){
    int c = lcs[threadIdx.x];
    if (c) atomicAdd(&csize[threadIdx.x], c);
  }
}

__global__ __launch_bounds__(512) void k_scan_bsum2(int* __restrict__ bsum1, int* __restrict__ bsum2, int nb){
  int* bs = blockIdx.x ? bsum2 : bsum1;
  __shared__ int buf[512];
  int v = (threadIdx.x < nb) ? bs[threadIdx.x] : 0;
  buf[threadIdx.x] = v; __syncthreads();
  for (int off=1; off<512; off<<=1){
    int t = (threadIdx.x>=off) ? buf[threadIdx.x-off] : 0;
    __syncthreads();
    buf[threadIdx.x] += t;
    __syncthreads();
  }
  if (threadIdx.x < nb) bs[threadIdx.x] = buf[threadIdx.x] - v;
}

__global__ __launch_bounds__(256) void k_scan_add2(int* __restrict__ out1, int* __restrict__ out2,
                                                   const int* __restrict__ bsum1, const int* __restrict__ bsum2,
                                                   int n, int total1, int total2){
  int* out = blockIdx.y ? out2 : out1;
  const int* bs = blockIdx.y ? bsum2 : bsum1;
  int total = blockIdx.y ? total2 : total1;
  int i = blockIdx.x*256 + threadIdx.x;
  if (i < n) out[i] += bs[i>>8];
  if (i == 0) out[n] = total;
}

// fill main CSR + intra CSR (no atomics on float data)
__global__ __launch_bounds__(256) void k_fill_csr(const int* __restrict__ ei, const int* __restrict__ clus,
                                                  const int* __restrict__ offs, const int* __restrict__ ioffs,
                                                  int* __restrict__ cursor, int* __restrict__ cursor2,
                                                  int2* __restrict__ csr, int* __restrict__ csr2){
  int e = blockIdx.x*256 + threadIdx.x;
  if (e >= NEDGES) return;
  int s = ei[e], d = ei[NEDGES+e];
  int pos = offs[d] + atomicAdd(&cursor[d], 1);
  csr[pos] = make_int2(s, e);
  if (clus[s] == clus[d]){
    int p2 = ioffs[d] + atomicAdd(&cursor2[d], 1);
    csr2[p2] = s;
  }
}

// per-node mean edge-attr (self-loop fill), from CSR
__global__ __launch_bounds__(256) void k_loopattr(const int* __restrict__ offs, const int2* __restrict__ csr,
                                                  const float* __restrict__ eattr, float* __restrict__ la){
  int n = blockIdx.x*256 + threadIdx.x;
  if (n >= NNODES) return;
  int b0 = offs[n], b1 = offs[n+1];
  float s0=0.f, s1=0.f;
  for (int i=b0; i<b1; ++i){
    int e = csr[i].y;
    float2 a = *reinterpret_cast<const float2*>(&eattr[2*e]);
    s0 += a.x; s1 += a.y;
  }
  float inv = 1.f/fmaxf((float)(b1-b0), 1.f);
  la[2*n] = s0*inv; la[2*n+1] = s1*inv;
}

// ---------------- weight converts + glt2(W' for agg GEMM) + AsAll/AdAll + M2, one kernel ----------------
__global__ __launch_bounds__(256) void k_wtall_m2(const float* __restrict__ W1, const float* __restrict__ W2,
                       const float* __restrict__ gcnW, const float* __restrict__ gat_lin,
                       unsigned short* __restrict__ W1t, unsigned short* __restrict__ W2t,
                       unsigned short* __restrict__ gcnWt, unsigned short* __restrict__ glt2,
                       const float* __restrict__ att_s, const float* __restrict__ att_d,
                       float* __restrict__ AsAll, float* __restrict__ AdAll,
                       const float* __restrict__ g_lin_e, const float* __restrict__ g_att_e,
                       const float* __restrict__ gat_lin_e, const float* __restrict__ gat_att_e,
                       float* __restrict__ M2g, float* __restrict__ M2){
  int i = blockIdx.x*256 + threadIdx.x;
  if (i < 229376){            // W1: K=896, N=256
    int n = i/896, k = i - n*896;
    W1t[i] = f2bf(W1[(size_t)k*256 + n]);
  } else if (i < 262144){     // W2: K=256, N=128
    int j = i - 229376; int n = j/256, k = j - n*256;
    W2t[j] = f2bf(W2[(size_t)k*128 + n]);
  } else if (i < 278528){     // gcnW: 128x128
    int j = i - 262144; int n = j/128, k = j - n*128;
    gcnWt[j] = f2bf(gcnW[(size_t)k*128 + n]);
  } else if (i < 475136){     // glt2: 3 x [128 d][512 hk]
    int j = i - 278528; int l = j >> 16; int r = j & 65535; int d = r >> 9; int hk = r & 511;
    glt2[j] = f2bf(0.25f * gat_lin[(size_t)l*65536 + (size_t)(hk & 127)*512 + (hk >> 7)*128 + d]);
  } else if (i < 478208){     // AsAll/AdAll: 3*128*4*2
    int j = i - 475136;
    int which = j & 1, h = (j >> 1) & 3, k = (j >> 3) & 127, l = j >> 10;
    const float* att = which ? att_d : att_s;
    float s = 0.f;
    for (int c=0;c<128;c++) s += gat_lin[(size_t)l*65536 + k*512 + h*128 + c] * att[l*512 + h*128 + c];
    float* dst = which ? AdAll : AsAll;
    dst[l*512 + k*4 + h] = s;
  } else if (i < 478240){     // M2 precompute
    int t = i - 478208;
    if (t < 8){
      int j = t >> 2, h = t & 3;
      float s = 0.f;
      for (int c=0;c<128;c++) s += g_lin_e[j*512 + h*128 + c] * g_att_e[h*128 + c];
      M2g[j*4+h] = s;
    } else {
      int u = t - 8; int l = u >> 3, j = (u >> 2) & 1, h = u & 3;
      float s = 0.f;
      for (int c=0;c<128;c++) s += gat_lin_e[l*1024 + j*512 + h*128 + c] * gat_att_e[l*512 + h*128 + c];
      M2[l*8 + j*4 + h] = s;
    }
  }
}

// ---------------- bf16 MFMA GEMM: C = act(A @ Bt^T + bias), 128x128 tile ----------------
// Staging via global_load_lds (async DMA): LDS layout kept linear per-wave (8 rows x 128B = 1KB),
// XOR swizzle realized by pre-swizzling the per-lane GLOBAL source column (cSw = cA ^ (row&7)).
template<int AF32, int CONCAT, int OUT, int RELU, int BIAS>
__global__ __launch_bounds__(256)
void k_mgemm(const void* __restrict__ Av, const float* __restrict__ A2,
             const unsigned short* __restrict__ Bt, const float* __restrict__ bias,
             void* __restrict__ Cv, int M, int N, int K, int K1)
{
  __shared__ unsigned short As[128*64];
  __shared__ unsigned short Bs[128*64];
  const int tid = threadIdx.x;
  const int lane = tid & 63, w = tid >> 6;
  const int row0 = blockIdx.x*128, col0 = blockIdx.y*128;
  const int wm = w >> 1, wn = w & 1;
  const int l15 = lane & 15, l4 = lane >> 4;
  f32x4 acc[4][4];
  #pragma unroll
  for (int i=0;i<4;i++)
    #pragma unroll
    for (int n=0;n<4;n++) acc[i][n] = (f32x4){0.f,0.f,0.f,0.f};

  const int rr0 = w*32 + (lane>>3);
  const int cA = lane & 7;
  const int cSw = cA ^ (rr0 & 7);    // swizzled source chunk (rr&7 constant over i since i*8 multiple of 8)

  for (int kt = 0; kt < K; kt += 64){
    float4 fa[4][2];
    if (AF32){
      #pragma unroll
      for (int i=0;i<4;i++){
        int rr = rr0 + i*8;
        int ga = row0 + rr; ga = (ga < M) ? ga : (M-1);
        int gk = kt + cA*8;
        const float* src;
        if (CONCAT && gk >= K1) src = A2 + (size_t)ga*(K-K1) + (gk - K1);
        else                    src = ((const float*)Av) + (size_t)ga*(CONCAT ? K1 : K) + gk;
        fa[i][0] = ((const float4*)src)[0];
        fa[i][1] = ((const float4*)src)[1];
      }
    }
    __syncthreads();   // prev tile MFMA reads done; LDS writable
    #pragma unroll
    for (int i=0;i<4;i++){
      int rr = rr0 + i*8;
      int gb = col0 + rr; gb = (gb < N) ? gb : (N-1);
      gload_lds16(Bt + (size_t)gb*K + kt + cSw*8, &Bs[(w*32 + i*8)*64]);
      if (!AF32){
        int ga = row0 + rr; ga = (ga < M) ? ga : (M-1);
        gload_lds16((const unsigned short*)Av + (size_t)ga*K + kt + cSw*8, &As[(w*32 + i*8)*64]);
      }
    }
    if (AF32){
      #pragma unroll
      for (int i=0;i<4;i++){
        int rr = rr0 + i*8;
        int ch = cA ^ (rr & 7);
        uint4 va = make_uint4(pk2(fa[i][0].x,fa[i][0].y), pk2(fa[i][0].z,fa[i][0].w),
                              pk2(fa[i][1].x,fa[i][1].y), pk2(fa[i][1].z,fa[i][1].w));
        *reinterpret_cast<uint4*>(&As[rr*64 + ch*8]) = va;
      }
    }
    __syncthreads();   // drains vmcnt (async LDS DMA) + lgkm
    #pragma unroll
    for (int k0=0;k0<2;k0++){
      bf16x8 af[4], bff[4];
      #pragma unroll
      for (int i=0;i<4;i++){
        int row = wm*64 + i*16 + l15;
        int ch = (k0*4 + l4) ^ (row & 7);
        af[i] = *reinterpret_cast<const bf16x8*>(&As[row*64 + ch*8]);
      }
      #pragma unroll
      for (int n=0;n<4;n++){
        int row = wn*64 + n*16 + l15;
        int ch = (k0*4 + l4) ^ (row & 7);
        bff[n] = *reinterpret_cast<const bf16x8*>(&Bs[row*64 + ch*8]);
      }
      #pragma unroll
      for (int i=0;i<4;i++)
        #pragma unroll
        for (int n=0;n<4;n++)
          acc[i][n] = __builtin_amdgcn_mfma_f32_16x16x32_bf16(af[i], bff[n], acc[i][n], 0, 0, 0);
    }
  }
  // C store
  #pragma unroll
  for (int i=0;i<4;i++){
    int rowb = row0 + wm*64 + i*16 + l4*4;
    #pragma unroll
    for (int n=0;n<4;n++){
      int col = col0 + wn*64 + n*16 + l15;
      float bv = BIAS ? bias[col] : 0.f;
      #pragma unroll
      for (int r=0;r<4;r++){
        int row = rowb + r;
        if (row < M){
          float y = acc[i][n][r] + bv;
          if (RELU) y = fmaxf(y, 0.f);
          if (OUT == 1)      ((unsigned short*)Cv)[(size_t)row*N + col] = f2bf(y);
          else if (OUT == 2) ((__half*)Cv)[(size_t)row*N + col] = __float2half(y);
          else               ((float*)Cv)[(size_t)row*N + col] = y;
        }
      }
    }
  }
}

// ---------------- f32 SGEMM (tiny pooled GEMM only) ----------------
template<int CONCAT, int ACT>
__global__ __launch_bounds__(256)
void k_sgemm(const float* __restrict__ A, const float* __restrict__ A2,
             const float* __restrict__ B, const float* __restrict__ bias,
             float* __restrict__ C, int M, int N, int K, int K1)
{
  __shared__ float As[8][128];
  __shared__ float Bs[8][128];
  int row0 = blockIdx.x*128, col0 = blockIdx.y*128;
  int tid = threadIdx.x;
  int tx = tid & 15, ty = tid >> 4;
  float acc[8][8];
  #pragma unroll
  for (int i=0;i<8;i++)
    #pragma unroll
    for (int j=0;j<8;j++) acc[i][j]=0.f;

  int arow = tid >> 1, acol = (tid & 1)*4;
  int brow = tid >> 5, bcol = (tid & 31)*4;
  int K2 = K - K1;

  for (int k0=0; k0<K; k0+=8){
    float4 av = make_float4(0.f,0.f,0.f,0.f);
    int gr = row0 + arow, gk = k0 + acol;
    if (gr < M){
      if (CONCAT){
        if (gk < K1) av = *reinterpret_cast<const float4*>(&A [(size_t)gr*K1 + gk]);
        else         av = *reinterpret_cast<const float4*>(&A2[(size_t)gr*K2 + (gk-K1)]);
      } else {
        av = *reinterpret_cast<const float4*>(&A[(size_t)gr*K + gk]);
      }
    }
    As[acol+0][arow]=av.x; As[acol+1][arow]=av.y; As[acol+2][arow]=av.z; As[acol+3][arow]=av.w;
    float4 bv = *reinterpret_cast<const float4*>(&B[(size_t)(k0+brow)*N + col0 + bcol]);
    *reinterpret_cast<float4*>(&Bs[brow][bcol]) = bv;
    __syncthreads();
    #pragma unroll
    for (int kk=0; kk<8; ++kk){
      float a[8], b[8];
      *(float4*)&a[0] = *(float4*)&As[kk][ty*8];
      *(float4*)&a[4] = *(float4*)&As[kk][ty*8+4];
      *(float4*)&b[0] = *(float4*)&Bs[kk][tx*8];
      *(float4*)&b[4] = *(float4*)&Bs[kk][tx*8+4];
      #pragma unroll
      for (int i=0;i<8;i++)
        #pragma unroll
        for (int j=0;j<8;j++) acc[i][j] = fmaf(a[i], b[j], acc[i][j]);
    }
    __syncthreads();
  }
  #pragma unroll
  for (int i=0;i<8;i++){
    int r = row0 + ty*8 + i;
    if (r >= M) continue;
    #pragma unroll
    for (int j4=0;j4<2;j4++){
      int c = col0 + tx*8 + j4*4;
      float4 v = make_float4(acc[i][j4*4], acc[i][j4*4+1], acc[i][j4*4+2], acc[i][j4*4+3]);
      if (bias){
        float4 bb = *reinterpret_cast<const float4*>(&bias[c]);
        v = f4add(v, bb);
      }
      if (ACT == 1){
        v.x=fmaxf(v.x,0.f); v.y=fmaxf(v.y,0.f); v.z=fmaxf(v.z,0.f); v.w=fmaxf(v.w,0.f);
      }
      *reinterpret_cast<float4*>(&C[(size_t)r*N + c]) = v;
    }
  }
}

// ---------------- GCN aggregation (intra-CSR: only intra-cluster edges) ----------------
__global__ __launch_bounds__(256) void k_gcn(const unsigned short* __restrict__ XWh, const int* __restrict__ ioffs,
                      const int* __restrict__ csr2, const int* __restrict__ intra,
                      const float* __restrict__ gcn_b, float* __restrict__ Xc)
{
  int wid  = (blockIdx.x*blockDim.x + threadIdx.x) >> 6;
  int lane = threadIdx.x & 63;
  int nw   = (gridDim.x*blockDim.x) >> 6;
  for (int n = wid; n < NNODES; n += nw){
    int cntn = intra[n];
    float deg = 1.f + (float)cntn;
    float dinv_n = rsqrtf(deg);
    __half2 hx = *reinterpret_cast<const __half2*>(XWh + (size_t)n*128 + lane*2);
    float2 acc;
    acc.x = __low2float(hx)/deg; acc.y = __high2float(hx)/deg;
    int io0 = ioffs[n];
    for (int j=0; j<cntn; ++j){
      int s = csr2[io0+j];
      float w = dinv_n * rsqrtf(1.f + (float)intra[s]);
      __half2 hs = *reinterpret_cast<const __half2*>(XWh + (size_t)s*128 + lane*2);
      acc.x = fmaf(w, __low2float(hs), acc.x);
      acc.y = fmaf(w, __high2float(hs), acc.y);
    }
    float2 bb = *reinterpret_cast<const float2*>(&gcn_b[lane*2]);
    acc.x += bb.x; acc.y += bb.y;
    *reinterpret_cast<float2*>(&Xc[(size_t)n*128 + lane*2]) = acc;
  }
}

// ---------------- cluster pooling: LDS partials + reduce ----------------
__global__ __launch_bounds__(256) void k_pool1(const float* __restrict__ Xc, const int* __restrict__ clus,
                                               float* __restrict__ part){
  __shared__ float lp[8192];
  for (int i=threadIdx.x; i<8192; i+=256) lp[i]=0.f;
  __syncthreads();
  int d = threadIdx.x & 127, rg = threadIdx.x >> 7;
  int n0 = blockIdx.x*200;
  for (int n = n0+rg; n < n0+200; n += 2){
    int c = clus[n];
    atomicAdd(&lp[c*128 + d], Xc[(size_t)n*128 + d]);
  }
  __syncthreads();
  for (int i=threadIdx.x; i<8192; i+=256) part[(size_t)blockIdx.x*8192 + i] = lp[i];
}
__global__ __launch_bounds__(256) void k_pool2(const float* __restrict__ part, const int* __restrict__ csize,
                                               float* __restrict__ pooled){
  int i = blockIdx.x*256 + threadIdx.x; // 8192
  float s = 0.f;
  for (int b=0;b<400;b++) s += part[(size_t)b*8192 + i];
  pooled[i] = s / fmaxf((float)csize[i>>7], 1.f);
}

// ---------------- cluster GAT small kernels fused: block0=asc, block1=loop_c ----------------
__global__ __launch_bounds__(256) void k_cluster_small(const float* __restrict__ xh_c,
                     const float* __restrict__ g_att_s, const float* __restrict__ g_att_d,
                     float* __restrict__ a_s_c, float* __restrict__ a_d_c,
                     const float* __restrict__ pair_cnt, const float* __restrict__ avg_attr,
                     float* __restrict__ loop_c){
  int t = threadIdx.x;
  if (blockIdx.x == 0){
    int s = t >> 2, h = t & 3;
    float ss=0.f, sd=0.f;
    for (int c=0;c<128;c++){
      float x = xh_c[s*512 + h*128 + c];
      ss += x * g_att_s[h*128 + c];
      sd += x * g_att_d[h*128 + c];
    }
    a_s_c[s*4+h] = ss; a_d_c[s*4+h] = sd;
  } else {
    if (t >= NCLUS) return;
    int d = t;
    float ic=0.f, l0=0.f, l1=0.f;
    for (int s=0;s<NCLUS;s++){
      int k = s*NCLUS + d;
      if (pair_cnt[k] > 0.f){ ic += 1.f; l0 += avg_attr[2*k]; l1 += avg_attr[2*k+1]; }
    }
    float inv = 1.f / fmaxf(ic, 1.f);
    loop_c[2*d] = l0*inv; loop_c[2*d+1] = l1*inv;
  }
}

__global__ __launch_bounds__(128) void k_clout(const float* __restrict__ a_s_c, const float* __restrict__ a_d_c,
                       const float* __restrict__ loop_c, const float* __restrict__ M2g,
                       const float* __restrict__ pair_cnt, const float* __restrict__ avg_attr,
                       const float* __restrict__ xh_c, const float* __restrict__ g_bias,
                       float* __restrict__ cl_out)
{
  int d = blockIdx.x;
  __shared__ float p[NCLUS*4];
  int t = threadIdx.x;
  if (t < NCLUS){
    int s = t;
    for (int h=0; h<4; ++h){
      float v;
      if (s == d){
        v = lrelu(a_s_c[d*4+h] + a_d_c[d*4+h] + loop_c[2*d]*M2g[h] + loop_c[2*d+1]*M2g[4+h]);
      } else if (pair_cnt[s*NCLUS+d] > 0.f){
        int k = s*NCLUS + d;
        v = lrelu(a_s_c[s*4+h] + a_d_c[d*4+h] + avg_attr[2*k]*M2g[h] + avg_attr[2*k+1]*M2g[4+h]);
      } else {
        v = -INFINITY;
      }
      p[s*4+h] = v;
    }
  }
  __syncthreads();
  if (t < 4){
    int h = t;
    float m = -INFINITY;
    for (int s=0;s<NCLUS;s++) m = fmaxf(m, p[s*4+h]);
    float sum = 0.f;
    for (int s=0;s<NCLUS;s++){
      float a = p[s*4+h];
      float e = (a == -INFINITY) ? 0.f : expf(a - m);
      p[s*4+h] = e; sum += e;
    }
    float inv = 1.f/sum;
    for (int s=0;s<NCLUS;s++) p[s*4+h] *= inv;
  }
  __syncthreads();
  int c = t;
  float acc = 0.f;
  for (int s=0;s<NCLUS;s++){
    #pragma unroll
    for (int h=0;h<4;h++) acc += p[s*4+h]*xh_c[s*512 + h*128 + c];
  }
  cl_out[d*128 + c] = 0.25f*acc + g_bias[c];
}

// Xcomb = Xc + cl_out[clus]; write f16 X + fused a_s/a_d dots (layer 0)
__global__ __launch_bounds__(256) void k_xcomb(const float* __restrict__ Xc, const float* __restrict__ cl_out,
                                               const int* __restrict__ clus, __half* __restrict__ xh16,
                                               const float* __restrict__ AsA, const float* __restrict__ AdA,
                                               float* __restrict__ a_s, float* __restrict__ a_d){
  int i = blockIdx.x*256 + threadIdx.x;
  int stride = gridDim.x*256;
  for (; i < NNODES*32; i += stride){
    int n = i >> 5, d4 = i & 31;
    float4 a = ((const float4*)Xc)[i];
    float4 b = ((const float4*)&cl_out[clus[n]*128])[d4];
    float4 r = f4add(a, b);
    __half2 hv[2];
    hv[0] = __floats2half2_rn(r.x, r.y);
    hv[1] = __floats2half2_rn(r.z, r.w);
    ((uint2*)xh16)[i] = *reinterpret_cast<uint2*>(hv);
    float4 ps = make_float4(0,0,0,0), pd = make_float4(0,0,0,0);
    const float4* As4 = (const float4*)(AsA) + d4*4;
    const float4* Ad4 = (const float4*)(AdA) + d4*4;
    ps = f4fma1(r.x, As4[0], ps); ps = f4fma1(r.y, As4[1], ps);
    ps = f4fma1(r.z, As4[2], ps); ps = f4fma1(r.w, As4[3], ps);
    pd = f4fma1(r.x, Ad4[0], pd); pd = f4fma1(r.y, Ad4[1], pd);
    pd = f4fma1(r.z, Ad4[2], pd); pd = f4fma1(r.w, Ad4[3], pd);
    #pragma unroll
    for (int m=16; m>=1; m>>=1){
      ps.x += __shfl_xor(ps.x, m); ps.y += __shfl_xor(ps.y, m);
      ps.z += __shfl_xor(ps.z, m); ps.w += __shfl_xor(ps.w, m);
      pd.x += __shfl_xor(pd.x, m); pd.y += __shfl_xor(pd.y, m);
      pd.z += __shfl_xor(pd.z, m); pd.w += __shfl_xor(pd.w, m);
    }
    if (d4 == 0){
      *reinterpret_cast<float4*>(&a_s[n*4]) = ps;
      *reinterpret_cast<float4*>(&a_d[n*4]) = pd;
    }
  }
}

// ---------------- GAT aggregation in X-space (f16 X gather, full 2-deep prefetch of all operands) ----------------
__global__ __launch_bounds__(256) void k_gat_x(const __half* __restrict__ Xh, const float* __restrict__ a_s,
                     const float* __restrict__ a_d, const float* __restrict__ eattr,
                     const int* __restrict__ offs, const int2* __restrict__ csr,
                     const float* __restrict__ la, const float* __restrict__ M2l,
                     unsigned short* __restrict__ agg)
{
  int wid  = (blockIdx.x*blockDim.x + threadIdx.x) >> 6;
  int lane = threadIdx.x & 63;
  int nw   = (gridDim.x*blockDim.x) >> 6;
  int h = lane >> 4;
  int kslot = (lane & 15)*8;
  float m2a = M2l[h], m2b = M2l[4+h];
  for (int n = wid; n < NNODES; n += nw){
    float asn = a_s[n*4+h];
    float adn = a_d[n*4+h];
    float al = lrelu(asn + adn + la[2*n]*m2a + la[2*n+1]*m2b);
    float pl = __expf(al);
    float denom = pl;
    uint4 u0 = *reinterpret_cast<const uint4*>(Xh + (size_t)n*128 + kslot);
    __half2* x0 = reinterpret_cast<__half2*>(&u0);
    __half2 pl2 = __float2half2_rn(pl);
    __half2 acc0 = __hmul2(x0[0], pl2), acc1 = __hmul2(x0[1], pl2);
    __half2 acc2 = __hmul2(x0[2], pl2), acc3 = __hmul2(x0[3], pl2);
    int b0 = offs[n], b1 = offs[n+1];
    int2 seA = make_int2(0,0), seB = make_int2(0,0);
    uint4 uA = make_uint4(0,0,0,0), uB = make_uint4(0,0,0,0);
    float asA = 0.f, asB = 0.f;
    float2 eaA = make_float2(0.f,0.f), eaB = make_float2(0.f,0.f);
    if (b0 < b1){
      seA = csr[b0];
      uA  = *reinterpret_cast<const uint4*>(Xh + (size_t)seA.x*128 + kslot);
      asA = a_s[seA.x*4+h];
      eaA = *reinterpret_cast<const float2*>(&eattr[2*seA.y]);
    }
    if (b0+1 < b1){
      seB = csr[b0+1];
      uB  = *reinterpret_cast<const uint4*>(Xh + (size_t)seB.x*128 + kslot);
      asB = a_s[seB.x*4+h];
      eaB = *reinterpret_cast<const float2*>(&eattr[2*seB.y]);
    }
    for (int idx=b0; idx<b1; ++idx){
      uint4 u = uA; float asv = asA; float2 ea = eaA;
      seA = seB; uA = uB; asA = asB; eaA = eaB;
      if (idx+2 < b1){
        seB = csr[idx+2];
        uB  = *reinterpret_cast<const uint4*>(Xh + (size_t)seB.x*128 + kslot);
        asB = a_s[seB.x*4+h];
        eaB = *reinterpret_cast<const float2*>(&eattr[2*seB.y]);
      }
      float pe = __expf(lrelu(asv + adn + ea.x*m2a + ea.y*m2b));
      denom += pe;
      __half2 pe2 = __float2half2_rn(pe);
      __half2* y = reinterpret_cast<__half2*>(&u);
      acc0 = __hfma2(y[0], pe2, acc0);
      acc1 = __hfma2(y[1], pe2, acc1);
      acc2 = __hfma2(y[2], pe2, acc2);
      acc3 = __hfma2(y[3], pe2, acc3);
    }
    float sc = 1.f/denom;   // 0.25 mean folded into glt2
    uint4 w;
    w.x = pk2(__low2float(acc0)*sc, __high2float(acc0)*sc);
    w.y = pk2(__low2float(acc1)*sc, __high2float(acc1)*sc);
    w.z = pk2(__low2float(acc2)*sc, __high2float(acc2)*sc);
    w.w = pk2(__low2float(acc3)*sc, __high2float(acc3)*sc);
    *reinterpret_cast<uint4*>(agg + (size_t)n*512 + h*128 + kslot) = w;
  }
}

// ---------------- graph norm: colstat + finstat fused (threadfence last-block pattern) ----------------
__global__ __launch_bounds__(256) void k_colstat_fin(const __half* __restrict__ X, float* __restrict__ part,
                         int* __restrict__ counter,
                         const float* __restrict__ w, const float* __restrict__ b, const float* __restrict__ ms,
                         float* __restrict__ scaleA, float* __restrict__ shiftB){
  int d = threadIdx.x & 127;
  int rg = threadIdx.x >> 7;
  float s1=0.f, s2=0.f;
  for (int n = blockIdx.x*2 + rg; n < NNODES; n += 512){
    float v = __half2float(X[(size_t)n*128 + d]);
    s1 += v; s2 = fmaf(v, v, s2);
  }
  __shared__ float sh[512];
  sh[threadIdx.x] = s1; sh[256+threadIdx.x] = s2;
  __syncthreads();
  if (threadIdx.x < 128){
    s1 = sh[threadIdx.x] + sh[threadIdx.x+128];
    s2 = sh[256+threadIdx.x] + sh[256+threadIdx.x+128];
    part[blockIdx.x*256 + d]       = s1;
    part[blockIdx.x*256 + 128 + d] = s2;
  }
  __threadfence();
  __syncthreads();
  __shared__ int isLast;
  if (threadIdx.x == 0){
    int done = atomicAdd(counter, 1);
    isLast = (done == 255);
  }
  __syncthreads();
  if (isLast){
    __threadfence();
    if (threadIdx.x < 128){
      int dd = threadIdx.x;
      float t1=0.f, t2=0.f;
      for (int bq=0; bq<256; bq++){ t1 += part[bq*256 + dd]; t2 += part[bq*256 + 128 + dd]; }
      float mean = t1 * (1.f/NNODES);
      float ex2  = t2 * (1.f/NNODES);
      float m = ms[dd];
      float var = ex2 - m*mean*mean*(2.f - m);
      float sc = w[dd] * rsqrtf(var + EPSV);
      scaleA[dd] = sc;
      shiftB[dd] = b[dd] - sc*m*mean;
    }
    if (threadIdx.x == 0) *counter = 0;
  }
}

// norm + residual(f16) + ELU; write f16 X + fused next-layer a_s/a_d (or f32 final output)
__global__ __launch_bounds__(256) void k_normelu(const __half* __restrict__ o, __half* __restrict__ xh16,
                         const float* __restrict__ scaleA, const float* __restrict__ shiftB,
                         const float* __restrict__ AsA, const float* __restrict__ AdA,
                         float* __restrict__ a_s, float* __restrict__ a_d,
                         float* __restrict__ fout){
  int i = blockIdx.x*256 + threadIdx.x;
  int stride = gridDim.x*256;
  for (; i < NNODES*32; i += stride){
    int n = i >> 5, d4 = i & 31;
    uint2 ou = ((const uint2*)o)[i];
    __half2* oh = reinterpret_cast<__half2*>(&ou);
    float o0 = __low2float(oh[0]), o1 = __high2float(oh[0]);
    float o2 = __low2float(oh[1]), o3 = __high2float(oh[1]);
    uint2 xu = ((const uint2*)xh16)[i];
    __half2* xh = reinterpret_cast<__half2*>(&xu);
    float xi0 = __low2float(xh[0]), xi1 = __high2float(xh[0]);
    float xi2 = __low2float(xh[1]), xi3 = __high2float(xh[1]);
    float4 sc = ((const float4*)scaleA)[d4];
    float4 sh = ((const float4*)shiftB)[d4];
    float4 r; float y;
    y = fmaf(sc.x, o0, sh.x) + xi0; r.x = y > 0.f ? y : expm1f(y);
    y = fmaf(sc.y, o1, sh.y) + xi1; r.y = y > 0.f ? y : expm1f(y);
    y = fmaf(sc.z, o2, sh.z) + xi2; r.z = y > 0.f ? y : expm1f(y);
    y = fmaf(sc.w, o3, sh.w) + xi3; r.w = y > 0.f ? y : expm1f(y);
    if (fout){
      ((float4*)fout)[i] = r;
    } else {
      __half2 hv[2];
      hv[0] = __floats2half2_rn(r.x, r.y);
      hv[1] = __floats2half2_rn(r.z, r.w);
      ((uint2*)xh16)[i] = *reinterpret_cast<uint2*>(hv);
      float4 ps = make_float4(0,0,0,0), pd = make_float4(0,0,0,0);
      const float4* As4 = (const float4*)(AsA) + d4*4;
      const float4* Ad4 = (const float4*)(AdA) + d4*4;
      ps = f4fma1(r.x, As4[0], ps); ps = f4fma1(r.y, As4[1], ps);
      ps = f4fma1(r.z, As4[2], ps); ps = f4fma1(r.w, As4[3], ps);
      pd = f4fma1(r.x, Ad4[0], pd); pd = f4fma1(r.y, Ad4[1], pd);
      pd = f4fma1(r.z, Ad4[2], pd); pd = f4fma1(r.w, Ad4[3], pd);
      #pragma unroll
      for (int m=16; m>=1; m>>=1){
        ps.x += __shfl_xor(ps.x, m); ps.y += __shfl_xor(ps.y, m);
        ps.z += __shfl_xor(ps.z, m); ps.w += __shfl_xor(ps.w, m);
        pd.x += __shfl_xor(pd.x, m); pd.y += __shfl_xor(pd.y, m);
        pd.z += __shfl_xor(pd.z, m); pd.w += __shfl_xor(pd.w, m);
      }
      if (d4 == 0){
        *reinterpret_cast<float4*>(&a_s[n*4]) = ps;
        *reinterpret_cast<float4*>(&a_d[n*4]) = pd;
      }
    }
  }
}

// ---------------- host launch ----------------
extern "C" void kernel_launch(void* const* d_in, const int* in_sizes, int n_in,
                              void* d_out, int out_size, void* d_ws, size_t ws_size,
                              hipStream_t stream)
{
  const float* extra    = (const float*)d_in[0];
  const int*   ei       = (const int*)  d_in[1];
  const float* eattr    = (const float*)d_in[2];
  const int*   clus     = (const int*)  d_in[3];
  const float* user     = (const float*)d_in[4];
  const float* item     = (const float*)d_in[5];
  const float* W1       = (const float*)d_in[6];
  const float* b1       = (const float*)d_in[7];
  const float* W2       = (const float*)d_in[8];
  const float* b2       = (const float*)d_in[9];
  const float* gcnW     = (const float*)d_in[10];
  const float* gcnb     = (const float*)d_in[11];
  const float* g_lin    = (const float*)d_in[12];
  const float* g_lin_e  = (const float*)d_in[13];
  const float* g_att_s  = (const float*)d_in[14];
  const float* g_att_d  = (const float*)d_in[15];
  const float* g_att_e  = (const float*)d_in[16];
  const float* g_bias   = (const float*)d_in[17];
  const float* gat_lin  = (const float*)d_in[18];
  const float* gat_lin_e= (const float*)d_in[19];
  const float* gat_att_s= (const float*)d_in[20];
  const float* gat_att_d= (const float*)d_in[21];
  const float* gat_att_e= (const float*)d_in[22];
  const float* gat_bias = (const float*)d_in[23];
  const float* nw_      = (const float*)d_in[24];
  const float* nb_      = (const float*)d_in[25];
  const float* nms_     = (const float*)d_in[26];

  char* ws = (char*)d_ws;
  size_t off = 0;
  auto alloc = [&](size_t bytes)->char*{
    char* p = ws + off;
    off += (bytes + 255) & ~size_t(255);
    return p;
  };

  float* bufX = (float*)alloc((size_t)NNODES*128*4);
  float* bufY = (float*)alloc((size_t)NNODES*128*4);
  float* bufZ = (float*)alloc((size_t)NNODES*128*4);
  char* big = alloc((size_t)112*1024*1024);
  __half* Xh16          = (__half*)big;
  unsigned short* agg   = (unsigned short*)(big + (size_t)22*1024*1024);
  unsigned short* Hbf   = (unsigned short*)(big + (size_t)22*1024*1024);
  float* pcb  = (float*)(big + (size_t)22*1024*1024);
  float* pa0b = pcb  + 4096*128;
  float* pa1b = pa0b + 4096*128;
  float* ppart = (float*)(big + (size_t)40*1024*1024);
  int* offs   = (int*)alloc((NNODES+1)*4);
  int* ioffs  = (int*)alloc((NNODES+1)*4);
  int* bsum   = (int*)alloc(1024*4);
  int* bsum2  = (int*)alloc(1024*4);
  int2* csr   = (int2*)alloc((size_t)NEDGES*8);
  int* csr2   = (int*)alloc((size_t)NEDGES*4);
  float* a_s  = (float*)alloc((size_t)NNODES*4*4);
  float* a_d  = (float*)alloc((size_t)NNODES*4*4);
  float* la   = (float*)alloc((size_t)NNODES*2*4);
  // zeroed-per-call region (single memset)
  char* zero0 = ws + off;
  int*   cnt      = (int*)  alloc((size_t)NNODES*4);
  int*   intra    = (int*)  alloc((size_t)NNODES*4);
  int*   cursor   = (int*)  alloc((size_t)NNODES*4);
  int*   cursor2  = (int*)  alloc((size_t)NNODES*4);
  int*   csize    = (int*)  alloc(256*4);
  int*   lcounter = (int*)  alloc(256);
  size_t zbytes = (size_t)((ws + off) - zero0);
  // small buffers
  float* pooled= (float*)alloc(8192*4);
  float* M2g   = (float*)alloc(8*4);
  float* M2    = (float*)alloc(24*4);
  float* AsAll = (float*)alloc(3*512*4);
  float* AdAll = (float*)alloc(3*512*4);
  float* pair_cnt = (float*)alloc(4096*4);
  float* avg_attr = (float*)alloc(8192*4);
  float* loop_c   = (float*)alloc(128*4);
  float* xh_c     = (float*)alloc(64*512*4);
  float* a_s_c    = (float*)alloc(256*4);
  float* a_d_c    = (float*)alloc(256*4);
  float* cl_out   = (float*)alloc(64*128*4);
  float* colpart  = (float*)alloc(256*256*4);
  float* scaleA   = (float*)alloc(128*4);
  float* shiftB   = (float*)alloc(128*4);
  unsigned short* W1t  = (unsigned short*)alloc((size_t)896*256*2);
  unsigned short* W2t  = (unsigned short*)alloc((size_t)256*128*2);
  unsigned short* gcnWt= (unsigned short*)alloc((size_t)128*128*2);
  unsigned short* glt2 = (unsigned short*)alloc((size_t)3*128*512*2);
  if (off > ws_size) return;

  hipMemsetAsync(zero0, 0, zbytes, stream);

  const int NB = (NNODES+255)/256;
  // phase 0: pair hist + cnt/intra, reduce; fused dual scans (LDS csize); fill; gather la
  k_pairhist<<<128, 1024, 0, stream>>>(ei, eattr, clus, cnt, intra, pcb, pa0b, pa1b);
  k_pairreduce<<<64, 64, 0, stream>>>(pcb, pa0b, pa1b, pair_cnt, avg_attr);
  k_scan_block2<<<NB, 256, 0, stream>>>(cnt, intra, offs, ioffs, bsum, bsum2, NNODES, clus, csize);
  k_scan_bsum2<<<2, 512, 0, stream>>>(bsum, bsum2, NB);
  {
    dim3 ga(NB, 2);
    k_scan_add2<<<ga, 256, 0, stream>>>(offs, ioffs, bsum, bsum2, NNODES, NEDGES, 0);
  }
  k_fill_csr<<<(NEDGES+255)/256, 256, 0, stream>>>(ei, clus, offs, ioffs, cursor, cursor2, csr, csr2);
  k_loopattr<<<NB, 256, 0, stream>>>(offs, csr, eattr, la);

  // weight conversions + glt2 + AsAll/AdAll + M2 (one kernel)
  k_wtall_m2<<<1869, 256, 0, stream>>>(W1, W2, gcnW, gat_lin, W1t, W2t, gcnWt, glt2,
                                       gat_att_s, gat_att_d, AsAll, AdAll,
                                       g_lin_e, g_att_e, gat_lin_e, gat_att_e, M2g, M2);

  // enrichment MLP (bf16 MFMA, f32-A fused conversion); Hbf reuses dead pairhist region
  {
    dim3 g1((N_ITEMS+127)/128, 2);
    k_mgemm<1,1,1,1,1><<<g1, 256, 0, stream>>>((const void*)item, extra, W1t, b1, (void*)Hbf,
                                               N_ITEMS, 256, 896, 128);
    dim3 g2((N_ITEMS+127)/128, 1);
    k_mgemm<0,0,0,0,1><<<g2, 256, 0, stream>>>((const void*)Hbf, nullptr, W2t, b2,
                                               (void*)(bufX + (size_t)N_USERS*128),
                                               N_ITEMS, 128, 256, 0);
  }
  hipMemcpyAsync(bufX, user, (size_t)N_USERS*128*4, hipMemcpyDeviceToDevice, stream);

  // cluster GCN: XW (f16) = X @ gcnW; aggregate over intra-CSR only
  {
    dim3 g3((NNODES+127)/128, 1);
    k_mgemm<1,0,2,0,0><<<g3, 256, 0, stream>>>((const void*)bufX, nullptr, gcnWt, nullptr, (void*)bufY,
                                               NNODES, 128, 128, 0);
  }
  k_gcn<<<5000, 256, 0, stream>>>((const unsigned short*)bufY, ioffs, csr2, intra, gcnb, bufZ);

  // pooling (LDS partials) + cluster GAT
  k_pool1<<<400, 256, 0, stream>>>(bufZ, clus, ppart);
  k_pool2<<<32, 256, 0, stream>>>(ppart, csize, pooled);
  {
    dim3 g4(1, 4);
    k_sgemm<0,0><<<g4, 256, 0, stream>>>(pooled, nullptr, g_lin, nullptr, xh_c, 64, 512, 128, 0);
  }
  k_cluster_small<<<2, 256, 0, stream>>>(xh_c, g_att_s, g_att_d, a_s_c, a_d_c, pair_cnt, avg_attr, loop_c);
  k_clout<<<64, 128, 0, stream>>>(a_s_c, a_d_c, loop_c, M2g, pair_cnt, avg_attr, xh_c, g_bias, cl_out);
  k_xcomb<<<1280, 256, 0, stream>>>(bufZ, cl_out, clus, Xh16, AsAll, AdAll, a_s, a_d);

  // 3 GAT layers: k_gat_x (fused logits, X-space agg) -> agg @ glt2 GEMM (128x128 tile, gload_lds)
  for (int l = 0; l < 3; ++l){
    k_gat_x<<<20000, 256, 0, stream>>>(Xh16, a_s, a_d, eattr, offs, csr, la, M2 + l*8, agg);
    {
      dim3 gg((NNODES+127)/128, 1);
      k_mgemm<0,0,2,0,1><<<gg, 256, 0, stream>>>((const void*)agg, nullptr, glt2 + (size_t)l*65536,
                                                 gat_bias + l*128, (void*)bufY, NNODES, 128, 512, 0);
    }
    k_colstat_fin<<<256, 256, 0, stream>>>((const __half*)bufY, colpart, lcounter,
                                           nw_ + l*128, nb_ + l*128, nms_ + l*128, scaleA, shiftB);
    k_normelu<<<1280, 256, 0, stream>>>((const __half*)bufY, Xh16, scaleA, shiftB,
                                        AsAll + (l+1 < 3 ? (l+1)*512 : 0),
                                        AdAll + (l+1 < 3 ? (l+1)*512 : 0),
                                        a_s, a_d,
                                        (l==2) ? (float*)d_out : nullptr);
  }
}

// Round 22
// 970.101 us; speedup vs baseline: 1.3161x; 1.0820x over previous
//
#include <hip/hip_runtime.h>
#include <hip/hip_fp16.h>
#include <math.h>

#define N_USERS 50000
#define N_ITEMS 30000
#define NNODES  80000
#define NEDGES  640000
#define NCLUS   64
#define NEG     0.2f
#define EPSV    1e-5f

typedef __attribute__((ext_vector_type(8))) short bf16x8;
typedef __attribute__((ext_vector_type(4))) float f32x4;

__device__ __forceinline__ float lrelu(float x){ return x > 0.f ? x : NEG*x; }

__device__ __forceinline__ unsigned short f2bf(float f){
  unsigned u = __float_as_uint(f);
  u += 0x7fffu + ((u>>16)&1u);
  return (unsigned short)(u>>16);
}
__device__ __forceinline__ unsigned pk2(float lo, float hi){
  return (unsigned)f2bf(lo) | ((unsigned)f2bf(hi) << 16);
}
__device__ __forceinline__ float4 f4add(float4 a, float4 b){
  return make_float4(a.x+b.x, a.y+b.y, a.z+b.z, a.w+b.w);
}
__device__ __forceinline__ float4 f4fma1(float s, float4 a, float4 b){
  return make_float4(fmaf(s,a.x,b.x), fmaf(s,a.y,b.y), fmaf(s,a.z,b.z), fmaf(s,a.w,b.w));
}
__device__ __forceinline__ void gload_lds16(const void* g, void* l){
  __builtin_amdgcn_global_load_lds(
    (const __attribute__((address_space(1))) unsigned int*)g,
    (__attribute__((address_space(3))) unsigned int*)l, 16, 0, 0);
}

// ---------------- phase 0: pair histogram (LDS-aggregated, 1024-thread blocks) ----------------
__global__ __launch_bounds__(1024) void k_pairhist(
    const int* __restrict__ ei, const float* __restrict__ eattr, const int* __restrict__ clus,
    int* __restrict__ cnt, int* __restrict__ intra,
    float* __restrict__ pcb, float* __restrict__ pa0b, float* __restrict__ pa1b)
{
  __shared__ float pc[4096];
  __shared__ float pa0[4096];
  __shared__ float pa1[4096];
  for (int i=threadIdx.x; i<4096; i+=1024){ pc[i]=0.f; pa0[i]=0.f; pa1[i]=0.f; }
  __syncthreads();
  for (int e = blockIdx.x*1024 + threadIdx.x; e < NEDGES; e += 128*1024){
    int s = ei[e], d = ei[NEDGES+e];
    int cu = clus[s], cv = clus[d];
    atomicAdd(&cnt[d], 1);
    if (cu == cv) { atomicAdd(&intra[d], 1); }
    else {
      float2 a = *reinterpret_cast<const float2*>(&eattr[2*e]);
      int k = cu*NCLUS + cv;
      atomicAdd(&pc[k], 1.f);
      atomicAdd(&pa0[k], a.x);
      atomicAdd(&pa1[k], a.y);
    }
  }
  __syncthreads();
  int b = blockIdx.x;
  for (int i=threadIdx.x; i<4096; i+=1024){
    pcb [i*128 + b] = pc[i];
    pa0b[i*128 + b] = pa0[i];
    pa1b[i*128 + b] = pa1[i];
  }
}

__global__ __launch_bounds__(64) void k_pairreduce(
    const float* __restrict__ pcb, const float* __restrict__ pa0b, const float* __restrict__ pa1b,
    float* __restrict__ pair_cnt, float* __restrict__ avg_attr)
{
  int i = blockIdx.x*64 + threadIdx.x;  // 4096 total over grid 64
  float c=0.f, s0=0.f, s1=0.f;
  const float4* P0 = (const float4*)(pcb  + (size_t)i*128);
  const float4* P1 = (const float4*)(pa0b + (size_t)i*128);
  const float4* P2 = (const float4*)(pa1b + (size_t)i*128);
  for (int b=0;b<32;b++){
    float4 v0=P0[b], v1=P1[b], v2=P2[b];
    c  += v0.x+v0.y+v0.z+v0.w;
    s0 += v1.x+v1.y+v1.z+v1.w;
    s1 += v2.x+v2.y+v2.z+v2.w;
  }
  pair_cnt[i] = c;
  float inv = 1.f/fmaxf(c, 1.f);
  avg_attr[2*i]   = s0*inv;
  avg_attr[2*i+1] = s1*inv;
}

// dual scan: cnt->offs and intra->ioffs, one launch; csize histogram LDS-aggregated
__global__ __launch_bounds__(256) void k_scan_block2(const int* __restrict__ in1, const int* __restrict__ in2,
                                                     int* __restrict__ out1, int* __restrict__ out2,
                                                     int* __restrict__ bsum1, int* __restrict__ bsum2, int n,
                                                     const int* __restrict__ clus, int* __restrict__ csize){
  __shared__ int buf[256];
  __shared__ int lcs[NCLUS];
  int i = blockIdx.x*256 + threadIdx.x;
  if (threadIdx.x < NCLUS) lcs[threadIdx.x] = 0;
  __syncthreads();
  if (i < n) atomicAdd(&lcs[clus[i]], 1);
  int v = (i < n) ? in1[i] : 0;
  buf[threadIdx.x] = v; __syncthreads();
  for (int off=1; off<256; off<<=1){
    int t = (threadIdx.x>=off) ? buf[threadIdx.x-off] : 0;
    __syncthreads();
    buf[threadIdx.x] += t;
    __syncthreads();
  }
  if (i < n) out1[i] = buf[threadIdx.x] - v;
  if (threadIdx.x == 255) bsum1[blockIdx.x] = buf[255];
  __syncthreads();
  v = (i < n) ? in2[i] : 0;
  buf[threadIdx.x] = v; __syncthreads();
  for (int off=1; off<256; off<<=1){
    int t = (threadIdx.x>=off) ? buf[threadIdx.x-off] : 0;
    __syncthreads();
    buf[threadIdx.x] += t;
    __syncthreads();
  }
  if (i < n) out2[i] = buf[threadIdx.x] - v;
  if (threadIdx.x == 255) bsum2[blockIdx.x] = buf[255];
  __syncthreads();
  if (threadIdx.x < NCLUS){
    int c = lcs[threadIdx.x];
    if (c) atomicAdd(&csize[threadIdx.x], c);
  }
}

__global__ __launch_bounds__(512) void k_scan_bsum2(int* __restrict__ bsum1, int* __restrict__ bsum2, int nb){
  int* bs = blockIdx.x ? bsum2 : bsum1;
  __shared__ int buf[512];
  int v = (threadIdx.x < nb) ? bs[threadIdx.x] : 0;
  buf[threadIdx.x] = v; __syncthreads();
  for (int off=1; off<512; off<<=1){
    int t = (threadIdx.x>=off) ? buf[threadIdx.x-off] : 0;
    __syncthreads();
    buf[threadIdx.x] += t;
    __syncthreads();
  }
  if (threadIdx.x < nb) bs[threadIdx.x] = buf[threadIdx.x] - v;
}

__global__ __launch_bounds__(256) void k_scan_add2(int* __restrict__ out1, int* __restrict__ out2,
                                                   const int* __restrict__ bsum1, const int* __restrict__ bsum2,
                                                   int n, int total1, int total2){
  int* out = blockIdx.y ? out2 : out1;
  const int* bs = blockIdx.y ? bsum2 : bsum1;
  int total = blockIdx.y ? total2 : total1;
  int i = blockIdx.x*256 + threadIdx.x;
  if (i < n) out[i] += bs[i>>8];
  if (i == 0) out[n] = total;
}

// fill main CSR + intra CSR (no atomics on float data)
__global__ __launch_bounds__(256) void k_fill_csr(const int* __restrict__ ei, const int* __restrict__ clus,
                                                  const int* __restrict__ offs, const int* __restrict__ ioffs,
                                                  int* __restrict__ cursor, int* __restrict__ cursor2,
                                                  int2* __restrict__ csr, int* __restrict__ csr2){
  int e = blockIdx.x*256 + threadIdx.x;
  if (e >= NEDGES) return;
  int s = ei[e], d = ei[NEDGES+e];
  int pos = offs[d] + atomicAdd(&cursor[d], 1);
  csr[pos] = make_int2(s, e);
  if (clus[s] == clus[d]){
    int p2 = ioffs[d] + atomicAdd(&cursor2[d], 1);
    csr2[p2] = s;
  }
}

// per-node mean edge-attr (self-loop fill), from CSR
__global__ __launch_bounds__(256) void k_loopattr(const int* __restrict__ offs, const int2* __restrict__ csr,
                                                  const float* __restrict__ eattr, float* __restrict__ la){
  int n = blockIdx.x*256 + threadIdx.x;
  if (n >= NNODES) return;
  int b0 = offs[n], b1 = offs[n+1];
  float s0=0.f, s1=0.f;
  for (int i=b0; i<b1; ++i){
    int e = csr[i].y;
    float2 a = *reinterpret_cast<const float2*>(&eattr[2*e]);
    s0 += a.x; s1 += a.y;
  }
  float inv = 1.f/fmaxf((float)(b1-b0), 1.f);
  la[2*n] = s0*inv; la[2*n+1] = s1*inv;
}

// ---------------- weight converts + glt2(W' for agg GEMM) + AsAll/AdAll + M2, one kernel ----------------
__global__ __launch_bounds__(256) void k_wtall_m2(const float* __restrict__ W1, const float* __restrict__ W2,
                       const float* __restrict__ gcnW, const float* __restrict__ gat_lin,
                       unsigned short* __restrict__ W1t, unsigned short* __restrict__ W2t,
                       unsigned short* __restrict__ gcnWt, unsigned short* __restrict__ glt2,
                       const float* __restrict__ att_s, const float* __restrict__ att_d,
                       float* __restrict__ AsAll, float* __restrict__ AdAll,
                       const float* __restrict__ g_lin_e, const float* __restrict__ g_att_e,
                       const float* __restrict__ gat_lin_e, const float* __restrict__ gat_att_e,
                       float* __restrict__ M2g, float* __restrict__ M2){
  int i = blockIdx.x*256 + threadIdx.x;
  if (i < 229376){            // W1: K=896, N=256
    int n = i/896, k = i - n*896;
    W1t[i] = f2bf(W1[(size_t)k*256 + n]);
  } else if (i < 262144){     // W2: K=256, N=128
    int j = i - 229376; int n = j/256, k = j - n*256;
    W2t[j] = f2bf(W2[(size_t)k*128 + n]);
  } else if (i < 278528){     // gcnW: 128x128
    int j = i - 262144; int n = j/128, k = j - n*128;
    gcnWt[j] = f2bf(gcnW[(size_t)k*128 + n]);
  } else if (i < 475136){     // glt2: 3 x [128 d][512 hk]
    int j = i - 278528; int l = j >> 16; int r = j & 65535; int d = r >> 9; int hk = r & 511;
    glt2[j] = f2bf(0.25f * gat_lin[(size_t)l*65536 + (size_t)(hk & 127)*512 + (hk >> 7)*128 + d]);
  } else if (i < 478208){     // AsAll/AdAll: 3*128*4*2
    int j = i - 475136;
    int which = j & 1, h = (j >> 1) & 3, k = (j >> 3) & 127, l = j >> 10;
    const float* att = which ? att_d : att_s;
    float s = 0.f;
    for (int c=0;c<128;c++) s += gat_lin[(size_t)l*65536 + k*512 + h*128 + c] * att[l*512 + h*128 + c];
    float* dst = which ? AdAll : AsAll;
    dst[l*512 + k*4 + h] = s;
  } else if (i < 478240){     // M2 precompute
    int t = i - 478208;
    if (t < 8){
      int j = t >> 2, h = t & 3;
      float s = 0.f;
      for (int c=0;c<128;c++) s += g_lin_e[j*512 + h*128 + c] * g_att_e[h*128 + c];
      M2g[j*4+h] = s;
    } else {
      int u = t - 8; int l = u >> 3, j = (u >> 2) & 1, h = u & 3;
      float s = 0.f;
      for (int c=0;c<128;c++) s += gat_lin_e[l*1024 + j*512 + h*128 + c] * gat_att_e[l*512 + h*128 + c];
      M2[l*8 + j*4 + h] = s;
    }
  }
}

// ---------------- bf16 MFMA GEMM: C = act(A @ Bt^T + bias), 128x128 tile ----------------
// Staging via global_load_lds (async DMA): LDS layout kept linear per-wave (8 rows x 128B = 1KB),
// XOR swizzle realized by pre-swizzling the per-lane GLOBAL source column (cSw = cA ^ (row&7)).
template<int AF32, int CONCAT, int OUT, int RELU, int BIAS>
__global__ __launch_bounds__(256)
void k_mgemm(const void* __restrict__ Av, const float* __restrict__ A2,
             const unsigned short* __restrict__ Bt, const float* __restrict__ bias,
             void* __restrict__ Cv, int M, int N, int K, int K1)
{
  __shared__ unsigned short As[128*64];
  __shared__ unsigned short Bs[128*64];
  const int tid = threadIdx.x;
  const int lane = tid & 63, w = tid >> 6;
  const int row0 = blockIdx.x*128, col0 = blockIdx.y*128;
  const int wm = w >> 1, wn = w & 1;
  const int l15 = lane & 15, l4 = lane >> 4;
  f32x4 acc[4][4];
  #pragma unroll
  for (int i=0;i<4;i++)
    #pragma unroll
    for (int n=0;n<4;n++) acc[i][n] = (f32x4){0.f,0.f,0.f,0.f};

  const int rr0 = w*32 + (lane>>3);
  const int cA = lane & 7;
  const int cSw = cA ^ (rr0 & 7);    // swizzled source chunk (rr&7 constant over i since i*8 multiple of 8)

  for (int kt = 0; kt < K; kt += 64){
    float4 fa[4][2];
    if (AF32){
      #pragma unroll
      for (int i=0;i<4;i++){
        int rr = rr0 + i*8;
        int ga = row0 + rr; ga = (ga < M) ? ga : (M-1);
        int gk = kt + cA*8;
        const float* src;
        if (CONCAT && gk >= K1) src = A2 + (size_t)ga*(K-K1) + (gk - K1);
        else                    src = ((const float*)Av) + (size_t)ga*(CONCAT ? K1 : K) + gk;
        fa[i][0] = ((const float4*)src)[0];
        fa[i][1] = ((const float4*)src)[1];
      }
    }
    __syncthreads();   // prev tile MFMA reads done; LDS writable
    #pragma unroll
    for (int i=0;i<4;i++){
      int rr = rr0 + i*8;
      int gb = col0 + rr; gb = (gb < N) ? gb : (N-1);
      gload_lds16(Bt + (size_t)gb*K + kt + cSw*8, &Bs[(w*32 + i*8)*64]);
      if (!AF32){
        int ga = row0 + rr; ga = (ga < M) ? ga : (M-1);
        gload_lds16((const unsigned short*)Av + (size_t)ga*K + kt + cSw*8, &As[(w*32 + i*8)*64]);
      }
    }
    if (AF32){
      #pragma unroll
      for (int i=0;i<4;i++){
        int rr = rr0 + i*8;
        int ch = cA ^ (rr & 7);
        uint4 va = make_uint4(pk2(fa[i][0].x,fa[i][0].y), pk2(fa[i][0].z,fa[i][0].w),
                              pk2(fa[i][1].x,fa[i][1].y), pk2(fa[i][1].z,fa[i][1].w));
        *reinterpret_cast<uint4*>(&As[rr*64 + ch*8]) = va;
      }
    }
    __syncthreads();   // drains vmcnt (async LDS DMA) + lgkm
    #pragma unroll
    for (int k0=0;k0<2;k0++){
      bf16x8 af[4], bff[4];
      #pragma unroll
      for (int i=0;i<4;i++){
        int row = wm*64 + i*16 + l15;
        int ch = (k0*4 + l4) ^ (row & 7);
        af[i] = *reinterpret_cast<const bf16x8*>(&As[row*64 + ch*8]);
      }
      #pragma unroll
      for (int n=0;n<4;n++){
        int row = wn*64 + n*16 + l15;
        int ch = (k0*4 + l4) ^ (row & 7);
        bff[n] = *reinterpret_cast<const bf16x8*>(&Bs[row*64 + ch*8]);
      }
      #pragma unroll
      for (int i=0;i<4;i++)
        #pragma unroll
        for (int n=0;n<4;n++)
          acc[i][n] = __builtin_amdgcn_mfma_f32_16x16x32_bf16(af[i], bff[n], acc[i][n], 0, 0, 0);
    }
  }
  // C store
  #pragma unroll
  for (int i=0;i<4;i++){
    int rowb = row0 + wm*64 + i*16 + l4*4;
    #pragma unroll
    for (int n=0;n<4;n++){
      int col = col0 + wn*64 + n*16 + l15;
      float bv = BIAS ? bias[col] : 0.f;
      #pragma unroll
      for (int r=0;r<4;r++){
        int row = rowb + r;
        if (row < M){
          float y = acc[i][n][r] + bv;
          if (RELU) y = fmaxf(y, 0.f);
          if (OUT == 1)      ((unsigned short*)Cv)[(size_t)row*N + col] = f2bf(y);
          else if (OUT == 2) ((__half*)Cv)[(size_t)row*N + col] = __float2half(y);
          else               ((float*)Cv)[(size_t)row*N + col] = y;
        }
      }
    }
  }
}

// ---------------- f32 SGEMM (tiny pooled GEMM only) ----------------
template<int CONCAT, int ACT>
__global__ __launch_bounds__(256)
void k_sgemm(const float* __restrict__ A, const float* __restrict__ A2,
             const float* __restrict__ B, const float* __restrict__ bias,
             float* __restrict__ C, int M, int N, int K, int K1)
{
  __shared__ float As[8][128];
  __shared__ float Bs[8][128];
  int row0 = blockIdx.x*128, col0 = blockIdx.y*128;
  int tid = threadIdx.x;
  int tx = tid & 15, ty = tid >> 4;
  float acc[8][8];
  #pragma unroll
  for (int i=0;i<8;i++)
    #pragma unroll
    for (int j=0;j<8;j++) acc[i][j]=0.f;

  int arow = tid >> 1, acol = (tid & 1)*4;
  int brow = tid >> 5, bcol = (tid & 31)*4;
  int K2 = K - K1;

  for (int k0=0; k0<K; k0+=8){
    float4 av = make_float4(0.f,0.f,0.f,0.f);
    int gr = row0 + arow, gk = k0 + acol;
    if (gr < M){
      if (CONCAT){
        if (gk < K1) av = *reinterpret_cast<const float4*>(&A [(size_t)gr*K1 + gk]);
        else         av = *reinterpret_cast<const float4*>(&A2[(size_t)gr*K2 + (gk-K1)]);
      } else {
        av = *reinterpret_cast<const float4*>(&A[(size_t)gr*K + gk]);
      }
    }
    As[acol+0][arow]=av.x; As[acol+1][arow]=av.y; As[acol+2][arow]=av.z; As[acol+3][arow]=av.w;
    float4 bv = *reinterpret_cast<const float4*>(&B[(size_t)(k0+brow)*N + col0 + bcol]);
    *reinterpret_cast<float4*>(&Bs[brow][bcol]) = bv;
    __syncthreads();
    #pragma unroll
    for (int kk=0; kk<8; ++kk){
      float a[8], b[8];
      *(float4*)&a[0] = *(float4*)&As[kk][ty*8];
      *(float4*)&a[4] = *(float4*)&As[kk][ty*8+4];
      *(float4*)&b[0] = *(float4*)&Bs[kk][tx*8];
      *(float4*)&b[4] = *(float4*)&Bs[kk][tx*8+4];
      #pragma unroll
      for (int i=0;i<8;i++)
        #pragma unroll
        for (int j=0;j<8;j++) acc[i][j] = fmaf(a[i], b[j], acc[i][j]);
    }
    __syncthreads();
  }
  #pragma unroll
  for (int i=0;i<8;i++){
    int r = row0 + ty*8 + i;
    if (r >= M) continue;
    #pragma unroll
    for (int j4=0;j4<2;j4++){
      int c = col0 + tx*8 + j4*4;
      float4 v = make_float4(acc[i][j4*4], acc[i][j4*4+1], acc[i][j4*4+2], acc[i][j4*4+3]);
      if (bias){
        float4 bb = *reinterpret_cast<const float4*>(&bias[c]);
        v = f4add(v, bb);
      }
      if (ACT == 1){
        v.x=fmaxf(v.x,0.f); v.y=fmaxf(v.y,0.f); v.z=fmaxf(v.z,0.f); v.w=fmaxf(v.w,0.f);
      }
      *reinterpret_cast<float4*>(&C[(size_t)r*N + c]) = v;
    }
  }
}

// ---------------- GCN aggregation (intra-CSR: only intra-cluster edges) ----------------
__global__ __launch_bounds__(256) void k_gcn(const unsigned short* __restrict__ XWh, const int* __restrict__ ioffs,
                      const int* __restrict__ csr2, const int* __restrict__ intra,
                      const float* __restrict__ gcn_b, float* __restrict__ Xc)
{
  int wid  = (blockIdx.x*blockDim.x + threadIdx.x) >> 6;
  int lane = threadIdx.x & 63;
  int nw   = (gridDim.x*blockDim.x) >> 6;
  for (int n = wid; n < NNODES; n += nw){
    int cntn = intra[n];
    float deg = 1.f + (float)cntn;
    float dinv_n = rsqrtf(deg);
    __half2 hx = *reinterpret_cast<const __half2*>(XWh + (size_t)n*128 + lane*2);
    float2 acc;
    acc.x = __low2float(hx)/deg; acc.y = __high2float(hx)/deg;
    int io0 = ioffs[n];
    for (int j=0; j<cntn; ++j){
      int s = csr2[io0+j];
      float w = dinv_n * rsqrtf(1.f + (float)intra[s]);
      __half2 hs = *reinterpret_cast<const __half2*>(XWh + (size_t)s*128 + lane*2);
      acc.x = fmaf(w, __low2float(hs), acc.x);
      acc.y = fmaf(w, __high2float(hs), acc.y);
    }
    float2 bb = *reinterpret_cast<const float2*>(&gcn_b[lane*2]);
    acc.x += bb.x; acc.y += bb.y;
    *reinterpret_cast<float2*>(&Xc[(size_t)n*128 + lane*2]) = acc;
  }
}

// ---------------- cluster pooling: LDS partials + reduce ----------------
__global__ __launch_bounds__(256) void k_pool1(const float* __restrict__ Xc, const int* __restrict__ clus,
                                               float* __restrict__ part){
  __shared__ float lp[8192];
  for (int i=threadIdx.x; i<8192; i+=256) lp[i]=0.f;
  __syncthreads();
  int d = threadIdx.x & 127, rg = threadIdx.x >> 7;
  int n0 = blockIdx.x*200;
  for (int n = n0+rg; n < n0+200; n += 2){
    int c = clus[n];
    atomicAdd(&lp[c*128 + d], Xc[(size_t)n*128 + d]);
  }
  __syncthreads();
  for (int i=threadIdx.x; i<8192; i+=256) part[(size_t)blockIdx.x*8192 + i] = lp[i];
}
__global__ __launch_bounds__(256) void k_pool2(const float* __restrict__ part, const int* __restrict__ csize,
                                               float* __restrict__ pooled){
  int i = blockIdx.x*256 + threadIdx.x; // 8192
  float s = 0.f;
  for (int b=0;b<400;b++) s += part[(size_t)b*8192 + i];
  pooled[i] = s / fmaxf((float)csize[i>>7], 1.f);
}

// ---------------- cluster GAT small kernels fused: block0=asc, block1=loop_c ----------------
__global__ __launch_bounds__(256) void k_cluster_small(const float* __restrict__ xh_c,
                     const float* __restrict__ g_att_s, const float* __restrict__ g_att_d,
                     float* __restrict__ a_s_c, float* __restrict__ a_d_c,
                     const float* __restrict__ pair_cnt, const float* __restrict__ avg_attr,
                     float* __restrict__ loop_c){
  int t = threadIdx.x;
  if (blockIdx.x == 0){
    int s = t >> 2, h = t & 3;
    float ss=0.f, sd=0.f;
    for (int c=0;c<128;c++){
      float x = xh_c[s*512 + h*128 + c];
      ss += x * g_att_s[h*128 + c];
      sd += x * g_att_d[h*128 + c];
    }
    a_s_c[s*4+h] = ss; a_d_c[s*4+h] = sd;
  } else {
    if (t >= NCLUS) return;
    int d = t;
    float ic=0.f, l0=0.f, l1=0.f;
    for (int s=0;s<NCLUS;s++){
      int k = s*NCLUS + d;
      if (pair_cnt[k] > 0.f){ ic += 1.f; l0 += avg_attr[2*k]; l1 += avg_attr[2*k+1]; }
    }
    float inv = 1.f / fmaxf(ic, 1.f);
    loop_c[2*d] = l0*inv; loop_c[2*d+1] = l1*inv;
  }
}

__global__ __launch_bounds__(128) void k_clout(const float* __restrict__ a_s_c, const float* __restrict__ a_d_c,
                       const float* __restrict__ loop_c, const float* __restrict__ M2g,
                       const float* __restrict__ pair_cnt, const float* __restrict__ avg_attr,
                       const float* __restrict__ xh_c, const float* __restrict__ g_bias,
                       float* __restrict__ cl_out)
{
  int d = blockIdx.x;
  __shared__ float p[NCLUS*4];
  int t = threadIdx.x;
  if (t < NCLUS){
    int s = t;
    for (int h=0; h<4; ++h){
      float v;
      if (s == d){
        v = lrelu(a_s_c[d*4+h] + a_d_c[d*4+h] + loop_c[2*d]*M2g[h] + loop_c[2*d+1]*M2g[4+h]);
      } else if (pair_cnt[s*NCLUS+d] > 0.f){
        int k = s*NCLUS + d;
        v = lrelu(a_s_c[s*4+h] + a_d_c[d*4+h] + avg_attr[2*k]*M2g[h] + avg_attr[2*k+1]*M2g[4+h]);
      } else {
        v = -INFINITY;
      }
      p[s*4+h] = v;
    }
  }
  __syncthreads();
  if (t < 4){
    int h = t;
    float m = -INFINITY;
    for (int s=0;s<NCLUS;s++) m = fmaxf(m, p[s*4+h]);
    float sum = 0.f;
    for (int s=0;s<NCLUS;s++){
      float a = p[s*4+h];
      float e = (a == -INFINITY) ? 0.f : expf(a - m);
      p[s*4+h] = e; sum += e;
    }
    float inv = 1.f/sum;
    for (int s=0;s<NCLUS;s++) p[s*4+h] *= inv;
  }
  __syncthreads();
  int c = t;
  float acc = 0.f;
  for (int s=0;s<NCLUS;s++){
    #pragma unroll
    for (int h=0;h<4;h++) acc += p[s*4+h]*xh_c[s*512 + h*128 + c];
  }
  cl_out[d*128 + c] = 0.25f*acc + g_bias[c];
}

// Xcomb = Xc + cl_out[clus]; write f16 X + fused a_s/a_d dots (layer 0)
__global__ __launch_bounds__(256) void k_xcomb(const float* __restrict__ Xc, const float* __restrict__ cl_out,
                                               const int* __restrict__ clus, __half* __restrict__ xh16,
                                               const float* __restrict__ AsA, const float* __restrict__ AdA,
                                               float* __restrict__ a_s, float* __restrict__ a_d){
  int i = blockIdx.x*256 + threadIdx.x;
  int stride = gridDim.x*256;
  for (; i < NNODES*32; i += stride){
    int n = i >> 5, d4 = i & 31;
    float4 a = ((const float4*)Xc)[i];
    float4 b = ((const float4*)&cl_out[clus[n]*128])[d4];
    float4 r = f4add(a, b);
    __half2 hv[2];
    hv[0] = __floats2half2_rn(r.x, r.y);
    hv[1] = __floats2half2_rn(r.z, r.w);
    ((uint2*)xh16)[i] = *reinterpret_cast<uint2*>(hv);
    float4 ps = make_float4(0,0,0,0), pd = make_float4(0,0,0,0);
    const float4* As4 = (const float4*)(AsA) + d4*4;
    const float4* Ad4 = (const float4*)(AdA) + d4*4;
    ps = f4fma1(r.x, As4[0], ps); ps = f4fma1(r.y, As4[1], ps);
    ps = f4fma1(r.z, As4[2], ps); ps = f4fma1(r.w, As4[3], ps);
    pd = f4fma1(r.x, Ad4[0], pd); pd = f4fma1(r.y, Ad4[1], pd);
    pd = f4fma1(r.z, Ad4[2], pd); pd = f4fma1(r.w, Ad4[3], pd);
    #pragma unroll
    for (int m=16; m>=1; m>>=1){
      ps.x += __shfl_xor(ps.x, m); ps.y += __shfl_xor(ps.y, m);
      ps.z += __shfl_xor(ps.z, m); ps.w += __shfl_xor(ps.w, m);
      pd.x += __shfl_xor(pd.x, m); pd.y += __shfl_xor(pd.y, m);
      pd.z += __shfl_xor(pd.z, m); pd.w += __shfl_xor(pd.w, m);
    }
    if (d4 == 0){
      *reinterpret_cast<float4*>(&a_s[n*4]) = ps;
      *reinterpret_cast<float4*>(&a_d[n*4]) = pd;
    }
  }
}

// ---------------- GAT aggregation in X-space: 16-edge batched logits (1 exp/edge/group) + shfl broadcast ----------------
__global__ __launch_bounds__(256) void k_gat_x(const __half* __restrict__ Xh, const float* __restrict__ a_s,
                     const float* __restrict__ a_d, const float* __restrict__ eattr,
                     const int* __restrict__ offs, const int2* __restrict__ csr,
                     const float* __restrict__ la, const float* __restrict__ M2l,
                     unsigned short* __restrict__ agg)
{
  int wid  = (blockIdx.x*blockDim.x + threadIdx.x) >> 6;
  int lane = threadIdx.x & 63;
  int nw   = (gridDim.x*blockDim.x) >> 6;
  int h = lane >> 4;
  int j = lane & 15;
  int grpbase = h << 4;
  int kslot = j*8;
  float m2a = M2l[h], m2b = M2l[4+h];
  for (int n = wid; n < NNODES; n += nw){
    float adn = a_d[n*4+h];
    float pl = __expf(lrelu(a_s[n*4+h] + adn + la[2*n]*m2a + la[2*n+1]*m2b));
    uint4 u0 = *reinterpret_cast<const uint4*>(Xh + (size_t)n*128 + kslot);
    __half2* x0 = reinterpret_cast<__half2*>(&u0);
    __half2 pl2 = __float2half2_rn(pl);
    __half2 acc0 = __hmul2(x0[0], pl2), acc1 = __hmul2(x0[1], pl2);
    __half2 acc2 = __hmul2(x0[2], pl2), acc3 = __hmul2(x0[3], pl2);
    int b0 = offs[n], b1 = offs[n+1];
    float dsum = 0.f;
    for (int base = b0; base < b1; base += 16){
      int cnt = min(16, b1 - base);
      // batch phase: lane j computes edge (base+j)'s logit ONCE per group
      float pe_j = 0.f; int sx_j = 0;
      if (j < cnt){
        int2 se = csr[base + j];
        sx_j = se.x;
        float2 ea = *reinterpret_cast<const float2*>(&eattr[2*se.y]);
        float asv = a_s[se.x*4+h];
        pe_j = __expf(lrelu(asv + adn + ea.x*m2a + ea.y*m2b));
      }
      dsum += pe_j;
      // accumulate phase: shfl-broadcast src/pe; 2-deep X-row prefetch
      uint4 uA = make_uint4(0,0,0,0), uB = make_uint4(0,0,0,0);
      if (cnt > 0){
        int sx = __shfl(sx_j, grpbase);
        uA = *reinterpret_cast<const uint4*>(Xh + (size_t)sx*128 + kslot);
      }
      if (cnt > 1){
        int sx = __shfl(sx_j, grpbase+1);
        uB = *reinterpret_cast<const uint4*>(Xh + (size_t)sx*128 + kslot);
      }
      for (int jj=0; jj<cnt; ++jj){
        uint4 u = uA; uA = uB;
        if (jj+2 < cnt){
          int sx = __shfl(sx_j, grpbase+jj+2);
          uB = *reinterpret_cast<const uint4*>(Xh + (size_t)sx*128 + kslot);
        }
        float pe = __shfl(pe_j, grpbase+jj);
        __half2 pe2 = __float2half2_rn(pe);
        __half2* y = reinterpret_cast<__half2*>(&u);
        acc0 = __hfma2(y[0], pe2, acc0);
        acc1 = __hfma2(y[1], pe2, acc1);
        acc2 = __hfma2(y[2], pe2, acc2);
        acc3 = __hfma2(y[3], pe2, acc3);
      }
    }
    // group (16-lane) reduce of edge-prob sum
    dsum += __shfl_xor(dsum, 1);
    dsum += __shfl_xor(dsum, 2);
    dsum += __shfl_xor(dsum, 4);
    dsum += __shfl_xor(dsum, 8);
    float sc = 1.f/(pl + dsum);   // 0.25 mean folded into glt2
    uint4 w;
    w.x = pk2(__low2float(acc0)*sc, __high2float(acc0)*sc);
    w.y = pk2(__low2float(acc1)*sc, __high2float(acc1)*sc);
    w.z = pk2(__low2float(acc2)*sc, __high2float(acc2)*sc);
    w.w = pk2(__low2float(acc3)*sc, __high2float(acc3)*sc);
    *reinterpret_cast<uint4*>(agg + (size_t)n*512 + h*128 + kslot) = w;
  }
}

// ---------------- graph norm: colstat + finstat fused (threadfence last-block pattern) ----------------
__global__ __launch_bounds__(256) void k_colstat_fin(const __half* __restrict__ X, float* __restrict__ part,
                         int* __restrict__ counter,
                         const float* __restrict__ w, const float* __restrict__ b, const float* __restrict__ ms,
                         float* __restrict__ scaleA, float* __restrict__ shiftB){
  int d = threadIdx.x & 127;
  int rg = threadIdx.x >> 7;
  float s1=0.f, s2=0.f;
  for (int n = blockIdx.x*2 + rg; n < NNODES; n += 512){
    float v = __half2float(X[(size_t)n*128 + d]);
    s1 += v; s2 = fmaf(v, v, s2);
  }
  __shared__ float sh[512];
  sh[threadIdx.x] = s1; sh[256+threadIdx.x] = s2;
  __syncthreads();
  if (threadIdx.x < 128){
    s1 = sh[threadIdx.x] + sh[threadIdx.x+128];
    s2 = sh[256+threadIdx.x] + sh[256+threadIdx.x+128];
    part[blockIdx.x*256 + d]       = s1;
    part[blockIdx.x*256 + 128 + d] = s2;
  }
  __threadfence();
  __syncthreads();
  __shared__ int isLast;
  if (threadIdx.x == 0){
    int done = atomicAdd(counter, 1);
    isLast = (done == 255);
  }
  __syncthreads();
  if (isLast){
    __threadfence();
    if (threadIdx.x < 128){
      int dd = threadIdx.x;
      float t1=0.f, t2=0.f;
      for (int bq=0; bq<256; bq++){ t1 += part[bq*256 + dd]; t2 += part[bq*256 + 128 + dd]; }
      float mean = t1 * (1.f/NNODES);
      float ex2  = t2 * (1.f/NNODES);
      float m = ms[dd];
      float var = ex2 - m*mean*mean*(2.f - m);
      float sc = w[dd] * rsqrtf(var + EPSV);
      scaleA[dd] = sc;
      shiftB[dd] = b[dd] - sc*m*mean;
    }
    if (threadIdx.x == 0) *counter = 0;
  }
}

// norm + residual(f16) + ELU; write f16 X + fused next-layer a_s/a_d (or f32 final output)
__global__ __launch_bounds__(256) void k_normelu(const __half* __restrict__ o, __half* __restrict__ xh16,
                         const float* __restrict__ scaleA, const float* __restrict__ shiftB,
                         const float* __restrict__ AsA, const float* __restrict__ AdA,
                         float* __restrict__ a_s, float* __restrict__ a_d,
                         float* __restrict__ fout){
  int i = blockIdx.x*256 + threadIdx.x;
  int stride = gridDim.x*256;
  for (; i < NNODES*32; i += stride){
    int n = i >> 5, d4 = i & 31;
    uint2 ou = ((const uint2*)o)[i];
    __half2* oh = reinterpret_cast<__half2*>(&ou);
    float o0 = __low2float(oh[0]), o1 = __high2float(oh[0]);
    float o2 = __low2float(oh[1]), o3 = __high2float(oh[1]);
    uint2 xu = ((const uint2*)xh16)[i];
    __half2* xh = reinterpret_cast<__half2*>(&xu);
    float xi0 = __low2float(xh[0]), xi1 = __high2float(xh[0]);
    float xi2 = __low2float(xh[1]), xi3 = __high2float(xh[1]);
    float4 sc = ((const float4*)scaleA)[d4];
    float4 sh = ((const float4*)shiftB)[d4];
    float4 r; float y;
    y = fmaf(sc.x, o0, sh.x) + xi0; r.x = y > 0.f ? y : expm1f(y);
    y = fmaf(sc.y, o1, sh.y) + xi1; r.y = y > 0.f ? y : expm1f(y);
    y = fmaf(sc.z, o2, sh.z) + xi2; r.z = y > 0.f ? y : expm1f(y);
    y = fmaf(sc.w, o3, sh.w) + xi3; r.w = y > 0.f ? y : expm1f(y);
    if (fout){
      ((float4*)fout)[i] = r;
    } else {
      __half2 hv[2];
      hv[0] = __floats2half2_rn(r.x, r.y);
      hv[1] = __floats2half2_rn(r.z, r.w);
      ((uint2*)xh16)[i] = *reinterpret_cast<uint2*>(hv);
      float4 ps = make_float4(0,0,0,0), pd = make_float4(0,0,0,0);
      const float4* As4 = (const float4*)(AsA) + d4*4;
      const float4* Ad4 = (const float4*)(AdA) + d4*4;
      ps = f4fma1(r.x, As4[0], ps); ps = f4fma1(r.y, As4[1], ps);
      ps = f4fma1(r.z, As4[2], ps); ps = f4fma1(r.w, As4[3], ps);
      pd = f4fma1(r.x, Ad4[0], pd); pd = f4fma1(r.y, Ad4[1], pd);
      pd = f4fma1(r.z, Ad4[2], pd); pd = f4fma1(r.w, Ad4[3], pd);
      #pragma unroll
      for (int m=16; m>=1; m>>=1){
        ps.x += __shfl_xor(ps.x, m); ps.y += __shfl_xor(ps.y, m);
        ps.z += __shfl_xor(ps.z, m); ps.w += __shfl_xor(ps.w, m);
        pd.x += __shfl_xor(pd.x, m); pd.y += __shfl_xor(pd.y, m);
        pd.z += __shfl_xor(pd.z, m); pd.w += __shfl_xor(pd.w, m);
      }
      if (d4 == 0){
        *reinterpret_cast<float4*>(&a_s[n*4]) = ps;
        *reinterpret_cast<float4*>(&a_d[n*4]) = pd;
      }
    }
  }
}

// ---------------- host launch ----------------
extern "C" void kernel_launch(void* const* d_in, const int* in_sizes, int n_in,
                              void* d_out, int out_size, void* d_ws, size_t ws_size,
                              hipStream_t stream)
{
  const float* extra    = (const float*)d_in[0];
  const int*   ei       = (const int*)  d_in[1];
  const float* eattr    = (const float*)d_in[2];
  const int*   clus     = (const int*)  d_in[3];
  const float* user     = (const float*)d_in[4];
  const float* item     = (const float*)d_in[5];
  const float* W1       = (const float*)d_in[6];
  const float* b1       = (const float*)d_in[7];
  const float* W2       = (const float*)d_in[8];
  const float* b2       = (const float*)d_in[9];
  const float* gcnW     = (const float*)d_in[10];
  const float* gcnb     = (const float*)d_in[11];
  const float* g_lin    = (const float*)d_in[12];
  const float* g_lin_e  = (const float*)d_in[13];
  const float* g_att_s  = (const float*)d_in[14];
  const float* g_att_d  = (const float*)d_in[15];
  const float* g_att_e  = (const float*)d_in[16];
  const float* g_bias   = (const float*)d_in[17];
  const float* gat_lin  = (const float*)d_in[18];
  const float* gat_lin_e= (const float*)d_in[19];
  const float* gat_att_s= (const float*)d_in[20];
  const float* gat_att_d= (const float*)d_in[21];
  const float* gat_att_e= (const float*)d_in[22];
  const float* gat_bias = (const float*)d_in[23];
  const float* nw_      = (const float*)d_in[24];
  const float* nb_      = (const float*)d_in[25];
  const float* nms_     = (const float*)d_in[26];

  char* ws = (char*)d_ws;
  size_t off = 0;
  auto alloc = [&](size_t bytes)->char*{
    char* p = ws + off;
    off += (bytes + 255) & ~size_t(255);
    return p;
  };

  float* bufX = (float*)alloc((size_t)NNODES*128*4);
  float* bufY = (float*)alloc((size_t)NNODES*128*4);
  float* bufZ = (float*)alloc((size_t)NNODES*128*4);
  char* big = alloc((size_t)112*1024*1024);
  __half* Xh16          = (__half*)big;
  unsigned short* agg   = (unsigned short*)(big + (size_t)22*1024*1024);
  unsigned short* Hbf   = (unsigned short*)(big + (size_t)22*1024*1024);
  float* pcb  = (float*)(big + (size_t)22*1024*1024);
  float* pa0b = pcb  + 4096*128;
  float* pa1b = pa0b + 4096*128;
  float* ppart = (float*)(big + (size_t)40*1024*1024);
  int* offs   = (int*)alloc((NNODES+1)*4);
  int* ioffs  = (int*)alloc((NNODES+1)*4);
  int* bsum   = (int*)alloc(1024*4);
  int* bsum2  = (int*)alloc(1024*4);
  int2* csr   = (int2*)alloc((size_t)NEDGES*8);
  int* csr2   = (int*)alloc((size_t)NEDGES*4);
  float* a_s  = (float*)alloc((size_t)NNODES*4*4);
  float* a_d  = (float*)alloc((size_t)NNODES*4*4);
  float* la   = (float*)alloc((size_t)NNODES*2*4);
  // zeroed-per-call region (single memset)
  char* zero0 = ws + off;
  int*   cnt      = (int*)  alloc((size_t)NNODES*4);
  int*   intra    = (int*)  alloc((size_t)NNODES*4);
  int*   cursor   = (int*)  alloc((size_t)NNODES*4);
  int*   cursor2  = (int*)  alloc((size_t)NNODES*4);
  int*   csize    = (int*)  alloc(256*4);
  int*   lcounter = (int*)  alloc(256);
  size_t zbytes = (size_t)((ws + off) - zero0);
  // small buffers
  float* pooled= (float*)alloc(8192*4);
  float* M2g   = (float*)alloc(8*4);
  float* M2    = (float*)alloc(24*4);
  float* AsAll = (float*)alloc(3*512*4);
  float* AdAll = (float*)alloc(3*512*4);
  float* pair_cnt = (float*)alloc(4096*4);
  float* avg_attr = (float*)alloc(8192*4);
  float* loop_c   = (float*)alloc(128*4);
  float* xh_c     = (float*)alloc(64*512*4);
  float* a_s_c    = (float*)alloc(256*4);
  float* a_d_c    = (float*)alloc(256*4);
  float* cl_out   = (float*)alloc(64*128*4);
  float* colpart  = (float*)alloc(256*256*4);
  float* scaleA   = (float*)alloc(128*4);
  float* shiftB   = (float*)alloc(128*4);
  unsigned short* W1t  = (unsigned short*)alloc((size_t)896*256*2);
  unsigned short* W2t  = (unsigned short*)alloc((size_t)256*128*2);
  unsigned short* gcnWt= (unsigned short*)alloc((size_t)128*128*2);
  unsigned short* glt2 = (unsigned short*)alloc((size_t)3*128*512*2);
  if (off > ws_size) return;

  hipMemsetAsync(zero0, 0, zbytes, stream);

  const int NB = (NNODES+255)/256;
  // phase 0: pair hist + cnt/intra, reduce; fused dual scans (LDS csize); fill; gather la
  k_pairhist<<<128, 1024, 0, stream>>>(ei, eattr, clus, cnt, intra, pcb, pa0b, pa1b);
  k_pairreduce<<<64, 64, 0, stream>>>(pcb, pa0b, pa1b, pair_cnt, avg_attr);
  k_scan_block2<<<NB, 256, 0, stream>>>(cnt, intra, offs, ioffs, bsum, bsum2, NNODES, clus, csize);
  k_scan_bsum2<<<2, 512, 0, stream>>>(bsum, bsum2, NB);
  {
    dim3 ga(NB, 2);
    k_scan_add2<<<ga, 256, 0, stream>>>(offs, ioffs, bsum, bsum2, NNODES, NEDGES, 0);
  }
  k_fill_csr<<<(NEDGES+255)/256, 256, 0, stream>>>(ei, clus, offs, ioffs, cursor, cursor2, csr, csr2);
  k_loopattr<<<NB, 256, 0, stream>>>(offs, csr, eattr, la);

  // weight conversions + glt2 + AsAll/AdAll + M2 (one kernel)
  k_wtall_m2<<<1869, 256, 0, stream>>>(W1, W2, gcnW, gat_lin, W1t, W2t, gcnWt, glt2,
                                       gat_att_s, gat_att_d, AsAll, AdAll,
                                       g_lin_e, g_att_e, gat_lin_e, gat_att_e, M2g, M2);

  // enrichment MLP (bf16 MFMA, f32-A fused conversion); Hbf reuses dead pairhist region
  {
    dim3 g1((N_ITEMS+127)/128, 2);
    k_mgemm<1,1,1,1,1><<<g1, 256, 0, stream>>>((const void*)item, extra, W1t, b1, (void*)Hbf,
                                               N_ITEMS, 256, 896, 128);
    dim3 g2((N_ITEMS+127)/128, 1);
    k_mgemm<0,0,0,0,1><<<g2, 256, 0, stream>>>((const void*)Hbf, nullptr, W2t, b2,
                                               (void*)(bufX + (size_t)N_USERS*128),
                                               N_ITEMS, 128, 256, 0);
  }
  hipMemcpyAsync(bufX, user, (size_t)N_USERS*128*4, hipMemcpyDeviceToDevice, stream);

  // cluster GCN: XW (f16) = X @ gcnW; aggregate over intra-CSR only
  {
    dim3 g3((NNODES+127)/128, 1);
    k_mgemm<1,0,2,0,0><<<g3, 256, 0, stream>>>((const void*)bufX, nullptr, gcnWt, nullptr, (void*)bufY,
                                               NNODES, 128, 128, 0);
  }
  k_gcn<<<5000, 256, 0, stream>>>((const unsigned short*)bufY, ioffs, csr2, intra, gcnb, bufZ);

  // pooling (LDS partials) + cluster GAT
  k_pool1<<<400, 256, 0, stream>>>(bufZ, clus, ppart);
  k_pool2<<<32, 256, 0, stream>>>(ppart, csize, pooled);
  {
    dim3 g4(1, 4);
    k_sgemm<0,0><<<g4, 256, 0, stream>>>(pooled, nullptr, g_lin, nullptr, xh_c, 64, 512, 128, 0);
  }
  k_cluster_small<<<2, 256, 0, stream>>>(xh_c, g_att_s, g_att_d, a_s_c, a_d_c, pair_cnt, avg_attr, loop_c);
  k_clout<<<64, 128, 0, stream>>>(a_s_c, a_d_c, loop_c, M2g, pair_cnt, avg_attr, xh_c, g_bias, cl_out);
  k_xcomb<<<1280, 256, 0, stream>>>(bufZ, cl_out, clus, Xh16, AsAll, AdAll, a_s, a_d);

  // 3 GAT layers: k_gat_x (batched logits, X-space agg) -> agg @ glt2 GEMM (gload_lds)
  for (int l = 0; l < 3; ++l){
    k_gat_x<<<20000, 256, 0, stream>>>(Xh16, a_s, a_d, eattr, offs, csr, la, M2 + l*8, agg);
    {
      dim3 gg((NNODES+127)/128, 1);
      k_mgemm<0,0,2,0,1><<<gg, 256, 0, stream>>>((const void*)agg, nullptr, glt2 + (size_t)l*65536,
                                                 gat_bias + l*128, (void*)bufY, NNODES, 128, 512, 0);
    }
    k_colstat_fin<<<256, 256, 0, stream>>>((const __half*)bufY, colpart, lcounter,
                                           nw_ + l*128, nb_ + l*128, nms_ + l*128, scaleA, shiftB);
    k_normelu<<<1280, 256, 0, stream>>>((const __half*)bufY, Xh16, scaleA, shiftB,
                                        AsAll + (l+1 < 3 ? (l+1)*512 : 0),
                                        AdAll + (l+1 < 3 ? (l+1)*512 : 0),
                                        a_s, a_d,
                                        (l==2) ? (float*)d_out : nullptr);
  }
}

// Round 23
// 969.007 us; speedup vs baseline: 1.3175x; 1.0011x over previous
//
#include <hip/hip_runtime.h>
#include <hip/hip_fp16.h>
#include <math.h>

#define N_USERS 50000
#define N_ITEMS 30000
#define NNODES  80000
#define NEDGES  640000
#define NCLUS   64
#define NEG     0.2f
#define EPSV    1e-5f

typedef __attribute__((ext_vector_type(8))) short bf16x8;
typedef __attribute__((ext_vector_type(4))) float f32x4;

__device__ __forceinline__ float lrelu(float x){ return x > 0.f ? x : NEG*x; }

__device__ __forceinline__ unsigned short f2bf(float f){
  unsigned u = __float_as_uint(f);
  u += 0x7fffu + ((u>>16)&1u);
  return (unsigned short)(u>>16);
}
__device__ __forceinline__ unsigned pk2(float lo, float hi){
  return (unsigned)f2bf(lo) | ((unsigned)f2bf(hi) << 16);
}
__device__ __forceinline__ float4 f4add(float4 a, float4 b){
  return make_float4(a.x+b.x, a.y+b.y, a.z+b.z, a.w+b.w);
}
__device__ __forceinline__ float4 f4fma1(float s, float4 a, float4 b){
  return make_float4(fmaf(s,a.x,b.x), fmaf(s,a.y,b.y), fmaf(s,a.z,b.z), fmaf(s,a.w,b.w));
}
__device__ __forceinline__ void gload_lds16(const void* g, void* l){
  __builtin_amdgcn_global_load_lds(
    (const __attribute__((address_space(1))) unsigned int*)g,
    (__attribute__((address_space(3))) unsigned int*)l, 16, 0, 0);
}

// ---------------- phase 0: pair histogram (LDS-aggregated, 1024-thread blocks) ----------------
__global__ __launch_bounds__(1024) void k_pairhist(
    const int* __restrict__ ei, const float* __restrict__ eattr, const int* __restrict__ clus,
    int* __restrict__ cnt, int* __restrict__ intra,
    float* __restrict__ pcb, float* __restrict__ pa0b, float* __restrict__ pa1b)
{
  __shared__ float pc[4096];
  __shared__ float pa0[4096];
  __shared__ float pa1[4096];
  for (int i=threadIdx.x; i<4096; i+=1024){ pc[i]=0.f; pa0[i]=0.f; pa1[i]=0.f; }
  __syncthreads();
  for (int e = blockIdx.x*1024 + threadIdx.x; e < NEDGES; e += 128*1024){
    int s = ei[e], d = ei[NEDGES+e];
    int cu = clus[s], cv = clus[d];
    atomicAdd(&cnt[d], 1);
    if (cu == cv) { atomicAdd(&intra[d], 1); }
    else {
      float2 a = *reinterpret_cast<const float2*>(&eattr[2*e]);
      int k = cu*NCLUS + cv;
      atomicAdd(&pc[k], 1.f);
      atomicAdd(&pa0[k], a.x);
      atomicAdd(&pa1[k], a.y);
    }
  }
  __syncthreads();
  int b = blockIdx.x;
  for (int i=threadIdx.x; i<4096; i+=1024){
    pcb [i*128 + b] = pc[i];
    pa0b[i*128 + b] = pa0[i];
    pa1b[i*128 + b] = pa1[i];
  }
}

__global__ __launch_bounds__(64) void k_pairreduce(
    const float* __restrict__ pcb, const float* __restrict__ pa0b, const float* __restrict__ pa1b,
    float* __restrict__ pair_cnt, float* __restrict__ avg_attr)
{
  int i = blockIdx.x*64 + threadIdx.x;  // 4096 total over grid 64
  float c=0.f, s0=0.f, s1=0.f;
  const float4* P0 = (const float4*)(pcb  + (size_t)i*128);
  const float4* P1 = (const float4*)(pa0b + (size_t)i*128);
  const float4* P2 = (const float4*)(pa1b + (size_t)i*128);
  for (int b=0;b<32;b++){
    float4 v0=P0[b], v1=P1[b], v2=P2[b];
    c  += v0.x+v0.y+v0.z+v0.w;
    s0 += v1.x+v1.y+v1.z+v1.w;
    s1 += v2.x+v2.y+v2.z+v2.w;
  }
  pair_cnt[i] = c;
  float inv = 1.f/fmaxf(c, 1.f);
  avg_attr[2*i]   = s0*inv;
  avg_attr[2*i+1] = s1*inv;
}

// dual scan: cnt->offs and intra->ioffs, one launch; csize histogram LDS-aggregated
__global__ __launch_bounds__(256) void k_scan_block2(const int* __restrict__ in1, const int* __restrict__ in2,
                                                     int* __restrict__ out1, int* __restrict__ out2,
                                                     int* __restrict__ bsum1, int* __restrict__ bsum2, int n,
                                                     const int* __restrict__ clus, int* __restrict__ csize){
  __shared__ int buf[256];
  __shared__ int lcs[NCLUS];
  int i = blockIdx.x*256 + threadIdx.x;
  if (threadIdx.x < NCLUS) lcs[threadIdx.x] = 0;
  __syncthreads();
  if (i < n) atomicAdd(&lcs[clus[i]], 1);
  int v = (i < n) ? in1[i] : 0;
  buf[threadIdx.x] = v; __syncthreads();
  for (int off=1; off<256; off<<=1){
    int t = (threadIdx.x>=off) ? buf[threadIdx.x-off] : 0;
    __syncthreads();
    buf[threadIdx.x] += t;
    __syncthreads();
  }
  if (i < n) out1[i] = buf[threadIdx.x] - v;
  if (threadIdx.x == 255) bsum1[blockIdx.x] = buf[255];
  __syncthreads();
  v = (i < n) ? in2[i] : 0;
  buf[threadIdx.x] = v; __syncthreads();
  for (int off=1; off<256; off<<=1){
    int t = (threadIdx.x>=off) ? buf[threadIdx.x-off] : 0;
    __syncthreads();
    buf[threadIdx.x] += t;
    __syncthreads();
  }
  if (i < n) out2[i] = buf[threadIdx.x] - v;
  if (threadIdx.x == 255) bsum2[blockIdx.x] = buf[255];
  __syncthreads();
  if (threadIdx.x < NCLUS){
    int c = lcs[threadIdx.x];
    if (c) atomicAdd(&csize[threadIdx.x], c);
  }
}

__global__ __launch_bounds__(512) void k_scan_bsum2(int* __restrict__ bsum1, int* __restrict__ bsum2, int nb){
  int* bs = blockIdx.x ? bsum2 : bsum1;
  __shared__ int buf[512];
  int v = (threadIdx.x < nb) ? bs[threadIdx.x] : 0;
  buf[threadIdx.x] = v; __syncthreads();
  for (int off=1; off<512; off<<=1){
    int t = (threadIdx.x>=off) ? buf[threadIdx.x-off] : 0;
    __syncthreads();
    buf[threadIdx.x] += t;
    __syncthreads();
  }
  if (threadIdx.x < nb) bs[threadIdx.x] = buf[threadIdx.x] - v;
}

__global__ __launch_bounds__(256) void k_scan_add2(int* __restrict__ out1, int* __restrict__ out2,
                                                   const int* __restrict__ bsum1, const int* __restrict__ bsum2,
                                                   int n, int total1, int total2){
  int* out = blockIdx.y ? out2 : out1;
  const int* bs = blockIdx.y ? bsum2 : bsum1;
  int total = blockIdx.y ? total2 : total1;
  int i = blockIdx.x*256 + threadIdx.x;
  if (i < n) out[i] += bs[i>>8];
  if (i == 0) out[n] = total;
}

// fill main CSR + intra CSR (no atomics on float data)
__global__ __launch_bounds__(256) void k_fill_csr(const int* __restrict__ ei, const int* __restrict__ clus,
                                                  const int* __restrict__ offs, const int* __restrict__ ioffs,
                                                  int* __restrict__ cursor, int* __restrict__ cursor2,
                                                  int2* __restrict__ csr, int* __restrict__ csr2){
  int e = blockIdx.x*256 + threadIdx.x;
  if (e >= NEDGES) return;
  int s = ei[e], d = ei[NEDGES+e];
  int pos = offs[d] + atomicAdd(&cursor[d], 1);
  csr[pos] = make_int2(s, e);
  if (clus[s] == clus[d]){
    int p2 = ioffs[d] + atomicAdd(&cursor2[d], 1);
    csr2[p2] = s;
  }
}

// per-node mean edge-attr (self-loop fill), from CSR
__global__ __launch_bounds__(256) void k_loopattr(const int* __restrict__ offs, const int2* __restrict__ csr,
                                                  const float* __restrict__ eattr, float* __restrict__ la){
  int n = blockIdx.x*256 + threadIdx.x;
  if (n >= NNODES) return;
  int b0 = offs[n], b1 = offs[n+1];
  float s0=0.f, s1=0.f;
  for (int i=b0; i<b1; ++i){
    int e = csr[i].y;
    float2 a = *reinterpret_cast<const float2*>(&eattr[2*e]);
    s0 += a.x; s1 += a.y;
  }
  float inv = 1.f/fmaxf((float)(b1-b0), 1.f);
  la[2*n] = s0*inv; la[2*n+1] = s1*inv;
}

// ---------------- weight converts + glt2(W' for agg GEMM) + AsAll/AdAll + M2, one kernel ----------------
__global__ __launch_bounds__(256) void k_wtall_m2(const float* __restrict__ W1, const float* __restrict__ W2,
                       const float* __restrict__ gcnW, const float* __restrict__ gat_lin,
                       unsigned short* __restrict__ W1t, unsigned short* __restrict__ W2t,
                       unsigned short* __restrict__ gcnWt, unsigned short* __restrict__ glt2,
                       const float* __restrict__ att_s, const float* __restrict__ att_d,
                       float* __restrict__ AsAll, float* __restrict__ AdAll,
                       const float* __restrict__ g_lin_e, const float* __restrict__ g_att_e,
                       const float* __restrict__ gat_lin_e, const float* __restrict__ gat_att_e,
                       float* __restrict__ M2g, float* __restrict__ M2){
  int i = blockIdx.x*256 + threadIdx.x;
  if (i < 229376){            // W1: K=896, N=256
    int n = i/896, k = i - n*896;
    W1t[i] = f2bf(W1[(size_t)k*256 + n]);
  } else if (i < 262144){     // W2: K=256, N=128
    int j = i - 229376; int n = j/256, k = j - n*256;
    W2t[j] = f2bf(W2[(size_t)k*128 + n]);
  } else if (i < 278528){     // gcnW: 128x128
    int j = i - 262144; int n = j/128, k = j - n*128;
    gcnWt[j] = f2bf(gcnW[(size_t)k*128 + n]);
  } else if (i < 475136){     // glt2: 3 x [128 d][512 hk]
    int j = i - 278528; int l = j >> 16; int r = j & 65535; int d = r >> 9; int hk = r & 511;
    glt2[j] = f2bf(0.25f * gat_lin[(size_t)l*65536 + (size_t)(hk & 127)*512 + (hk >> 7)*128 + d]);
  } else if (i < 478208){     // AsAll/AdAll: 3*128*4*2
    int j = i - 475136;
    int which = j & 1, h = (j >> 1) & 3, k = (j >> 3) & 127, l = j >> 10;
    const float* att = which ? att_d : att_s;
    float s = 0.f;
    for (int c=0;c<128;c++) s += gat_lin[(size_t)l*65536 + k*512 + h*128 + c] * att[l*512 + h*128 + c];
    float* dst = which ? AdAll : AsAll;
    dst[l*512 + k*4 + h] = s;
  } else if (i < 478240){     // M2 precompute
    int t = i - 478208;
    if (t < 8){
      int j = t >> 2, h = t & 3;
      float s = 0.f;
      for (int c=0;c<128;c++) s += g_lin_e[j*512 + h*128 + c] * g_att_e[h*128 + c];
      M2g[j*4+h] = s;
    } else {
      int u = t - 8; int l = u >> 3, j = (u >> 2) & 1, h = u & 3;
      float s = 0.f;
      for (int c=0;c<128;c++) s += gat_lin_e[l*1024 + j*512 + h*128 + c] * gat_att_e[l*512 + h*128 + c];
      M2[l*8 + j*4 + h] = s;
    }
  }
}

// ---------------- bf16 MFMA GEMM: C = act(A @ Bt^T + bias), 128x128 tile ----------------
// Staging via global_load_lds (async DMA): LDS layout kept linear per-wave (8 rows x 128B = 1KB),
// XOR swizzle realized by pre-swizzling the per-lane GLOBAL source column (cSw = cA ^ (row&7)).
template<int AF32, int CONCAT, int OUT, int RELU, int BIAS>
__global__ __launch_bounds__(256)
void k_mgemm(const void* __restrict__ Av, const float* __restrict__ A2,
             const unsigned short* __restrict__ Bt, const float* __restrict__ bias,
             void* __restrict__ Cv, int M, int N, int K, int K1)
{
  __shared__ unsigned short As[128*64];
  __shared__ unsigned short Bs[128*64];
  const int tid = threadIdx.x;
  const int lane = tid & 63, w = tid >> 6;
  const int row0 = blockIdx.x*128, col0 = blockIdx.y*128;
  const int wm = w >> 1, wn = w & 1;
  const int l15 = lane & 15, l4 = lane >> 4;
  f32x4 acc[4][4];
  #pragma unroll
  for (int i=0;i<4;i++)
    #pragma unroll
    for (int n=0;n<4;n++) acc[i][n] = (f32x4){0.f,0.f,0.f,0.f};

  const int rr0 = w*32 + (lane>>3);
  const int cA = lane & 7;
  const int cSw = cA ^ (rr0 & 7);    // swizzled source chunk (rr&7 constant over i since i*8 multiple of 8)

  for (int kt = 0; kt < K; kt += 64){
    float4 fa[4][2];
    if (AF32){
      #pragma unroll
      for (int i=0;i<4;i++){
        int rr = rr0 + i*8;
        int ga = row0 + rr; ga = (ga < M) ? ga : (M-1);
        int gk = kt + cA*8;
        const float* src;
        if (CONCAT && gk >= K1) src = A2 + (size_t)ga*(K-K1) + (gk - K1);
        else                    src = ((const float*)Av) + (size_t)ga*(CONCAT ? K1 : K) + gk;
        fa[i][0] = ((const float4*)src)[0];
        fa[i][1] = ((const float4*)src)[1];
      }
    }
    __syncthreads();   // prev tile MFMA reads done; LDS writable
    #pragma unroll
    for (int i=0;i<4;i++){
      int rr = rr0 + i*8;
      int gb = col0 + rr; gb = (gb < N) ? gb : (N-1);
      gload_lds16(Bt + (size_t)gb*K + kt + cSw*8, &Bs[(w*32 + i*8)*64]);
      if (!AF32){
        int ga = row0 + rr; ga = (ga < M) ? ga : (M-1);
        gload_lds16((const unsigned short*)Av + (size_t)ga*K + kt + cSw*8, &As[(w*32 + i*8)*64]);
      }
    }
    if (AF32){
      #pragma unroll
      for (int i=0;i<4;i++){
        int rr = rr0 + i*8;
        int ch = cA ^ (rr & 7);
        uint4 va = make_uint4(pk2(fa[i][0].x,fa[i][0].y), pk2(fa[i][0].z,fa[i][0].w),
                              pk2(fa[i][1].x,fa[i][1].y), pk2(fa[i][1].z,fa[i][1].w));
        *reinterpret_cast<uint4*>(&As[rr*64 + ch*8]) = va;
      }
    }
    __syncthreads();   // drains vmcnt (async LDS DMA) + lgkm
    #pragma unroll
    for (int k0=0;k0<2;k0++){
      bf16x8 af[4], bff[4];
      #pragma unroll
      for (int i=0;i<4;i++){
        int row = wm*64 + i*16 + l15;
        int ch = (k0*4 + l4) ^ (row & 7);
        af[i] = *reinterpret_cast<const bf16x8*>(&As[row*64 + ch*8]);
      }
      #pragma unroll
      for (int n=0;n<4;n++){
        int row = wn*64 + n*16 + l15;
        int ch = (k0*4 + l4) ^ (row & 7);
        bff[n] = *reinterpret_cast<const bf16x8*>(&Bs[row*64 + ch*8]);
      }
      #pragma unroll
      for (int i=0;i<4;i++)
        #pragma unroll
        for (int n=0;n<4;n++)
          acc[i][n] = __builtin_amdgcn_mfma_f32_16x16x32_bf16(af[i], bff[n], acc[i][n], 0, 0, 0);
    }
  }
  // C store
  #pragma unroll
  for (int i=0;i<4;i++){
    int rowb = row0 + wm*64 + i*16 + l4*4;
    #pragma unroll
    for (int n=0;n<4;n++){
      int col = col0 + wn*64 + n*16 + l15;
      float bv = BIAS ? bias[col] : 0.f;
      #pragma unroll
      for (int r=0;r<4;r++){
        int row = rowb + r;
        if (row < M){
          float y = acc[i][n][r] + bv;
          if (RELU) y = fmaxf(y, 0.f);
          if (OUT == 1)      ((unsigned short*)Cv)[(size_t)row*N + col] = f2bf(y);
          else if (OUT == 2) ((__half*)Cv)[(size_t)row*N + col] = __float2half(y);
          else               ((float*)Cv)[(size_t)row*N + col] = y;
        }
      }
    }
  }
}

// ---------------- f32 SGEMM (tiny pooled GEMM only) ----------------
template<int CONCAT, int ACT>
__global__ __launch_bounds__(256)
void k_sgemm(const float* __restrict__ A, const float* __restrict__ A2,
             const float* __restrict__ B, const float* __restrict__ bias,
             float* __restrict__ C, int M, int N, int K, int K1)
{
  __shared__ float As[8][128];
  __shared__ float Bs[8][128];
  int row0 = blockIdx.x*128, col0 = blockIdx.y*128;
  int tid = threadIdx.x;
  int tx = tid & 15, ty = tid >> 4;
  float acc[8][8];
  #pragma unroll
  for (int i=0;i<8;i++)
    #pragma unroll
    for (int j=0;j<8;j++) acc[i][j]=0.f;

  int arow = tid >> 1, acol = (tid & 1)*4;
  int brow = tid >> 5, bcol = (tid & 31)*4;
  int K2 = K - K1;

  for (int k0=0; k0<K; k0+=8){
    float4 av = make_float4(0.f,0.f,0.f,0.f);
    int gr = row0 + arow, gk = k0 + acol;
    if (gr < M){
      if (CONCAT){
        if (gk < K1) av = *reinterpret_cast<const float4*>(&A [(size_t)gr*K1 + gk]);
        else         av = *reinterpret_cast<const float4*>(&A2[(size_t)gr*K2 + (gk-K1)]);
      } else {
        av = *reinterpret_cast<const float4*>(&A[(size_t)gr*K + gk]);
      }
    }
    As[acol+0][arow]=av.x; As[acol+1][arow]=av.y; As[acol+2][arow]=av.z; As[acol+3][arow]=av.w;
    float4 bv = *reinterpret_cast<const float4*>(&B[(size_t)(k0+brow)*N + col0 + bcol]);
    *reinterpret_cast<float4*>(&Bs[brow][bcol]) = bv;
    __syncthreads();
    #pragma unroll
    for (int kk=0; kk<8; ++kk){
      float a[8], b[8];
      *(float4*)&a[0] = *(float4*)&As[kk][ty*8];
      *(float4*)&a[4] = *(float4*)&As[kk][ty*8+4];
      *(float4*)&b[0] = *(float4*)&Bs[kk][tx*8];
      *(float4*)&b[4] = *(float4*)&Bs[kk][tx*8+4];
      #pragma unroll
      for (int i=0;i<8;i++)
        #pragma unroll
        for (int j=0;j<8;j++) acc[i][j] = fmaf(a[i], b[j], acc[i][j]);
    }
    __syncthreads();
  }
  #pragma unroll
  for (int i=0;i<8;i++){
    int r = row0 + ty*8 + i;
    if (r >= M) continue;
    #pragma unroll
    for (int j4=0;j4<2;j4++){
      int c = col0 + tx*8 + j4*4;
      float4 v = make_float4(acc[i][j4*4], acc[i][j4*4+1], acc[i][j4*4+2], acc[i][j4*4+3]);
      if (bias){
        float4 bb = *reinterpret_cast<const float4*>(&bias[c]);
        v = f4add(v, bb);
      }
      if (ACT == 1){
        v.x=fmaxf(v.x,0.f); v.y=fmaxf(v.y,0.f); v.z=fmaxf(v.z,0.f); v.w=fmaxf(v.w,0.f);
      }
      *reinterpret_cast<float4*>(&C[(size_t)r*N + c]) = v;
    }
  }
}

// ---------------- GCN aggregation (intra-CSR: only intra-cluster edges) ----------------
__global__ __launch_bounds__(256) void k_gcn(const unsigned short* __restrict__ XWh, const int* __restrict__ ioffs,
                      const int* __restrict__ csr2, const int* __restrict__ intra,
                      const float* __restrict__ gcn_b, float* __restrict__ Xc)
{
  int wid  = (blockIdx.x*blockDim.x + threadIdx.x) >> 6;
  int lane = threadIdx.x & 63;
  int nw   = (gridDim.x*blockDim.x) >> 6;
  for (int n = wid; n < NNODES; n += nw){
    int cntn = intra[n];
    float deg = 1.f + (float)cntn;
    float dinv_n = rsqrtf(deg);
    __half2 hx = *reinterpret_cast<const __half2*>(XWh + (size_t)n*128 + lane*2);
    float2 acc;
    acc.x = __low2float(hx)/deg; acc.y = __high2float(hx)/deg;
    int io0 = ioffs[n];
    for (int j=0; j<cntn; ++j){
      int s = csr2[io0+j];
      float w = dinv_n * rsqrtf(1.f + (float)intra[s]);
      __half2 hs = *reinterpret_cast<const __half2*>(XWh + (size_t)s*128 + lane*2);
      acc.x = fmaf(w, __low2float(hs), acc.x);
      acc.y = fmaf(w, __high2float(hs), acc.y);
    }
    float2 bb = *reinterpret_cast<const float2*>(&gcn_b[lane*2]);
    acc.x += bb.x; acc.y += bb.y;
    *reinterpret_cast<float2*>(&Xc[(size_t)n*128 + lane*2]) = acc;
  }
}

// ---------------- cluster pooling: LDS partials + reduce ----------------
__global__ __launch_bounds__(256) void k_pool1(const float* __restrict__ Xc, const int* __restrict__ clus,
                                               float* __restrict__ part){
  __shared__ float lp[8192];
  for (int i=threadIdx.x; i<8192; i+=256) lp[i]=0.f;
  __syncthreads();
  int d = threadIdx.x & 127, rg = threadIdx.x >> 7;
  int n0 = blockIdx.x*200;
  for (int n = n0+rg; n < n0+200; n += 2){
    int c = clus[n];
    atomicAdd(&lp[c*128 + d], Xc[(size_t)n*128 + d]);
  }
  __syncthreads();
  for (int i=threadIdx.x; i<8192; i+=256) part[(size_t)blockIdx.x*8192 + i] = lp[i];
}
__global__ __launch_bounds__(256) void k_pool2(const float* __restrict__ part, const int* __restrict__ csize,
                                               float* __restrict__ pooled){
  int i = blockIdx.x*256 + threadIdx.x; // 8192
  float s = 0.f;
  for (int b=0;b<400;b++) s += part[(size_t)b*8192 + i];
  pooled[i] = s / fmaxf((float)csize[i>>7], 1.f);
}

// ---------------- cluster GAT small kernels fused: block0=asc, block1=loop_c ----------------
__global__ __launch_bounds__(256) void k_cluster_small(const float* __restrict__ xh_c,
                     const float* __restrict__ g_att_s, const float* __restrict__ g_att_d,
                     float* __restrict__ a_s_c, float* __restrict__ a_d_c,
                     const float* __restrict__ pair_cnt, const float* __restrict__ avg_attr,
                     float* __restrict__ loop_c){
  int t = threadIdx.x;
  if (blockIdx.x == 0){
    int s = t >> 2, h = t & 3;
    float ss=0.f, sd=0.f;
    for (int c=0;c<128;c++){
      float x = xh_c[s*512 + h*128 + c];
      ss += x * g_att_s[h*128 + c];
      sd += x * g_att_d[h*128 + c];
    }
    a_s_c[s*4+h] = ss; a_d_c[s*4+h] = sd;
  } else {
    if (t >= NCLUS) return;
    int d = t;
    float ic=0.f, l0=0.f, l1=0.f;
    for (int s=0;s<NCLUS;s++){
      int k = s*NCLUS + d;
      if (pair_cnt[k] > 0.f){ ic += 1.f; l0 += avg_attr[2*k]; l1 += avg_attr[2*k+1]; }
    }
    float inv = 1.f / fmaxf(ic, 1.f);
    loop_c[2*d] = l0*inv; loop_c[2*d+1] = l1*inv;
  }
}

__global__ __launch_bounds__(128) void k_clout(const float* __restrict__ a_s_c, const float* __restrict__ a_d_c,
                       const float* __restrict__ loop_c, const float* __restrict__ M2g,
                       const float* __restrict__ pair_cnt, const float* __restrict__ avg_attr,
                       const float* __restrict__ xh_c, const float* __restrict__ g_bias,
                       float* __restrict__ cl_out)
{
  int d = blockIdx.x;
  __shared__ float p[NCLUS*4];
  int t = threadIdx.x;
  if (t < NCLUS){
    int s = t;
    for (int h=0; h<4; ++h){
      float v;
      if (s == d){
        v = lrelu(a_s_c[d*4+h] + a_d_c[d*4+h] + loop_c[2*d]*M2g[h] + loop_c[2*d+1]*M2g[4+h]);
      } else if (pair_cnt[s*NCLUS+d] > 0.f){
        int k = s*NCLUS + d;
        v = lrelu(a_s_c[s*4+h] + a_d_c[d*4+h] + avg_attr[2*k]*M2g[h] + avg_attr[2*k+1]*M2g[4+h]);
      } else {
        v = -INFINITY;
      }
      p[s*4+h] = v;
    }
  }
  __syncthreads();
  if (t < 4){
    int h = t;
    float m = -INFINITY;
    for (int s=0;s<NCLUS;s++) m = fmaxf(m, p[s*4+h]);
    float sum = 0.f;
    for (int s=0;s<NCLUS;s++){
      float a = p[s*4+h];
      float e = (a == -INFINITY) ? 0.f : expf(a - m);
      p[s*4+h] = e; sum += e;
    }
    float inv = 1.f/sum;
    for (int s=0;s<NCLUS;s++) p[s*4+h] *= inv;
  }
  __syncthreads();
  int c = t;
  float acc = 0.f;
  for (int s=0;s<NCLUS;s++){
    #pragma unroll
    for (int h=0;h<4;h++) acc += p[s*4+h]*xh_c[s*512 + h*128 + c];
  }
  cl_out[d*128 + c] = 0.25f*acc + g_bias[c];
}

// Xcomb = Xc + cl_out[clus]; write f16 X + fused a_s/a_d dots (layer 0)
__global__ __launch_bounds__(256) void k_xcomb(const float* __restrict__ Xc, const float* __restrict__ cl_out,
                                               const int* __restrict__ clus, __half* __restrict__ xh16,
                                               const float* __restrict__ AsA, const float* __restrict__ AdA,
                                               float* __restrict__ a_s, float* __restrict__ a_d){
  int i = blockIdx.x*256 + threadIdx.x;
  int stride = gridDim.x*256;
  for (; i < NNODES*32; i += stride){
    int n = i >> 5, d4 = i & 31;
    float4 a = ((const float4*)Xc)[i];
    float4 b = ((const float4*)&cl_out[clus[n]*128])[d4];
    float4 r = f4add(a, b);
    __half2 hv[2];
    hv[0] = __floats2half2_rn(r.x, r.y);
    hv[1] = __floats2half2_rn(r.z, r.w);
    ((uint2*)xh16)[i] = *reinterpret_cast<uint2*>(hv);
    float4 ps = make_float4(0,0,0,0), pd = make_float4(0,0,0,0);
    const float4* As4 = (const float4*)(AsA) + d4*4;
    const float4* Ad4 = (const float4*)(AdA) + d4*4;
    ps = f4fma1(r.x, As4[0], ps); ps = f4fma1(r.y, As4[1], ps);
    ps = f4fma1(r.z, As4[2], ps); ps = f4fma1(r.w, As4[3], ps);
    pd = f4fma1(r.x, Ad4[0], pd); pd = f4fma1(r.y, Ad4[1], pd);
    pd = f4fma1(r.z, Ad4[2], pd); pd = f4fma1(r.w, Ad4[3], pd);
    #pragma unroll
    for (int m=16; m>=1; m>>=1){
      ps.x += __shfl_xor(ps.x, m); ps.y += __shfl_xor(ps.y, m);
      ps.z += __shfl_xor(ps.z, m); ps.w += __shfl_xor(ps.w, m);
      pd.x += __shfl_xor(pd.x, m); pd.y += __shfl_xor(pd.y, m);
      pd.z += __shfl_xor(pd.z, m); pd.w += __shfl_xor(pd.w, m);
    }
    if (d4 == 0){
      *reinterpret_cast<float4*>(&a_s[n*4]) = ps;
      *reinterpret_cast<float4*>(&a_d[n*4]) = pd;
    }
  }
}

// ---------------- GAT aggregation in X-space: 16-edge batched logits + shfl broadcast, 3-deep prefetch ----------------
__global__ __launch_bounds__(256) void k_gat_x(const __half* __restrict__ Xh, const float* __restrict__ a_s,
                     const float* __restrict__ a_d, const float* __restrict__ eattr,
                     const int* __restrict__ offs, const int2* __restrict__ csr,
                     const float* __restrict__ la, const float* __restrict__ M2l,
                     unsigned short* __restrict__ agg)
{
  int wid  = (blockIdx.x*blockDim.x + threadIdx.x) >> 6;
  int lane = threadIdx.x & 63;
  int nw   = (gridDim.x*blockDim.x) >> 6;
  int h = lane >> 4;
  int j = lane & 15;
  int grpbase = h << 4;
  int kslot = j*8;
  float m2a = M2l[h], m2b = M2l[4+h];
  for (int n = wid; n < NNODES; n += nw){
    float adn = a_d[n*4+h];
    float pl = __expf(lrelu(a_s[n*4+h] + adn + la[2*n]*m2a + la[2*n+1]*m2b));
    uint4 u0 = *reinterpret_cast<const uint4*>(Xh + (size_t)n*128 + kslot);
    __half2* x0 = reinterpret_cast<__half2*>(&u0);
    __half2 pl2 = __float2half2_rn(pl);
    __half2 acc0 = __hmul2(x0[0], pl2), acc1 = __hmul2(x0[1], pl2);
    __half2 acc2 = __hmul2(x0[2], pl2), acc3 = __hmul2(x0[3], pl2);
    int b0 = offs[n], b1 = offs[n+1];
    float dsum = 0.f;
    for (int base = b0; base < b1; base += 16){
      int cnt = min(16, b1 - base);
      // batch phase: lane j computes edge (base+j)'s logit ONCE per group
      float pe_j = 0.f; int sx_j = 0;
      if (j < cnt){
        int2 se = csr[base + j];
        sx_j = se.x;
        float2 ea = *reinterpret_cast<const float2*>(&eattr[2*se.y]);
        float asv = a_s[se.x*4+h];
        pe_j = __expf(lrelu(asv + adn + ea.x*m2a + ea.y*m2b));
      }
      dsum += pe_j;
      // accumulate phase: shfl-broadcast src/pe; 3-deep X-row prefetch
      uint4 uA = make_uint4(0,0,0,0), uB = make_uint4(0,0,0,0), uC = make_uint4(0,0,0,0);
      if (cnt > 0){
        int sx = __shfl(sx_j, grpbase);
        uA = *reinterpret_cast<const uint4*>(Xh + (size_t)sx*128 + kslot);
      }
      if (cnt > 1){
        int sx = __shfl(sx_j, grpbase+1);
        uB = *reinterpret_cast<const uint4*>(Xh + (size_t)sx*128 + kslot);
      }
      if (cnt > 2){
        int sx = __shfl(sx_j, grpbase+2);
        uC = *reinterpret_cast<const uint4*>(Xh + (size_t)sx*128 + kslot);
      }
      __builtin_amdgcn_s_setprio(1);
      for (int jj=0; jj<cnt; ++jj){
        uint4 u = uA; uA = uB; uB = uC;
        if (jj+3 < cnt){
          int sx = __shfl(sx_j, grpbase+jj+3);
          uC = *reinterpret_cast<const uint4*>(Xh + (size_t)sx*128 + kslot);
        }
        float pe = __shfl(pe_j, grpbase+jj);
        __half2 pe2 = __float2half2_rn(pe);
        __half2* y = reinterpret_cast<__half2*>(&u);
        acc0 = __hfma2(y[0], pe2, acc0);
        acc1 = __hfma2(y[1], pe2, acc1);
        acc2 = __hfma2(y[2], pe2, acc2);
        acc3 = __hfma2(y[3], pe2, acc3);
      }
      __builtin_amdgcn_s_setprio(0);
    }
    // group (16-lane) reduce of edge-prob sum
    dsum += __shfl_xor(dsum, 1);
    dsum += __shfl_xor(dsum, 2);
    dsum += __shfl_xor(dsum, 4);
    dsum += __shfl_xor(dsum, 8);
    float sc = 1.f/(pl + dsum);   // 0.25 mean folded into glt2
    uint4 w;
    w.x = pk2(__low2float(acc0)*sc, __high2float(acc0)*sc);
    w.y = pk2(__low2float(acc1)*sc, __high2float(acc1)*sc);
    w.z = pk2(__low2float(acc2)*sc, __high2float(acc2)*sc);
    w.w = pk2(__low2float(acc3)*sc, __high2float(acc3)*sc);
    *reinterpret_cast<uint4*>(agg + (size_t)n*512 + h*128 + kslot) = w;
  }
}

// ---------------- graph norm: colstat + finstat fused (threadfence last-block pattern) ----------------
__global__ __launch_bounds__(256) void k_colstat_fin(const __half* __restrict__ X, float* __restrict__ part,
                         int* __restrict__ counter,
                         const float* __restrict__ w, const float* __restrict__ b, const float* __restrict__ ms,
                         float* __restrict__ scaleA, float* __restrict__ shiftB){
  int d = threadIdx.x & 127;
  int rg = threadIdx.x >> 7;
  float s1=0.f, s2=0.f;
  for (int n = blockIdx.x*2 + rg; n < NNODES; n += 512){
    float v = __half2float(X[(size_t)n*128 + d]);
    s1 += v; s2 = fmaf(v, v, s2);
  }
  __shared__ float sh[512];
  sh[threadIdx.x] = s1; sh[256+threadIdx.x] = s2;
  __syncthreads();
  if (threadIdx.x < 128){
    s1 = sh[threadIdx.x] + sh[threadIdx.x+128];
    s2 = sh[256+threadIdx.x] + sh[256+threadIdx.x+128];
    part[blockIdx.x*256 + d]       = s1;
    part[blockIdx.x*256 + 128 + d] = s2;
  }
  __threadfence();
  __syncthreads();
  __shared__ int isLast;
  if (threadIdx.x == 0){
    int done = atomicAdd(counter, 1);
    isLast = (done == 255);
  }
  __syncthreads();
  if (isLast){
    __threadfence();
    if (threadIdx.x < 128){
      int dd = threadIdx.x;
      float t1=0.f, t2=0.f;
      for (int bq=0; bq<256; bq++){ t1 += part[bq*256 + dd]; t2 += part[bq*256 + 128 + dd]; }
      float mean = t1 * (1.f/NNODES);
      float ex2  = t2 * (1.f/NNODES);
      float m = ms[dd];
      float var = ex2 - m*mean*mean*(2.f - m);
      float sc = w[dd] * rsqrtf(var + EPSV);
      scaleA[dd] = sc;
      shiftB[dd] = b[dd] - sc*m*mean;
    }
    if (threadIdx.x == 0) *counter = 0;
  }
}

// norm + residual(f16) + ELU; write f16 X + fused next-layer a_s/a_d (or f32 final output)
__global__ __launch_bounds__(256) void k_normelu(const __half* __restrict__ o, __half* __restrict__ xh16,
                         const float* __restrict__ scaleA, const float* __restrict__ shiftB,
                         const float* __restrict__ AsA, const float* __restrict__ AdA,
                         float* __restrict__ a_s, float* __restrict__ a_d,
                         float* __restrict__ fout){
  int i = blockIdx.x*256 + threadIdx.x;
  int stride = gridDim.x*256;
  for (; i < NNODES*32; i += stride){
    int n = i >> 5, d4 = i & 31;
    uint2 ou = ((const uint2*)o)[i];
    __half2* oh = reinterpret_cast<__half2*>(&ou);
    float o0 = __low2float(oh[0]), o1 = __high2float(oh[0]);
    float o2 = __low2float(oh[1]), o3 = __high2float(oh[1]);
    uint2 xu = ((const uint2*)xh16)[i];
    __half2* xh = reinterpret_cast<__half2*>(&xu);
    float xi0 = __low2float(xh[0]), xi1 = __high2float(xh[0]);
    float xi2 = __low2float(xh[1]), xi3 = __high2float(xh[1]);
    float4 sc = ((const float4*)scaleA)[d4];
    float4 sh = ((const float4*)shiftB)[d4];
    float4 r; float y;
    y = fmaf(sc.x, o0, sh.x) + xi0; r.x = y > 0.f ? y : expm1f(y);
    y = fmaf(sc.y, o1, sh.y) + xi1; r.y = y > 0.f ? y : expm1f(y);
    y = fmaf(sc.z, o2, sh.z) + xi2; r.z = y > 0.f ? y : expm1f(y);
    y = fmaf(sc.w, o3, sh.w) + xi3; r.w = y > 0.f ? y : expm1f(y);
    if (fout){
      ((float4*)fout)[i] = r;
    } else {
      __half2 hv[2];
      hv[0] = __floats2half2_rn(r.x, r.y);
      hv[1] = __floats2half2_rn(r.z, r.w);
      ((uint2*)xh16)[i] = *reinterpret_cast<uint2*>(hv);
      float4 ps = make_float4(0,0,0,0), pd = make_float4(0,0,0,0);
      const float4* As4 = (const float4*)(AsA) + d4*4;
      const float4* Ad4 = (const float4*)(AdA) + d4*4;
      ps = f4fma1(r.x, As4[0], ps); ps = f4fma1(r.y, As4[1], ps);
      ps = f4fma1(r.z, As4[2], ps); ps = f4fma1(r.w, As4[3], ps);
      pd = f4fma1(r.x, Ad4[0], pd); pd = f4fma1(r.y, Ad4[1], pd);
      pd = f4fma1(r.z, Ad4[2], pd); pd = f4fma1(r.w, Ad4[3], pd);
      #pragma unroll
      for (int m=16; m>=1; m>>=1){
        ps.x += __shfl_xor(ps.x, m); ps.y += __shfl_xor(ps.y, m);
        ps.z += __shfl_xor(ps.z, m); ps.w += __shfl_xor(ps.w, m);
        pd.x += __shfl_xor(pd.x, m); pd.y += __shfl_xor(pd.y, m);
        pd.z += __shfl_xor(pd.z, m); pd.w += __shfl_xor(pd.w, m);
      }
      if (d4 == 0){
        *reinterpret_cast<float4*>(&a_s[n*4]) = ps;
        *reinterpret_cast<float4*>(&a_d[n*4]) = pd;
      }
    }
  }
}

// ---------------- host launch ----------------
extern "C" void kernel_launch(void* const* d_in, const int* in_sizes, int n_in,
                              void* d_out, int out_size, void* d_ws, size_t ws_size,
                              hipStream_t stream)
{
  const float* extra    = (const float*)d_in[0];
  const int*   ei       = (const int*)  d_in[1];
  const float* eattr    = (const float*)d_in[2];
  const int*   clus     = (const int*)  d_in[3];
  const float* user     = (const float*)d_in[4];
  const float* item     = (const float*)d_in[5];
  const float* W1       = (const float*)d_in[6];
  const float* b1       = (const float*)d_in[7];
  const float* W2       = (const float*)d_in[8];
  const float* b2       = (const float*)d_in[9];
  const float* gcnW     = (const float*)d_in[10];
  const float* gcnb     = (const float*)d_in[11];
  const float* g_lin    = (const float*)d_in[12];
  const float* g_lin_e  = (const float*)d_in[13];
  const float* g_att_s  = (const float*)d_in[14];
  const float* g_att_d  = (const float*)d_in[15];
  const float* g_att_e  = (const float*)d_in[16];
  const float* g_bias   = (const float*)d_in[17];
  const float* gat_lin  = (const float*)d_in[18];
  const float* gat_lin_e= (const float*)d_in[19];
  const float* gat_att_s= (const float*)d_in[20];
  const float* gat_att_d= (const float*)d_in[21];
  const float* gat_att_e= (const float*)d_in[22];
  const float* gat_bias = (const float*)d_in[23];
  const float* nw_      = (const float*)d_in[24];
  const float* nb_      = (const float*)d_in[25];
  const float* nms_     = (const float*)d_in[26];

  char* ws = (char*)d_ws;
  size_t off = 0;
  auto alloc = [&](size_t bytes)->char*{
    char* p = ws + off;
    off += (bytes + 255) & ~size_t(255);
    return p;
  };

  float* bufX = (float*)alloc((size_t)NNODES*128*4);
  float* bufY = (float*)alloc((size_t)NNODES*128*4);
  float* bufZ = (float*)alloc((size_t)NNODES*128*4);
  char* big = alloc((size_t)112*1024*1024);
  __half* Xh16          = (__half*)big;
  unsigned short* agg   = (unsigned short*)(big + (size_t)22*1024*1024);
  unsigned short* Hbf   = (unsigned short*)(big + (size_t)22*1024*1024);
  float* pcb  = (float*)(big + (size_t)22*1024*1024);
  float* pa0b = pcb  + 4096*128;
  float* pa1b = pa0b + 4096*128;
  float* ppart = (float*)(big + (size_t)40*1024*1024);
  int* offs   = (int*)alloc((NNODES+1)*4);
  int* ioffs  = (int*)alloc((NNODES+1)*4);
  int* bsum   = (int*)alloc(1024*4);
  int* bsum2  = (int*)alloc(1024*4);
  int2* csr   = (int2*)alloc((size_t)NEDGES*8);
  int* csr2   = (int*)alloc((size_t)NEDGES*4);
  float* a_s  = (float*)alloc((size_t)NNODES*4*4);
  float* a_d  = (float*)alloc((size_t)NNODES*4*4);
  float* la   = (float*)alloc((size_t)NNODES*2*4);
  // zeroed-per-call region (single memset)
  char* zero0 = ws + off;
  int*   cnt      = (int*)  alloc((size_t)NNODES*4);
  int*   intra    = (int*)  alloc((size_t)NNODES*4);
  int*   cursor   = (int*)  alloc((size_t)NNODES*4);
  int*   cursor2  = (int*)  alloc((size_t)NNODES*4);
  int*   csize    = (int*)  alloc(256*4);
  int*   lcounter = (int*)  alloc(256);
  size_t zbytes = (size_t)((ws + off) - zero0);
  // small buffers
  float* pooled= (float*)alloc(8192*4);
  float* M2g   = (float*)alloc(8*4);
  float* M2    = (float*)alloc(24*4);
  float* AsAll = (float*)alloc(3*512*4);
  float* AdAll = (float*)alloc(3*512*4);
  float* pair_cnt = (float*)alloc(4096*4);
  float* avg_attr = (float*)alloc(8192*4);
  float* loop_c   = (float*)alloc(128*4);
  float* xh_c     = (float*)alloc(64*512*4);
  float* a_s_c    = (float*)alloc(256*4);
  float* a_d_c    = (float*)alloc(256*4);
  float* cl_out   = (float*)alloc(64*128*4);
  float* colpart  = (float*)alloc(256*256*4);
  float* scaleA   = (float*)alloc(128*4);
  float* shiftB   = (float*)alloc(128*4);
  unsigned short* W1t  = (unsigned short*)alloc((size_t)896*256*2);
  unsigned short* W2t  = (unsigned short*)alloc((size_t)256*128*2);
  unsigned short* gcnWt= (unsigned short*)alloc((size_t)128*128*2);
  unsigned short* glt2 = (unsigned short*)alloc((size_t)3*128*512*2);
  if (off > ws_size) return;

  hipMemsetAsync(zero0, 0, zbytes, stream);

  const int NB = (NNODES+255)/256;
  // phase 0: pair hist + cnt/intra, reduce; fused dual scans (LDS csize); fill; gather la
  k_pairhist<<<128, 1024, 0, stream>>>(ei, eattr, clus, cnt, intra, pcb, pa0b, pa1b);
  k_pairreduce<<<64, 64, 0, stream>>>(pcb, pa0b, pa1b, pair_cnt, avg_attr);
  k_scan_block2<<<NB, 256, 0, stream>>>(cnt, intra, offs, ioffs, bsum, bsum2, NNODES, clus, csize);
  k_scan_bsum2<<<2, 512, 0, stream>>>(bsum, bsum2, NB);
  {
    dim3 ga(NB, 2);
    k_scan_add2<<<ga, 256, 0, stream>>>(offs, ioffs, bsum, bsum2, NNODES, NEDGES, 0);
  }
  k_fill_csr<<<(NEDGES+255)/256, 256, 0, stream>>>(ei, clus, offs, ioffs, cursor, cursor2, csr, csr2);
  k_loopattr<<<NB, 256, 0, stream>>>(offs, csr, eattr, la);

  // weight conversions + glt2 + AsAll/AdAll + M2 (one kernel)
  k_wtall_m2<<<1869, 256, 0, stream>>>(W1, W2, gcnW, gat_lin, W1t, W2t, gcnWt, glt2,
                                       gat_att_s, gat_att_d, AsAll, AdAll,
                                       g_lin_e, g_att_e, gat_lin_e, gat_att_e, M2g, M2);

  // enrichment MLP (bf16 MFMA, f32-A fused conversion); Hbf reuses dead pairhist region
  {
    dim3 g1((N_ITEMS+127)/128, 2);
    k_mgemm<1,1,1,1,1><<<g1, 256, 0, stream>>>((const void*)item, extra, W1t, b1, (void*)Hbf,
                                               N_ITEMS, 256, 896, 128);
    dim3 g2((N_ITEMS+127)/128, 1);
    k_mgemm<0,0,0,0,1><<<g2, 256, 0, stream>>>((const void*)Hbf, nullptr, W2t, b2,
                                               (void*)(bufX + (size_t)N_USERS*128),
                                               N_ITEMS, 128, 256, 0);
  }
  hipMemcpyAsync(bufX, user, (size_t)N_USERS*128*4, hipMemcpyDeviceToDevice, stream);

  // cluster GCN: XW (f16) = X @ gcnW; aggregate over intra-CSR only
  {
    dim3 g3((NNODES+127)/128, 1);
    k_mgemm<1,0,2,0,0><<<g3, 256, 0, stream>>>((const void*)bufX, nullptr, gcnWt, nullptr, (void*)bufY,
                                               NNODES, 128, 128, 0);
  }
  k_gcn<<<5000, 256, 0, stream>>>((const unsigned short*)bufY, ioffs, csr2, intra, gcnb, bufZ);

  // pooling (LDS partials) + cluster GAT
  k_pool1<<<400, 256, 0, stream>>>(bufZ, clus, ppart);
  k_pool2<<<32, 256, 0, stream>>>(ppart, csize, pooled);
  {
    dim3 g4(1, 4);
    k_sgemm<0,0><<<g4, 256, 0, stream>>>(pooled, nullptr, g_lin, nullptr, xh_c, 64, 512, 128, 0);
  }
  k_cluster_small<<<2, 256, 0, stream>>>(xh_c, g_att_s, g_att_d, a_s_c, a_d_c, pair_cnt, avg_attr, loop_c);
  k_clout<<<64, 128, 0, stream>>>(a_s_c, a_d_c, loop_c, M2g, pair_cnt, avg_attr, xh_c, g_bias, cl_out);
  k_xcomb<<<1280, 256, 0, stream>>>(bufZ, cl_out, clus, Xh16, AsAll, AdAll, a_s, a_d);

  // 3 GAT layers: k_gat_x (batched logits, X-space agg) -> agg @ glt2 GEMM (gload_lds)
  for (int l = 0; l < 3; ++l){
    k_gat_x<<<20000, 256, 0, stream>>>(Xh16, a_s, a_d, eattr, offs, csr, la, M2 + l*8, agg);
    {
      dim3 gg((NNODES+127)/128, 1);
      k_mgemm<0,0,2,0,1><<<gg, 256, 0, stream>>>((const void*)agg, nullptr, glt2 + (size_t)l*65536,
                                                 gat_bias + l*128, (void*)bufY, NNODES, 128, 512, 0);
    }
    k_colstat_fin<<<256, 256, 0, stream>>>((const __half*)bufY, colpart, lcounter,
                                           nw_ + l*128, nb_ + l*128, nms_ + l*128, scaleA, shiftB);
    k_normelu<<<1280, 256, 0, stream>>>((const __half*)bufY, Xh16, scaleA, shiftB,
                                        AsAll + (l+1 < 3 ? (l+1)*512 : 0),
                                        AdAll + (l+1 < 3 ? (l+1)*512 : 0),
                                        a_s, a_d,
                                        (l==2) ? (float*)d_out : nullptr);
  }
}